// Round 4
// baseline (517.247 us; speedup 1.0000x reference)
//
#include <hip/hip_runtime.h>
#include <hip/hip_fp16.h>

#define N_NODES   100000
#define N_EDGES   1600000
#define N_FEAT    100
#define HIDDEN    64
#define N_CLASSES 47
#define ZPAD      48
#define NODE_BLKS ((N_NODES + 255) / 256)   // 391
#define EDGE_BLKS ((N_EDGES + 255) / 256)   // 6250
#define NB        ((N_NODES + 63) / 64)     // 1563 buckets of 64 dest nodes

// ---------------- CSR build: counting sort by destination ----------------

__global__ void k_zero(int* __restrict__ cnt) {
    int i = blockIdx.x * 256 + threadIdx.x;
    if (i < N_NODES) cnt[i] = 0;
}

__global__ void k_count(const int* __restrict__ ecol, int* __restrict__ cnt) {
    int e = blockIdx.x * 256 + threadIdx.x;
    if (e < N_EDGES) atomicAdd(&cnt[ecol[e]], 1);
}

__global__ __launch_bounds__(256) void k_scan1(const int* __restrict__ cnt,
                                               int* __restrict__ rp,
                                               int* __restrict__ sums) {
    __shared__ int tmp[256];
    int i = blockIdx.x * 256 + threadIdx.x;
    int v = (i < N_NODES) ? cnt[i] : 0;
    tmp[threadIdx.x] = v;
    __syncthreads();
    for (int off = 1; off < 256; off <<= 1) {
        int t = (threadIdx.x >= off) ? tmp[threadIdx.x - off] : 0;
        __syncthreads();
        tmp[threadIdx.x] += t;
        __syncthreads();
    }
    if (i < N_NODES) rp[i] = tmp[threadIdx.x] - v;
    if (threadIdx.x == 255) sums[blockIdx.x] = tmp[255];
}

__global__ __launch_bounds__(512) void k_scan2(int* __restrict__ sums) {
    __shared__ int tmp[512];
    int i = threadIdx.x;
    int v = (i < NODE_BLKS) ? sums[i] : 0;
    tmp[i] = v;
    __syncthreads();
    for (int off = 1; off < 512; off <<= 1) {
        int t = (i >= off) ? tmp[i - off] : 0;
        __syncthreads();
        tmp[i] += t;
        __syncthreads();
    }
    if (i < NODE_BLKS) sums[i] = tmp[i] - v;
}

// rp += block offset; bucket cursors; dinv = rsqrt(1+deg)
__global__ void k_finish(const int* __restrict__ cnt, int* __restrict__ rp,
                         const int* __restrict__ sums, int* __restrict__ bcur,
                         float* __restrict__ dinv) {
    int i = blockIdx.x * 256 + threadIdx.x;
    if (i < N_NODES) {
        int r = rp[i] + sums[i >> 8];
        rp[i] = r;
        if ((i & 63) == 0) bcur[i >> 6] = r;   // bucket append cursor
        dinv[i] = rsqrtf(1.0f + (float)cnt[i]);
    }
    if (i == 0) rp[N_NODES] = N_EDGES;
}

// Phase A: append edges into per-bucket regions (cursor-local writes).
// payload packed: row (17 bits) | (col&63) << 17
__global__ void k_bucket(const int* __restrict__ erow, const int* __restrict__ ecol,
                         int* __restrict__ bcur, int* __restrict__ pairs) {
    int e = blockIdx.x * 256 + threadIdx.x;
    if (e < N_EDGES) {
        int r = erow[e], c = ecol[e];
        int pos = atomicAdd(&bcur[c >> 6], 1);
        pairs[pos] = r | ((c & 63) << 17);
    }
}

// Phase B: one block per bucket; exact placement via LDS cursors.
__global__ __launch_bounds__(256) void k_place(const int* __restrict__ rp,
                                               const int* __restrict__ pairs,
                                               int* __restrict__ eidx) {
    __shared__ int lcnt[64];
    int b = blockIdx.x;
    int n0 = b << 6;
    int t = threadIdx.x;
    int nEnd = (n0 + 64 < N_NODES) ? n0 + 64 : N_NODES;
    if (t < 64) lcnt[t] = (n0 + t < N_NODES) ? rp[n0 + t] : N_EDGES;
    __syncthreads();
    int beg = rp[n0], end = rp[nEnd];
    for (int i = beg + t; i < end; i += 256) {
        int p = pairs[i];
        int pos = atomicAdd(&lcnt[p >> 17], 1);
        eidx[pos] = p & 0x1FFFF;
    }
}

// -------- layer 0 GEMM: yh = fp16( dinv[row] * (x @ W0) ), 16 rows/block ----
__global__ __launch_bounds__(256) void k_gemm1(
    const float* __restrict__ x, const float* __restrict__ W0,
    const float* __restrict__ dinv, __half* __restrict__ yh) {
    __shared__ float Ws[N_FEAT][HIDDEN];   // 25600 B
    __shared__ float Xs[16][N_FEAT];       // 6400 B
    int tid = threadIdx.x;
    for (int i = tid; i < N_FEAT * HIDDEN; i += 256)
        Ws[i / HIDDEN][i % HIDDEN] = W0[i];
    int row0 = blockIdx.x * 16;
    for (int i = tid; i < 16 * N_FEAT; i += 256) {
        int r = i / N_FEAT, k = i - r * N_FEAT;
        int row = row0 + r;
        Xs[r][k] = (row < N_NODES) ? x[row * N_FEAT + k] : 0.0f;
    }
    __syncthreads();
    int c = tid & 63;
    int rb = (tid >> 6) * 4;
    float a0 = 0, a1 = 0, a2 = 0, a3 = 0;
    #pragma unroll 4
    for (int k = 0; k < N_FEAT; ++k) {
        float w = Ws[k][c];
        a0 += Xs[rb + 0][k] * w;
        a1 += Xs[rb + 1][k] * w;
        a2 += Xs[rb + 2][k] * w;
        a3 += Xs[rb + 3][k] * w;
    }
    int row = row0 + rb;
    if (row + 0 < N_NODES) yh[(row + 0) * HIDDEN + c] = __float2half(dinv[row + 0] * a0);
    if (row + 1 < N_NODES) yh[(row + 1) * HIDDEN + c] = __float2half(dinv[row + 1] * a1);
    if (row + 2 < N_NODES) yh[(row + 2) * HIDDEN + c] = __float2half(dinv[row + 2] * a2);
    if (row + 3 < N_NODES) yh[(row + 3) * HIDDEN + c] = __float2half(dinv[row + 3] * a3);
}

// -------- layer 0 aggregate: h[n] = dinv[n]*(yh[n] + sum yh[src]) + b0 ------
__global__ __launch_bounds__(256) void k_agg0(
    const int* __restrict__ rp, const int* __restrict__ eidx,
    const float* __restrict__ dinv, const __half* __restrict__ yh,
    const float* __restrict__ b0, float* __restrict__ h) {
    int n = (blockIdx.x * 256 + threadIdx.x) >> 6;
    int lane = threadIdx.x & 63;
    if (n >= N_NODES) return;
    int beg = rp[n], end = rp[n + 1];
    int deg = end - beg;
    int idx = beg + lane;
    int se = (idx < end) ? eidx[idx] : 0;   // coalesced edge-list preload
    float acc = __half2float(yh[n * HIDDEN + lane]);   // self loop
    int m = deg < 64 ? deg : 64;
    int j = 0;
    for (; j + 8 <= m; j += 8) {
        int s0 = __shfl(se, j + 0), s1 = __shfl(se, j + 1);
        int s2 = __shfl(se, j + 2), s3 = __shfl(se, j + 3);
        int s4 = __shfl(se, j + 4), s5 = __shfl(se, j + 5);
        int s6 = __shfl(se, j + 6), s7 = __shfl(se, j + 7);
        float v0 = __half2float(yh[s0 * HIDDEN + lane]);
        float v1 = __half2float(yh[s1 * HIDDEN + lane]);
        float v2 = __half2float(yh[s2 * HIDDEN + lane]);
        float v3 = __half2float(yh[s3 * HIDDEN + lane]);
        float v4 = __half2float(yh[s4 * HIDDEN + lane]);
        float v5 = __half2float(yh[s5 * HIDDEN + lane]);
        float v6 = __half2float(yh[s6 * HIDDEN + lane]);
        float v7 = __half2float(yh[s7 * HIDDEN + lane]);
        acc += ((v0 + v1) + (v2 + v3)) + ((v4 + v5) + (v6 + v7));
    }
    for (; j < m; ++j) {
        int s = __shfl(se, j);
        acc += __half2float(yh[s * HIDDEN + lane]);
    }
    if (deg > 64) {
        for (int e = beg + 64; e < end; ++e)
            acc += __half2float(yh[eidx[e] * HIDDEN + lane]);
    }
    h[n * HIDDEN + lane] = dinv[n] * acc + b0[lane];
}

// -------- layer 1 GEMM: zh = fp16( dinv[row] * (relu(h) @ W1) ), pad 48 -----
__global__ __launch_bounds__(256) void k_gemm2(
    const float* __restrict__ h, const float* __restrict__ W1,
    const float* __restrict__ dinv, __half* __restrict__ zh) {
    __shared__ float Ws[HIDDEN][ZPAD];   // 12288 B
    __shared__ float Hs[16][HIDDEN];     // 4096 B
    int tid = threadIdx.x;
    for (int i = tid; i < HIDDEN * N_CLASSES; i += 256) {
        int k = i / N_CLASSES, c = i - k * N_CLASSES;
        Ws[k][c] = W1[i];
    }
    int row0 = blockIdx.x * 16;
    for (int i = tid; i < 16 * HIDDEN; i += 256) {
        int r = i >> 6, k = i & 63;
        int row = row0 + r;
        Hs[r][k] = (row < N_NODES) ? fmaxf(h[row * HIDDEN + k], 0.0f) : 0.0f;
    }
    __syncthreads();
    int c = tid & 63;
    int rb = (tid >> 6) * 4;
    if (c < ZPAD) {
        float a0 = 0, a1 = 0, a2 = 0, a3 = 0;
        if (c < N_CLASSES) {
            #pragma unroll 4
            for (int k = 0; k < HIDDEN; ++k) {
                float w = Ws[k][c];
                a0 += Hs[rb + 0][k] * w;
                a1 += Hs[rb + 1][k] * w;
                a2 += Hs[rb + 2][k] * w;
                a3 += Hs[rb + 3][k] * w;
            }
        }
        int row = row0 + rb;
        if (row + 0 < N_NODES) zh[(row + 0) * ZPAD + c] = __float2half((c < N_CLASSES) ? dinv[row + 0] * a0 : 0.0f);
        if (row + 1 < N_NODES) zh[(row + 1) * ZPAD + c] = __float2half((c < N_CLASSES) ? dinv[row + 1] * a1 : 0.0f);
        if (row + 2 < N_NODES) zh[(row + 2) * ZPAD + c] = __float2half((c < N_CLASSES) ? dinv[row + 2] * a2 : 0.0f);
        if (row + 3 < N_NODES) zh[(row + 3) * ZPAD + c] = __float2half((c < N_CLASSES) ? dinv[row + 3] * a3 : 0.0f);
    }
}

// -------- layer 1 aggregate: out[n] = dinv[n]*(zh[n]+sum zh[src]) + b1 ------
__global__ __launch_bounds__(256) void k_agg1(
    const int* __restrict__ rp, const int* __restrict__ eidx,
    const float* __restrict__ dinv, const __half* __restrict__ zh,
    const float* __restrict__ b1, float* __restrict__ out) {
    int n = (blockIdx.x * 256 + threadIdx.x) >> 6;
    int lane = threadIdx.x & 63;
    if (n >= N_NODES) return;
    int beg = rp[n], end = rp[n + 1];
    int deg = end - beg;
    int idx = beg + lane;
    int se = (idx < end) ? eidx[idx] : 0;
    float acc = (lane < ZPAD) ? __half2float(zh[n * ZPAD + lane]) : 0.0f;
    int m = deg < 64 ? deg : 64;
    int j = 0;
    for (; j + 8 <= m; j += 8) {
        int s0 = __shfl(se, j + 0), s1 = __shfl(se, j + 1);
        int s2 = __shfl(se, j + 2), s3 = __shfl(se, j + 3);
        int s4 = __shfl(se, j + 4), s5 = __shfl(se, j + 5);
        int s6 = __shfl(se, j + 6), s7 = __shfl(se, j + 7);
        if (lane < ZPAD) {
            float v0 = __half2float(zh[s0 * ZPAD + lane]);
            float v1 = __half2float(zh[s1 * ZPAD + lane]);
            float v2 = __half2float(zh[s2 * ZPAD + lane]);
            float v3 = __half2float(zh[s3 * ZPAD + lane]);
            float v4 = __half2float(zh[s4 * ZPAD + lane]);
            float v5 = __half2float(zh[s5 * ZPAD + lane]);
            float v6 = __half2float(zh[s6 * ZPAD + lane]);
            float v7 = __half2float(zh[s7 * ZPAD + lane]);
            acc += ((v0 + v1) + (v2 + v3)) + ((v4 + v5) + (v6 + v7));
        }
    }
    for (; j < m; ++j) {
        int s = __shfl(se, j);
        if (lane < ZPAD) acc += __half2float(zh[s * ZPAD + lane]);
    }
    if (deg > 64) {
        for (int e = beg + 64; e < end; ++e) {
            int s = eidx[e];
            if (lane < ZPAD) acc += __half2float(zh[s * ZPAD + lane]);
        }
    }
    if (lane < N_CLASSES)
        out[n * N_CLASSES + lane] = dinv[n] * acc + b1[lane];
}

extern "C" void kernel_launch(void* const* d_in, const int* in_sizes, int n_in,
                              void* d_out, int out_size, void* d_ws, size_t ws_size,
                              hipStream_t stream) {
    const float* x  = (const float*)d_in[0];
    const int*   ei = (const int*)d_in[1];
    const float* W0 = (const float*)d_in[2];
    const float* b0 = (const float*)d_in[3];
    const float* W1 = (const float*)d_in[4];
    const float* b1 = (const float*)d_in[5];
    float* out = (float*)d_out;

    char* ws = (char*)d_ws;
    float*  dinv = (float*)(ws);                        // 400 KB
    int*    rp   = (int*)(ws + 412 * 1024);             // 400 KB + 4
    int*    bcur = (int*)(ws + 824 * 1024);             // 6.3 KB
    int*    cnt  = (int*)(ws + 836 * 1024);             // 400 KB
    int*    sums = (int*)(ws + 1248 * 1024);            // 2 KB
    int*    eidx = (int*)(ws + 1252 * 1024);            // 6.4 MB -> ends ~7.65 MB
    __half* yh   = (__half*)(ws + 8ull * 1024 * 1024);  // 12.8 MB -> ends ~20.8 MB
    float*  h    = (float*)(ws + 21ull * 1024 * 1024);  // 25.6 MB -> ends ~46.6 MB
    int*    pairs = (int*)h;   // 6.4 MB alias: dead before k_gemm1/agg0 write h
    __half* zh   = yh;         // reuse after agg0

    const int* erow = ei;             // edge_index[0] (sources)
    const int* ecol = ei + N_EDGES;   // edge_index[1] (destinations)

    k_zero  <<<NODE_BLKS, 256, 0, stream>>>(cnt);
    k_count <<<EDGE_BLKS, 256, 0, stream>>>(ecol, cnt);
    k_scan1 <<<NODE_BLKS, 256, 0, stream>>>(cnt, rp, sums);
    k_scan2 <<<1, 512, 0, stream>>>(sums);
    k_finish<<<NODE_BLKS, 256, 0, stream>>>(cnt, rp, sums, bcur, dinv);
    k_bucket<<<EDGE_BLKS, 256, 0, stream>>>(erow, ecol, bcur, pairs);
    k_place <<<NB, 256, 0, stream>>>(rp, pairs, eidx);

    k_gemm1<<<(N_NODES + 15) / 16, 256, 0, stream>>>(x, W0, dinv, yh);
    k_agg0 <<<(N_NODES * 64 + 255) / 256, 256, 0, stream>>>(rp, eidx, dinv, yh, b0, h);

    k_gemm2<<<(N_NODES + 15) / 16, 256, 0, stream>>>(h, W1, dinv, zh);
    k_agg1 <<<(N_NODES * 64 + 255) / 256, 256, 0, stream>>>(rp, eidx, dinv, zh, b1, out);
}

// Round 5
// 306.721 us; speedup vs baseline: 1.6864x; 1.6864x over previous
//
#include <hip/hip_runtime.h>
#include <hip/hip_fp16.h>

#define N_NODES   100000
#define N_EDGES   1600000
#define N_FEAT    100
#define HIDDEN    64
#define N_CLASSES 47
#define ZPAD      48
#define NODE_BLKS ((N_NODES + 255) / 256)   // 391
#define EDGE_BLKS ((N_EDGES + 255) / 256)   // 6250
#define NBIN      ((N_NODES + 511) / 512)   // 196 radix bins (dest >> 9)
#define SBLK      256                        // scatter blocks
#define CHUNK     (N_EDGES / SBLK)           // 6250 edges per scatter block
#define NHIST     (NBIN * SBLK)              // 50176 histogram entries

// ---------------- degree count ----------------

__global__ void k_zero(int* __restrict__ cnt) {
    int i = blockIdx.x * 256 + threadIdx.x;
    if (i < N_NODES) cnt[i] = 0;
}

__global__ void k_count(const int* __restrict__ ecol, int* __restrict__ cnt) {
    int e = blockIdx.x * 256 + threadIdx.x;
    if (e < N_EDGES) atomicAdd(&cnt[ecol[e]], 1);
}

// ---------------- generic 2-level exclusive scan ----------------

__global__ __launch_bounds__(256) void k_gscan1(const int* __restrict__ in,
                                                int* __restrict__ out,
                                                int* __restrict__ sums, int n) {
    __shared__ int tmp[256];
    int i = blockIdx.x * 256 + threadIdx.x;
    int v = (i < n) ? in[i] : 0;
    tmp[threadIdx.x] = v;
    __syncthreads();
    for (int off = 1; off < 256; off <<= 1) {
        int t = (threadIdx.x >= off) ? tmp[threadIdx.x - off] : 0;
        __syncthreads();
        tmp[threadIdx.x] += t;
        __syncthreads();
    }
    if (i < n) out[i] = tmp[threadIdx.x] - v;   // local exclusive
    if (threadIdx.x == 255) sums[blockIdx.x] = tmp[255];
}

__global__ __launch_bounds__(512) void k_gscan2(int* __restrict__ sums, int nb) {
    __shared__ int tmp[512];
    int i = threadIdx.x;
    int v = (i < nb) ? sums[i] : 0;
    tmp[i] = v;
    __syncthreads();
    for (int off = 1; off < 512; off <<= 1) {
        int t = (i >= off) ? tmp[i - off] : 0;
        __syncthreads();
        tmp[i] += t;
        __syncthreads();
    }
    if (i < nb) sums[i] = tmp[i] - v;   // exclusive
}

__global__ void k_hfix(int* __restrict__ out, const int* __restrict__ sums, int n) {
    int i = blockIdx.x * 256 + threadIdx.x;
    if (i < n) out[i] += sums[i >> 8];
}

// rp += block offset; dinv = rsqrt(1+deg)
__global__ void k_finish(const int* __restrict__ cnt, int* __restrict__ rp,
                         const int* __restrict__ sums, float* __restrict__ dinv) {
    int i = blockIdx.x * 256 + threadIdx.x;
    if (i < N_NODES) {
        rp[i] += sums[i >> 8];
        dinv[i] = rsqrtf(1.0f + (float)cnt[i]);
    }
    if (i == 0) rp[N_NODES] = N_EDGES;
}

// ---------------- radix pass: bin = dest >> 9 ----------------

// per-(block,bin) histogram, LDS-accumulated, laid out [bin][block]
__global__ __launch_bounds__(256) void k_hist(const int* __restrict__ ecol,
                                              int* __restrict__ gh) {
    __shared__ int lh[NBIN];
    int b = blockIdx.x, t = threadIdx.x;
    for (int i = t; i < NBIN; i += 256) lh[i] = 0;
    __syncthreads();
    int e0 = b * CHUNK;
    for (int i = t; i < CHUNK; i += 256)
        atomicAdd(&lh[ecol[e0 + i] >> 9], 1);
    __syncthreads();
    for (int i = t; i < NBIN; i += 256) gh[i * SBLK + b] = lh[i];
}

// scatter edges to bin-contiguous pairs[] using exact (block,bin) offsets
// payload: row (17 bits) | (dest & 511) << 17
__global__ __launch_bounds__(256) void k_radix_scatter(
    const int* __restrict__ erow, const int* __restrict__ ecol,
    const int* __restrict__ gpos, int* __restrict__ pairs) {
    __shared__ int lc[NBIN];
    int b = blockIdx.x, t = threadIdx.x;
    for (int i = t; i < NBIN; i += 256) lc[i] = gpos[i * SBLK + b];
    __syncthreads();
    int e0 = b * CHUNK;
    for (int i = t; i < CHUNK; i += 256) {
        int e = e0 + i;
        int r = erow[e], c = ecol[e];
        int pos = atomicAdd(&lc[c >> 9], 1);
        pairs[pos] = r | ((c & 511) << 17);
    }
}

// one block per bin: exact per-node placement via 512 LDS cursors
__global__ __launch_bounds__(512) void k_place2(const int* __restrict__ rp,
                                                const int* __restrict__ pairs,
                                                int* __restrict__ eidx) {
    __shared__ int lcnt[512];
    int b = blockIdx.x, t = threadIdx.x;
    int n0 = b << 9;
    int nEnd = (n0 + 512 < N_NODES) ? n0 + 512 : N_NODES;
    lcnt[t] = (n0 + t < N_NODES) ? rp[n0 + t] : N_EDGES;
    __syncthreads();
    int beg = rp[n0], end = rp[nEnd];
    for (int i = beg + t; i < end; i += 512) {
        int p = pairs[i];
        int pos = atomicAdd(&lcnt[(p >> 17) & 511], 1);
        eidx[pos] = p & 0x1FFFF;
    }
}

// -------- layer 0 GEMM: yh = fp16( dinv[row] * (x @ W0) ), 16 rows/block ----
__global__ __launch_bounds__(256) void k_gemm1(
    const float* __restrict__ x, const float* __restrict__ W0,
    const float* __restrict__ dinv, __half* __restrict__ yh) {
    __shared__ float Ws[N_FEAT][HIDDEN];   // 25600 B
    __shared__ float Xs[16][N_FEAT];       // 6400 B
    int tid = threadIdx.x;
    for (int i = tid; i < N_FEAT * HIDDEN; i += 256)
        Ws[i / HIDDEN][i % HIDDEN] = W0[i];
    int row0 = blockIdx.x * 16;
    for (int i = tid; i < 16 * N_FEAT; i += 256) {
        int r = i / N_FEAT, k = i - r * N_FEAT;
        int row = row0 + r;
        Xs[r][k] = (row < N_NODES) ? x[row * N_FEAT + k] : 0.0f;
    }
    __syncthreads();
    int c = tid & 63;
    int rb = (tid >> 6) * 4;
    float a0 = 0, a1 = 0, a2 = 0, a3 = 0;
    #pragma unroll 4
    for (int k = 0; k < N_FEAT; ++k) {
        float w = Ws[k][c];
        a0 += Xs[rb + 0][k] * w;
        a1 += Xs[rb + 1][k] * w;
        a2 += Xs[rb + 2][k] * w;
        a3 += Xs[rb + 3][k] * w;
    }
    int row = row0 + rb;
    if (row + 0 < N_NODES) yh[(row + 0) * HIDDEN + c] = __float2half(dinv[row + 0] * a0);
    if (row + 1 < N_NODES) yh[(row + 1) * HIDDEN + c] = __float2half(dinv[row + 1] * a1);
    if (row + 2 < N_NODES) yh[(row + 2) * HIDDEN + c] = __float2half(dinv[row + 2] * a2);
    if (row + 3 < N_NODES) yh[(row + 3) * HIDDEN + c] = __float2half(dinv[row + 3] * a3);
}

// -------- layer 0 aggregate: h[n] = dinv[n]*(yh[n] + sum yh[src]) + b0 ------
__global__ __launch_bounds__(256) void k_agg0(
    const int* __restrict__ rp, const int* __restrict__ eidx,
    const float* __restrict__ dinv, const __half* __restrict__ yh,
    const float* __restrict__ b0, float* __restrict__ h) {
    int n = (blockIdx.x * 256 + threadIdx.x) >> 6;
    int lane = threadIdx.x & 63;
    if (n >= N_NODES) return;
    int beg = rp[n], end = rp[n + 1];
    int deg = end - beg;
    int idx = beg + lane;
    int se = (idx < end) ? eidx[idx] : 0;   // coalesced edge-list preload
    float acc = __half2float(yh[n * HIDDEN + lane]);   // self loop
    int m = deg < 64 ? deg : 64;
    int j = 0;
    for (; j + 8 <= m; j += 8) {
        int s0 = __shfl(se, j + 0), s1 = __shfl(se, j + 1);
        int s2 = __shfl(se, j + 2), s3 = __shfl(se, j + 3);
        int s4 = __shfl(se, j + 4), s5 = __shfl(se, j + 5);
        int s6 = __shfl(se, j + 6), s7 = __shfl(se, j + 7);
        float v0 = __half2float(yh[s0 * HIDDEN + lane]);
        float v1 = __half2float(yh[s1 * HIDDEN + lane]);
        float v2 = __half2float(yh[s2 * HIDDEN + lane]);
        float v3 = __half2float(yh[s3 * HIDDEN + lane]);
        float v4 = __half2float(yh[s4 * HIDDEN + lane]);
        float v5 = __half2float(yh[s5 * HIDDEN + lane]);
        float v6 = __half2float(yh[s6 * HIDDEN + lane]);
        float v7 = __half2float(yh[s7 * HIDDEN + lane]);
        acc += ((v0 + v1) + (v2 + v3)) + ((v4 + v5) + (v6 + v7));
    }
    for (; j < m; ++j) {
        int s = __shfl(se, j);
        acc += __half2float(yh[s * HIDDEN + lane]);
    }
    if (deg > 64) {
        for (int e = beg + 64; e < end; ++e)
            acc += __half2float(yh[eidx[e] * HIDDEN + lane]);
    }
    h[n * HIDDEN + lane] = dinv[n] * acc + b0[lane];
}

// -------- layer 1 GEMM: zh = fp16( dinv[row] * (relu(h) @ W1) ), pad 48 -----
__global__ __launch_bounds__(256) void k_gemm2(
    const float* __restrict__ h, const float* __restrict__ W1,
    const float* __restrict__ dinv, __half* __restrict__ zh) {
    __shared__ float Ws[HIDDEN][ZPAD];   // 12288 B
    __shared__ float Hs[16][HIDDEN];     // 4096 B
    int tid = threadIdx.x;
    for (int i = tid; i < HIDDEN * N_CLASSES; i += 256) {
        int k = i / N_CLASSES, c = i - k * N_CLASSES;
        Ws[k][c] = W1[i];
    }
    int row0 = blockIdx.x * 16;
    for (int i = tid; i < 16 * HIDDEN; i += 256) {
        int r = i >> 6, k = i & 63;
        int row = row0 + r;
        Hs[r][k] = (row < N_NODES) ? fmaxf(h[row * HIDDEN + k], 0.0f) : 0.0f;
    }
    __syncthreads();
    int c = tid & 63;
    int rb = (tid >> 6) * 4;
    if (c < ZPAD) {
        float a0 = 0, a1 = 0, a2 = 0, a3 = 0;
        if (c < N_CLASSES) {
            #pragma unroll 4
            for (int k = 0; k < HIDDEN; ++k) {
                float w = Ws[k][c];
                a0 += Hs[rb + 0][k] * w;
                a1 += Hs[rb + 1][k] * w;
                a2 += Hs[rb + 2][k] * w;
                a3 += Hs[rb + 3][k] * w;
            }
        }
        int row = row0 + rb;
        if (row + 0 < N_NODES) zh[(row + 0) * ZPAD + c] = __float2half((c < N_CLASSES) ? dinv[row + 0] * a0 : 0.0f);
        if (row + 1 < N_NODES) zh[(row + 1) * ZPAD + c] = __float2half((c < N_CLASSES) ? dinv[row + 1] * a1 : 0.0f);
        if (row + 2 < N_NODES) zh[(row + 2) * ZPAD + c] = __float2half((c < N_CLASSES) ? dinv[row + 2] * a2 : 0.0f);
        if (row + 3 < N_NODES) zh[(row + 3) * ZPAD + c] = __float2half((c < N_CLASSES) ? dinv[row + 3] * a3 : 0.0f);
    }
}

// -------- layer 1 aggregate: out[n] = dinv[n]*(zh[n]+sum zh[src]) + b1 ------
__global__ __launch_bounds__(256) void k_agg1(
    const int* __restrict__ rp, const int* __restrict__ eidx,
    const float* __restrict__ dinv, const __half* __restrict__ zh,
    const float* __restrict__ b1, float* __restrict__ out) {
    int n = (blockIdx.x * 256 + threadIdx.x) >> 6;
    int lane = threadIdx.x & 63;
    if (n >= N_NODES) return;
    int beg = rp[n], end = rp[n + 1];
    int deg = end - beg;
    int idx = beg + lane;
    int se = (idx < end) ? eidx[idx] : 0;
    float acc = (lane < ZPAD) ? __half2float(zh[n * ZPAD + lane]) : 0.0f;
    int m = deg < 64 ? deg : 64;
    int j = 0;
    for (; j + 8 <= m; j += 8) {
        int s0 = __shfl(se, j + 0), s1 = __shfl(se, j + 1);
        int s2 = __shfl(se, j + 2), s3 = __shfl(se, j + 3);
        int s4 = __shfl(se, j + 4), s5 = __shfl(se, j + 5);
        int s6 = __shfl(se, j + 6), s7 = __shfl(se, j + 7);
        if (lane < ZPAD) {
            float v0 = __half2float(zh[s0 * ZPAD + lane]);
            float v1 = __half2float(zh[s1 * ZPAD + lane]);
            float v2 = __half2float(zh[s2 * ZPAD + lane]);
            float v3 = __half2float(zh[s3 * ZPAD + lane]);
            float v4 = __half2float(zh[s4 * ZPAD + lane]);
            float v5 = __half2float(zh[s5 * ZPAD + lane]);
            float v6 = __half2float(zh[s6 * ZPAD + lane]);
            float v7 = __half2float(zh[s7 * ZPAD + lane]);
            acc += ((v0 + v1) + (v2 + v3)) + ((v4 + v5) + (v6 + v7));
        }
    }
    for (; j < m; ++j) {
        int s = __shfl(se, j);
        if (lane < ZPAD) acc += __half2float(zh[s * ZPAD + lane]);
    }
    if (deg > 64) {
        for (int e = beg + 64; e < end; ++e) {
            int s = eidx[e];
            if (lane < ZPAD) acc += __half2float(zh[s * ZPAD + lane]);
        }
    }
    if (lane < N_CLASSES)
        out[n * N_CLASSES + lane] = dinv[n] * acc + b1[lane];
}

extern "C" void kernel_launch(void* const* d_in, const int* in_sizes, int n_in,
                              void* d_out, int out_size, void* d_ws, size_t ws_size,
                              hipStream_t stream) {
    const float* x  = (const float*)d_in[0];
    const int*   ei = (const int*)d_in[1];
    const float* W0 = (const float*)d_in[2];
    const float* b0 = (const float*)d_in[3];
    const float* W1 = (const float*)d_in[4];
    const float* b1 = (const float*)d_in[5];
    float* out = (float*)d_out;

    char* ws = (char*)d_ws;
    float*  dinv  = (float*)(ws);                         // 400 KB
    int*    rp    = (int*)(ws + 412 * 1024);              // 400 KB + 4
    int*    cnt   = (int*)(ws + 824 * 1024);              // 400 KB
    int*    sums  = (int*)(ws + 1236 * 1024);             // 2 KB
    int*    hsums = (int*)(ws + 1240 * 1024);             // 1 KB
    int*    gh    = (int*)(ws + 1244 * 1024);             // 196 KB
    int*    gpos  = (int*)(ws + 1444 * 1024);             // 196 KB
    int*    eidx  = (int*)(ws + 1664 * 1024);             // 6.4 MB -> ends ~8.06 MB
    __half* yh    = (__half*)(ws + 9ull * 1024 * 1024);   // 12.8 MB -> ends ~21.8 MB
    float*  h     = (float*)(ws + 22ull * 1024 * 1024);   // 25.6 MB -> ends ~47.6 MB
    int*    pairs = (int*)h;   // 6.4 MB alias: dead before k_agg0 writes h
    __half* zh    = yh;        // reuse after agg0

    const int* erow = ei;             // edge_index[0] (sources)
    const int* ecol = ei + N_EDGES;   // edge_index[1] (destinations)

    // per-node degree + row pointers
    k_zero  <<<NODE_BLKS, 256, 0, stream>>>(cnt);
    k_count <<<EDGE_BLKS, 256, 0, stream>>>(ecol, cnt);
    k_gscan1<<<NODE_BLKS, 256, 0, stream>>>(cnt, rp, sums, N_NODES);
    k_gscan2<<<1, 512, 0, stream>>>(sums, NODE_BLKS);
    k_finish<<<NODE_BLKS, 256, 0, stream>>>(cnt, rp, sums, dinv);

    // radix pass: hist -> scan -> scatter -> exact placement
    k_hist  <<<SBLK, 256, 0, stream>>>(ecol, gh);
    k_gscan1<<<(NHIST + 255) / 256, 256, 0, stream>>>(gh, gpos, hsums, NHIST);
    k_gscan2<<<1, 512, 0, stream>>>(hsums, (NHIST + 255) / 256);
    k_hfix  <<<(NHIST + 255) / 256, 256, 0, stream>>>(gpos, hsums, NHIST);
    k_radix_scatter<<<SBLK, 256, 0, stream>>>(erow, ecol, gpos, pairs);
    k_place2<<<NBIN, 512, 0, stream>>>(rp, pairs, eidx);

    // layer 0
    k_gemm1<<<(N_NODES + 15) / 16, 256, 0, stream>>>(x, W0, dinv, yh);
    k_agg0 <<<(N_NODES * 64 + 255) / 256, 256, 0, stream>>>(rp, eidx, dinv, yh, b0, h);

    // layer 1
    k_gemm2<<<(N_NODES + 15) / 16, 256, 0, stream>>>(h, W1, dinv, zh);
    k_agg1 <<<(N_NODES * 64 + 255) / 256, 256, 0, stream>>>(rp, eidx, dinv, zh, b1, out);
}

// Round 6
// 233.603 us; speedup vs baseline: 2.2142x; 1.3130x over previous
//
#include <hip/hip_runtime.h>
#include <hip/hip_fp16.h>

#define N_NODES   100000
#define N_EDGES   1600000
#define N_FEAT    100
#define HIDDEN    64
#define N_CLASSES 47
#define ZPAD      48
#define NBIN      ((N_NODES + 511) / 512)   // 196 radix bins (dest >> 9)
#define SBLK      256                        // scatter blocks
#define CHUNK     (N_EDGES / SBLK)           // 6250 edges per scatter block
#define NHIST     (NBIN * SBLK)              // 50176 histogram entries

// ---------------- generic 2-level exclusive scan (for bin histogram) -------

__global__ __launch_bounds__(256) void k_gscan1(const int* __restrict__ in,
                                                int* __restrict__ out,
                                                int* __restrict__ sums, int n) {
    __shared__ int tmp[256];
    int i = blockIdx.x * 256 + threadIdx.x;
    int v = (i < n) ? in[i] : 0;
    tmp[threadIdx.x] = v;
    __syncthreads();
    for (int off = 1; off < 256; off <<= 1) {
        int t = (threadIdx.x >= off) ? tmp[threadIdx.x - off] : 0;
        __syncthreads();
        tmp[threadIdx.x] += t;
        __syncthreads();
    }
    if (i < n) out[i] = tmp[threadIdx.x] - v;   // local exclusive
    if (threadIdx.x == 255) sums[blockIdx.x] = tmp[255];
}

__global__ __launch_bounds__(512) void k_gscan2(int* __restrict__ sums, int nb) {
    __shared__ int tmp[512];
    int i = threadIdx.x;
    int v = (i < nb) ? sums[i] : 0;
    tmp[i] = v;
    __syncthreads();
    for (int off = 1; off < 512; off <<= 1) {
        int t = (i >= off) ? tmp[i - off] : 0;
        __syncthreads();
        tmp[i] += t;
        __syncthreads();
    }
    if (i < nb) sums[i] = tmp[i] - v;   // exclusive
}

__global__ void k_hfix(int* __restrict__ out, const int* __restrict__ sums, int n) {
    int i = blockIdx.x * 256 + threadIdx.x;
    if (i < n) out[i] += sums[i >> 8];
}

// ---------------- radix pass: bin = dest >> 9 ----------------

// per-(block,bin) histogram, LDS-accumulated, laid out [bin][block]
__global__ __launch_bounds__(256) void k_hist(const int* __restrict__ ecol,
                                              int* __restrict__ gh) {
    __shared__ int lh[NBIN];
    int b = blockIdx.x, t = threadIdx.x;
    for (int i = t; i < NBIN; i += 256) lh[i] = 0;
    __syncthreads();
    int e0 = b * CHUNK;
    for (int i = t; i < CHUNK; i += 256)
        atomicAdd(&lh[ecol[e0 + i] >> 9], 1);
    __syncthreads();
    for (int i = t; i < NBIN; i += 256) gh[i * SBLK + b] = lh[i];
}

// scatter edges to bin-contiguous pairs[] using exact (block,bin) offsets
// payload: row (17 bits) | (dest & 511) << 17
__global__ __launch_bounds__(256) void k_radix_scatter(
    const int* __restrict__ erow, const int* __restrict__ ecol,
    const int* __restrict__ gpos, int* __restrict__ pairs) {
    __shared__ int lc[NBIN];
    int b = blockIdx.x, t = threadIdx.x;
    for (int i = t; i < NBIN; i += 256) lc[i] = gpos[i * SBLK + b];
    __syncthreads();
    int e0 = b * CHUNK;
    for (int i = t; i < CHUNK; i += 256) {
        int e = e0 + i;
        int r = erow[e], c = ecol[e];
        int pos = atomicAdd(&lc[c >> 9], 1);
        pairs[pos] = r | ((c & 511) << 17);
    }
}

// one block per bin: per-node degree (LDS hist) -> LDS scan -> rp/dinv ->
// exact placement of eidx. Fuses old k_count/k_zero/node-scan/k_finish/k_place2.
__global__ __launch_bounds__(512) void k_binfinish(
    const int* __restrict__ gpos, const int* __restrict__ pairs,
    int* __restrict__ rp, float* __restrict__ dinv, int* __restrict__ eidx) {
    __shared__ int cnt[512];
    __shared__ int tmp[512];
    int b = blockIdx.x, t = threadIdx.x;
    int n0 = b << 9;
    int beg = gpos[b * SBLK];
    int end = (b + 1 < NBIN) ? gpos[(b + 1) * SBLK] : N_EDGES;

    cnt[t] = 0;
    __syncthreads();
    // pass A: per-node degree within the bin
    for (int i = beg + t; i < end; i += 512)
        atomicAdd(&cnt[(pairs[i] >> 17) & 511], 1);
    __syncthreads();
    // LDS inclusive scan (Hillis-Steele), then exclusive via -v
    int v = cnt[t];
    tmp[t] = v;
    __syncthreads();
    for (int off = 1; off < 512; off <<= 1) {
        int u = (t >= off) ? tmp[t - off] : 0;
        __syncthreads();
        tmp[t] += u;
        __syncthreads();
    }
    int rpv = beg + tmp[t] - v;   // row pointer for node n0+t
    int n = n0 + t;
    if (n < N_NODES) {
        rp[n] = rpv;
        dinv[n] = rsqrtf(1.0f + (float)v);
    }
    if (b == NBIN - 1 && t == 0) rp[N_NODES] = N_EDGES;
    cnt[t] = rpv;                 // reuse as placement cursor
    __syncthreads();
    // pass B: exact placement
    for (int i = beg + t; i < end; i += 512) {
        int p = pairs[i];
        int pos = atomicAdd(&cnt[(p >> 17) & 511], 1);
        eidx[pos] = p & 0x1FFFF;
    }
}

// -------- layer 0 GEMM: yh = fp16( dinv[row] * (x @ W0) ), 16 rows/block ----
__global__ __launch_bounds__(256) void k_gemm1(
    const float* __restrict__ x, const float* __restrict__ W0,
    const float* __restrict__ dinv, __half* __restrict__ yh) {
    __shared__ float Ws[N_FEAT][HIDDEN];   // 25600 B
    __shared__ float Xs[16][N_FEAT];       // 6400 B
    int tid = threadIdx.x;
    for (int i = tid; i < N_FEAT * HIDDEN; i += 256)
        Ws[i / HIDDEN][i % HIDDEN] = W0[i];
    int row0 = blockIdx.x * 16;
    for (int i = tid; i < 16 * N_FEAT; i += 256) {
        int r = i / N_FEAT, k = i - r * N_FEAT;
        int row = row0 + r;
        Xs[r][k] = (row < N_NODES) ? x[row * N_FEAT + k] : 0.0f;
    }
    __syncthreads();
    int c = tid & 63;
    int rb = (tid >> 6) * 4;
    float a0 = 0, a1 = 0, a2 = 0, a3 = 0;
    #pragma unroll 4
    for (int k = 0; k < N_FEAT; ++k) {
        float w = Ws[k][c];
        a0 += Xs[rb + 0][k] * w;
        a1 += Xs[rb + 1][k] * w;
        a2 += Xs[rb + 2][k] * w;
        a3 += Xs[rb + 3][k] * w;
    }
    int row = row0 + rb;
    if (row + 0 < N_NODES) yh[(row + 0) * HIDDEN + c] = __float2half(dinv[row + 0] * a0);
    if (row + 1 < N_NODES) yh[(row + 1) * HIDDEN + c] = __float2half(dinv[row + 1] * a1);
    if (row + 2 < N_NODES) yh[(row + 2) * HIDDEN + c] = __float2half(dinv[row + 2] * a2);
    if (row + 3 < N_NODES) yh[(row + 3) * HIDDEN + c] = __float2half(dinv[row + 3] * a3);
}

// -------- layer 0 aggregate: h[n] = dinv[n]*(yh[n] + sum yh[src]) + b0 ------
__global__ __launch_bounds__(256) void k_agg0(
    const int* __restrict__ rp, const int* __restrict__ eidx,
    const float* __restrict__ dinv, const __half* __restrict__ yh,
    const float* __restrict__ b0, float* __restrict__ h) {
    int n = (blockIdx.x * 256 + threadIdx.x) >> 6;
    int lane = threadIdx.x & 63;
    if (n >= N_NODES) return;
    int beg = rp[n], end = rp[n + 1];
    int deg = end - beg;
    int idx = beg + lane;
    int se = (idx < end) ? eidx[idx] : 0;   // coalesced edge-list preload
    float acc = __half2float(yh[n * HIDDEN + lane]);   // self loop
    int m = deg < 64 ? deg : 64;
    int j = 0;
    for (; j + 8 <= m; j += 8) {
        int s0 = __shfl(se, j + 0), s1 = __shfl(se, j + 1);
        int s2 = __shfl(se, j + 2), s3 = __shfl(se, j + 3);
        int s4 = __shfl(se, j + 4), s5 = __shfl(se, j + 5);
        int s6 = __shfl(se, j + 6), s7 = __shfl(se, j + 7);
        float v0 = __half2float(yh[s0 * HIDDEN + lane]);
        float v1 = __half2float(yh[s1 * HIDDEN + lane]);
        float v2 = __half2float(yh[s2 * HIDDEN + lane]);
        float v3 = __half2float(yh[s3 * HIDDEN + lane]);
        float v4 = __half2float(yh[s4 * HIDDEN + lane]);
        float v5 = __half2float(yh[s5 * HIDDEN + lane]);
        float v6 = __half2float(yh[s6 * HIDDEN + lane]);
        float v7 = __half2float(yh[s7 * HIDDEN + lane]);
        acc += ((v0 + v1) + (v2 + v3)) + ((v4 + v5) + (v6 + v7));
    }
    for (; j < m; ++j) {
        int s = __shfl(se, j);
        acc += __half2float(yh[s * HIDDEN + lane]);
    }
    if (deg > 64) {
        for (int e = beg + 64; e < end; ++e)
            acc += __half2float(yh[eidx[e] * HIDDEN + lane]);
    }
    h[n * HIDDEN + lane] = dinv[n] * acc + b0[lane];
}

// -------- layer 1 GEMM: zh = fp16( dinv[row] * (relu(h) @ W1) ), pad 48 -----
__global__ __launch_bounds__(256) void k_gemm2(
    const float* __restrict__ h, const float* __restrict__ W1,
    const float* __restrict__ dinv, __half* __restrict__ zh) {
    __shared__ float Ws[HIDDEN][ZPAD];   // 12288 B
    __shared__ float Hs[16][HIDDEN];     // 4096 B
    int tid = threadIdx.x;
    for (int i = tid; i < HIDDEN * N_CLASSES; i += 256) {
        int k = i / N_CLASSES, c = i - k * N_CLASSES;
        Ws[k][c] = W1[i];
    }
    int row0 = blockIdx.x * 16;
    for (int i = tid; i < 16 * HIDDEN; i += 256) {
        int r = i >> 6, k = i & 63;
        int row = row0 + r;
        Hs[r][k] = (row < N_NODES) ? fmaxf(h[row * HIDDEN + k], 0.0f) : 0.0f;
    }
    __syncthreads();
    int c = tid & 63;
    int rb = (tid >> 6) * 4;
    if (c < ZPAD) {
        float a0 = 0, a1 = 0, a2 = 0, a3 = 0;
        if (c < N_CLASSES) {
            #pragma unroll 4
            for (int k = 0; k < HIDDEN; ++k) {
                float w = Ws[k][c];
                a0 += Hs[rb + 0][k] * w;
                a1 += Hs[rb + 1][k] * w;
                a2 += Hs[rb + 2][k] * w;
                a3 += Hs[rb + 3][k] * w;
            }
        }
        int row = row0 + rb;
        if (row + 0 < N_NODES) zh[(row + 0) * ZPAD + c] = __float2half((c < N_CLASSES) ? dinv[row + 0] * a0 : 0.0f);
        if (row + 1 < N_NODES) zh[(row + 1) * ZPAD + c] = __float2half((c < N_CLASSES) ? dinv[row + 1] * a1 : 0.0f);
        if (row + 2 < N_NODES) zh[(row + 2) * ZPAD + c] = __float2half((c < N_CLASSES) ? dinv[row + 2] * a2 : 0.0f);
        if (row + 3 < N_NODES) zh[(row + 3) * ZPAD + c] = __float2half((c < N_CLASSES) ? dinv[row + 3] * a3 : 0.0f);
    }
}

// -------- layer 1 aggregate: out[n] = dinv[n]*(zh[n]+sum zh[src]) + b1 ------
__global__ __launch_bounds__(256) void k_agg1(
    const int* __restrict__ rp, const int* __restrict__ eidx,
    const float* __restrict__ dinv, const __half* __restrict__ zh,
    const float* __restrict__ b1, float* __restrict__ out) {
    int n = (blockIdx.x * 256 + threadIdx.x) >> 6;
    int lane = threadIdx.x & 63;
    if (n >= N_NODES) return;
    int beg = rp[n], end = rp[n + 1];
    int deg = end - beg;
    int idx = beg + lane;
    int se = (idx < end) ? eidx[idx] : 0;
    float acc = (lane < ZPAD) ? __half2float(zh[n * ZPAD + lane]) : 0.0f;
    int m = deg < 64 ? deg : 64;
    int j = 0;
    for (; j + 8 <= m; j += 8) {
        int s0 = __shfl(se, j + 0), s1 = __shfl(se, j + 1);
        int s2 = __shfl(se, j + 2), s3 = __shfl(se, j + 3);
        int s4 = __shfl(se, j + 4), s5 = __shfl(se, j + 5);
        int s6 = __shfl(se, j + 6), s7 = __shfl(se, j + 7);
        if (lane < ZPAD) {
            float v0 = __half2float(zh[s0 * ZPAD + lane]);
            float v1 = __half2float(zh[s1 * ZPAD + lane]);
            float v2 = __half2float(zh[s2 * ZPAD + lane]);
            float v3 = __half2float(zh[s3 * ZPAD + lane]);
            float v4 = __half2float(zh[s4 * ZPAD + lane]);
            float v5 = __half2float(zh[s5 * ZPAD + lane]);
            float v6 = __half2float(zh[s6 * ZPAD + lane]);
            float v7 = __half2float(zh[s7 * ZPAD + lane]);
            acc += ((v0 + v1) + (v2 + v3)) + ((v4 + v5) + (v6 + v7));
        }
    }
    for (; j < m; ++j) {
        int s = __shfl(se, j);
        if (lane < ZPAD) acc += __half2float(zh[s * ZPAD + lane]);
    }
    if (deg > 64) {
        for (int e = beg + 64; e < end; ++e) {
            int s = eidx[e];
            if (lane < ZPAD) acc += __half2float(zh[s * ZPAD + lane]);
        }
    }
    if (lane < N_CLASSES)
        out[n * N_CLASSES + lane] = dinv[n] * acc + b1[lane];
}

extern "C" void kernel_launch(void* const* d_in, const int* in_sizes, int n_in,
                              void* d_out, int out_size, void* d_ws, size_t ws_size,
                              hipStream_t stream) {
    const float* x  = (const float*)d_in[0];
    const int*   ei = (const int*)d_in[1];
    const float* W0 = (const float*)d_in[2];
    const float* b0 = (const float*)d_in[3];
    const float* W1 = (const float*)d_in[4];
    const float* b1 = (const float*)d_in[5];
    float* out = (float*)d_out;

    char* ws = (char*)d_ws;
    float*  dinv  = (float*)(ws);                         // 400 KB
    int*    rp    = (int*)(ws + 412 * 1024);              // 400 KB + 4
    int*    hsums = (int*)(ws + 824 * 1024);              // 1 KB
    int*    gh    = (int*)(ws + 828 * 1024);              // 196 KB
    int*    gpos  = (int*)(ws + 1028 * 1024);             // 196 KB
    int*    eidx  = (int*)(ws + 1228 * 1024);             // 6.4 MB -> ends ~7.6 MB
    __half* yh    = (__half*)(ws + 8ull * 1024 * 1024);   // 12.8 MB -> ends ~20.8 MB
    float*  h     = (float*)(ws + 21ull * 1024 * 1024);   // 25.6 MB -> ends ~46.6 MB
    int*    pairs = (int*)h;   // 6.4 MB alias: dead before k_agg0 writes h
    __half* zh    = yh;        // reuse after agg0

    const int* erow = ei;             // edge_index[0] (sources)
    const int* ecol = ei + N_EDGES;   // edge_index[1] (destinations)

    // radix pass: bin histogram -> scan -> scatter -> fused degree+rp+place
    k_hist  <<<SBLK, 256, 0, stream>>>(ecol, gh);
    k_gscan1<<<(NHIST + 255) / 256, 256, 0, stream>>>(gh, gpos, hsums, NHIST);
    k_gscan2<<<1, 512, 0, stream>>>(hsums, (NHIST + 255) / 256);
    k_hfix  <<<(NHIST + 255) / 256, 256, 0, stream>>>(gpos, hsums, NHIST);
    k_radix_scatter<<<SBLK, 256, 0, stream>>>(erow, ecol, gpos, pairs);
    k_binfinish<<<NBIN, 512, 0, stream>>>(gpos, pairs, rp, dinv, eidx);

    // layer 0
    k_gemm1<<<(N_NODES + 15) / 16, 256, 0, stream>>>(x, W0, dinv, yh);
    k_agg0 <<<(N_NODES * 64 + 255) / 256, 256, 0, stream>>>(rp, eidx, dinv, yh, b0, h);

    // layer 1
    k_gemm2<<<(N_NODES + 15) / 16, 256, 0, stream>>>(h, W1, dinv, zh);
    k_agg1 <<<(N_NODES * 64 + 255) / 256, 256, 0, stream>>>(rp, eidx, dinv, zh, b1, out);
}

// Round 8
// 206.156 us; speedup vs baseline: 2.5090x; 1.1331x over previous
//
#include <hip/hip_runtime.h>
#include <hip/hip_fp16.h>

#define N_NODES   100000
#define N_EDGES   1600000
#define N_FEAT    100
#define HIDDEN    64
#define N_CLASSES 47
#define ZPAD      48
#define NBIN      ((N_NODES + 511) / 512)   // 196 radix bins (dest >> 9)
#define SBLK      256                        // scatter blocks
#define CHUNK     (N_EDGES / SBLK)           // 6250 edges per scatter block
#define NHIST     (NBIN * SBLK)              // 50176 histogram entries

typedef _Float16 f16x8 __attribute__((ext_vector_type(8)));
typedef float f32x4 __attribute__((ext_vector_type(4)));

// ---------------- generic 2-level exclusive scan (for bin histogram) -------

__global__ __launch_bounds__(256) void k_gscan1(const int* __restrict__ in,
                                                int* __restrict__ out,
                                                int* __restrict__ sums, int n) {
    __shared__ int tmp[256];
    int i = blockIdx.x * 256 + threadIdx.x;
    int v = (i < n) ? in[i] : 0;
    tmp[threadIdx.x] = v;
    __syncthreads();
    for (int off = 1; off < 256; off <<= 1) {
        int t = (threadIdx.x >= off) ? tmp[threadIdx.x - off] : 0;
        __syncthreads();
        tmp[threadIdx.x] += t;
        __syncthreads();
    }
    if (i < n) out[i] = tmp[threadIdx.x] - v;
    if (threadIdx.x == 255) sums[blockIdx.x] = tmp[255];
}

__global__ __launch_bounds__(512) void k_gscan2(int* __restrict__ sums, int nb) {
    __shared__ int tmp[512];
    int i = threadIdx.x;
    int v = (i < nb) ? sums[i] : 0;
    tmp[i] = v;
    __syncthreads();
    for (int off = 1; off < 512; off <<= 1) {
        int t = (i >= off) ? tmp[i - off] : 0;
        __syncthreads();
        tmp[i] += t;
        __syncthreads();
    }
    if (i < nb) sums[i] = tmp[i] - v;
}

__global__ void k_hfix(int* __restrict__ out, const int* __restrict__ sums, int n) {
    int i = blockIdx.x * 256 + threadIdx.x;
    if (i < n) out[i] += sums[i >> 8];
}

// ---------------- radix pass: bin = dest >> 9 ----------------

__global__ __launch_bounds__(256) void k_hist(const int* __restrict__ ecol,
                                              int* __restrict__ gh) {
    __shared__ int lh[NBIN];
    int b = blockIdx.x, t = threadIdx.x;
    for (int i = t; i < NBIN; i += 256) lh[i] = 0;
    __syncthreads();
    int e0 = b * CHUNK;
    for (int i = t; i < CHUNK; i += 256)
        atomicAdd(&lh[ecol[e0 + i] >> 9], 1);
    __syncthreads();
    for (int i = t; i < NBIN; i += 256) gh[i * SBLK + b] = lh[i];
}

__global__ __launch_bounds__(256) void k_radix_scatter(
    const int* __restrict__ erow, const int* __restrict__ ecol,
    const int* __restrict__ gpos, int* __restrict__ pairs) {
    __shared__ int lc[NBIN];
    int b = blockIdx.x, t = threadIdx.x;
    for (int i = t; i < NBIN; i += 256) lc[i] = gpos[i * SBLK + b];
    __syncthreads();
    int e0 = b * CHUNK;
    for (int i = t; i < CHUNK; i += 256) {
        int e = e0 + i;
        int r = erow[e], c = ecol[e];
        int pos = atomicAdd(&lc[c >> 9], 1);
        pairs[pos] = r | ((c & 511) << 17);
    }
}

// one block per bin: per-node degree -> LDS scan -> rp/dinv -> place eidx
__global__ __launch_bounds__(512) void k_binfinish(
    const int* __restrict__ gpos, const int* __restrict__ pairs,
    int* __restrict__ rp, float* __restrict__ dinv, int* __restrict__ eidx) {
    __shared__ int cnt[512];
    __shared__ int tmp[512];
    int b = blockIdx.x, t = threadIdx.x;
    int n0 = b << 9;
    int beg = gpos[b * SBLK];
    int end = (b + 1 < NBIN) ? gpos[(b + 1) * SBLK] : N_EDGES;

    cnt[t] = 0;
    __syncthreads();
    for (int i = beg + t; i < end; i += 512)
        atomicAdd(&cnt[(pairs[i] >> 17) & 511], 1);
    __syncthreads();
    int v = cnt[t];
    tmp[t] = v;
    __syncthreads();
    for (int off = 1; off < 512; off <<= 1) {
        int u = (t >= off) ? tmp[t - off] : 0;
        __syncthreads();
        tmp[t] += u;
        __syncthreads();
    }
    int rpv = beg + tmp[t] - v;
    int n = n0 + t;
    if (n < N_NODES) {
        rp[n] = rpv;
        dinv[n] = rsqrtf(1.0f + (float)v);
    }
    if (b == NBIN - 1 && t == 0) rp[N_NODES] = N_EDGES;
    cnt[t] = rpv;
    __syncthreads();
    for (int i = beg + t; i < end; i += 512) {
        int p = pairs[i];
        int pos = atomicAdd(&cnt[(p >> 17) & 511], 1);
        eidx[pos] = p & 0x1FFFF;
    }
}

// -------- weight prep: Wt0[64][128] = W0^T padded; Wt1[48][64] = W1^T padded
__global__ __launch_bounds__(64) void k_wprep(const float* __restrict__ W0,
                                              const float* __restrict__ W1,
                                              __half* __restrict__ wt0,
                                              __half* __restrict__ wt1) {
    int n = threadIdx.x;   // 0..63
    for (int k = 0; k < 128; ++k)
        wt0[n * 128 + k] = __float2half((k < N_FEAT) ? W0[k * HIDDEN + n] : 0.0f);
    if (n < ZPAD) {
        for (int k = 0; k < HIDDEN; ++k)
            wt1[n * 64 + k] = __float2half((n < N_CLASSES) ? W1[k * N_CLASSES + n] : 0.0f);
    }
}

// -------- layer 0 GEMM (MFMA): yh = fp16( dinv[row] * (x @ W0) )
// A frag: m = lane&15, k = 8*(lane>>4)+j contiguous; B frag: n = lane&15, same k
// D frag: m = 4*(lane>>4)+r, n = lane&15   [verified m89/m97 layouts]
__global__ __launch_bounds__(256) void k_gemm1(
    const float* __restrict__ x, const __half* __restrict__ wt0,
    const float* __restrict__ dinv, __half* __restrict__ yh) {
    int w = threadIdx.x >> 6, l = threadIdx.x & 63;
    int g = l >> 4, c16 = l & 15;
    int row = blockIdx.x * 64 + w * 16 + c16;
    int rl = (row < N_NODES) ? row : (N_NODES - 1);
    const float* xr = x + (size_t)rl * N_FEAT;

    f16x8 a[4];
    #pragma unroll
    for (int s = 0; s < 4; ++s) {
        int k0 = 32 * s + 8 * g;
        float4 f0 = (k0 + 3 < N_FEAT) ? *(const float4*)(xr + k0)
                                      : make_float4(0.f, 0.f, 0.f, 0.f);
        float4 f1 = (k0 + 7 < N_FEAT) ? *(const float4*)(xr + k0 + 4)
                                      : make_float4(0.f, 0.f, 0.f, 0.f);
        a[s][0] = (_Float16)f0.x; a[s][1] = (_Float16)f0.y;
        a[s][2] = (_Float16)f0.z; a[s][3] = (_Float16)f0.w;
        a[s][4] = (_Float16)f1.x; a[s][5] = (_Float16)f1.y;
        a[s][6] = (_Float16)f1.z; a[s][7] = (_Float16)f1.w;
    }
    f32x4 acc0 = {0,0,0,0}, acc1 = {0,0,0,0}, acc2 = {0,0,0,0}, acc3 = {0,0,0,0};
    #pragma unroll
    for (int s = 0; s < 4; ++s) {
        int ko = 32 * s + 8 * g;
        f16x8 b0 = *(const f16x8*)(wt0 + (0 * 16 + c16) * 128 + ko);
        f16x8 b1 = *(const f16x8*)(wt0 + (1 * 16 + c16) * 128 + ko);
        f16x8 b2 = *(const f16x8*)(wt0 + (2 * 16 + c16) * 128 + ko);
        f16x8 b3 = *(const f16x8*)(wt0 + (3 * 16 + c16) * 128 + ko);
        acc0 = __builtin_amdgcn_mfma_f32_16x16x32_f16(a[s], b0, acc0, 0, 0, 0);
        acc1 = __builtin_amdgcn_mfma_f32_16x16x32_f16(a[s], b1, acc1, 0, 0, 0);
        acc2 = __builtin_amdgcn_mfma_f32_16x16x32_f16(a[s], b2, acc2, 0, 0, 0);
        acc3 = __builtin_amdgcn_mfma_f32_16x16x32_f16(a[s], b3, acc3, 0, 0, 0);
    }
    int orow = blockIdx.x * 64 + w * 16 + 4 * g;
    #pragma unroll
    for (int r = 0; r < 4; ++r) {
        if (orow + r < N_NODES) {
            float di = dinv[orow + r];   // <-- the R7 bug: this scaling was dropped
            size_t base = (size_t)(orow + r) * HIDDEN + c16;
            yh[base +  0] = __float2half(di * acc0[r]);
            yh[base + 16] = __float2half(di * acc1[r]);
            yh[base + 32] = __float2half(di * acc2[r]);
            yh[base + 48] = __float2half(di * acc3[r]);
        }
    }
}

// -------- layer 0 aggregate: hr[n] = relu(dinv[n]*(yh[n]+sum yh[src]) + b0)
// 2 nodes per wave: 32 lanes/node, each lane owns a feature PAIR (half2)
__global__ __launch_bounds__(256) void k_agg0(
    const int* __restrict__ rp, const int* __restrict__ eidx,
    const float* __restrict__ dinv, const __half* __restrict__ yh,
    const float* __restrict__ b0, __half* __restrict__ hr) {
    int t = blockIdx.x * 256 + threadIdx.x;
    int n = t >> 5;
    int hl = threadIdx.x & 31;
    if (n >= N_NODES) return;
    int beg = rp[n], end = rp[n + 1];
    int deg = end - beg;
    int se = (beg + hl < end) ? eidx[beg + hl] : 0;
    const __half2* yh2 = (const __half2*)yh;
    float2 f = __half22float2(yh2[(size_t)n * 32 + hl]);   // self loop
    float ax = f.x, ay = f.y;
    int m = deg < 32 ? deg : 32;
    int base = threadIdx.x & 32;
    int j = 0;
    for (; j + 8 <= m; j += 8) {
        int s0 = __shfl(se, base + j + 0), s1 = __shfl(se, base + j + 1);
        int s2 = __shfl(se, base + j + 2), s3 = __shfl(se, base + j + 3);
        int s4 = __shfl(se, base + j + 4), s5 = __shfl(se, base + j + 5);
        int s6 = __shfl(se, base + j + 6), s7 = __shfl(se, base + j + 7);
        float2 f0 = __half22float2(yh2[(size_t)s0 * 32 + hl]);
        float2 f1 = __half22float2(yh2[(size_t)s1 * 32 + hl]);
        float2 f2 = __half22float2(yh2[(size_t)s2 * 32 + hl]);
        float2 f3 = __half22float2(yh2[(size_t)s3 * 32 + hl]);
        float2 f4 = __half22float2(yh2[(size_t)s4 * 32 + hl]);
        float2 f5 = __half22float2(yh2[(size_t)s5 * 32 + hl]);
        float2 f6 = __half22float2(yh2[(size_t)s6 * 32 + hl]);
        float2 f7 = __half22float2(yh2[(size_t)s7 * 32 + hl]);
        ax += ((f0.x + f1.x) + (f2.x + f3.x)) + ((f4.x + f5.x) + (f6.x + f7.x));
        ay += ((f0.y + f1.y) + (f2.y + f3.y)) + ((f4.y + f5.y) + (f6.y + f7.y));
    }
    for (; j < m; ++j) {
        int s = __shfl(se, base + j);
        float2 fv = __half22float2(yh2[(size_t)s * 32 + hl]);
        ax += fv.x; ay += fv.y;
    }
    if (deg > 32) {
        for (int e = beg + 32; e < end; ++e) {
            int s = eidx[e];
            float2 fv = __half22float2(yh2[(size_t)s * 32 + hl]);
            ax += fv.x; ay += fv.y;
        }
    }
    float di = dinv[n];
    float o0 = fmaxf(di * ax + b0[2 * hl], 0.0f);
    float o1 = fmaxf(di * ay + b0[2 * hl + 1], 0.0f);
    ((__half2*)hr)[(size_t)n * 32 + hl] = __floats2half2_rn(o0, o1);
}

// -------- layer 1 GEMM (MFMA): zh = fp16( dinv[row] * (hr @ W1) ), pad 48 ---
__global__ __launch_bounds__(256) void k_gemm2(
    const __half* __restrict__ hr, const __half* __restrict__ wt1,
    const float* __restrict__ dinv, __half* __restrict__ zh) {
    int w = threadIdx.x >> 6, l = threadIdx.x & 63;
    int g = l >> 4, c16 = l & 15;
    int row = blockIdx.x * 64 + w * 16 + c16;
    int rl = (row < N_NODES) ? row : (N_NODES - 1);

    f16x8 a0 = *(const f16x8*)(hr + (size_t)rl * 64 +  0 + 8 * g);
    f16x8 a1 = *(const f16x8*)(hr + (size_t)rl * 64 + 32 + 8 * g);
    f32x4 acc0 = {0,0,0,0}, acc1 = {0,0,0,0}, acc2 = {0,0,0,0};
    #pragma unroll
    for (int s = 0; s < 2; ++s) {
        int ko = 32 * s + 8 * g;
        f16x8 b0 = *(const f16x8*)(wt1 + (0 * 16 + c16) * 64 + ko);
        f16x8 b1 = *(const f16x8*)(wt1 + (1 * 16 + c16) * 64 + ko);
        f16x8 b2 = *(const f16x8*)(wt1 + (2 * 16 + c16) * 64 + ko);
        f16x8 av = s ? a1 : a0;
        acc0 = __builtin_amdgcn_mfma_f32_16x16x32_f16(av, b0, acc0, 0, 0, 0);
        acc1 = __builtin_amdgcn_mfma_f32_16x16x32_f16(av, b1, acc1, 0, 0, 0);
        acc2 = __builtin_amdgcn_mfma_f32_16x16x32_f16(av, b2, acc2, 0, 0, 0);
    }
    int orow = blockIdx.x * 64 + w * 16 + 4 * g;
    #pragma unroll
    for (int r = 0; r < 4; ++r) {
        if (orow + r < N_NODES) {
            float di = dinv[orow + r];   // <-- the R7 bug, second instance
            size_t base = (size_t)(orow + r) * ZPAD + c16;
            zh[base +  0] = __float2half(di * acc0[r]);
            zh[base + 16] = __float2half(di * acc1[r]);
            zh[base + 32] = __float2half(di * acc2[r]);
        }
    }
}

// -------- layer 1 aggregate: out[n] = dinv[n]*(zh[n]+sum zh[src]) + b1 ------
__global__ __launch_bounds__(256) void k_agg1(
    const int* __restrict__ rp, const int* __restrict__ eidx,
    const float* __restrict__ dinv, const __half* __restrict__ zh,
    const float* __restrict__ b1, float* __restrict__ out) {
    int t = blockIdx.x * 256 + threadIdx.x;
    int n = t >> 5;
    int hl = threadIdx.x & 31;
    if (n >= N_NODES) return;
    int beg = rp[n], end = rp[n + 1];
    int deg = end - beg;
    int se = (beg + hl < end) ? eidx[beg + hl] : 0;
    const __half2* zh2 = (const __half2*)zh;
    float ax = 0.0f, ay = 0.0f;
    if (hl < 24) {
        float2 f = __half22float2(zh2[(size_t)n * 24 + hl]);
        ax = f.x; ay = f.y;
    }
    int m = deg < 32 ? deg : 32;
    int base = threadIdx.x & 32;
    int j = 0;
    for (; j + 8 <= m; j += 8) {
        int s0 = __shfl(se, base + j + 0), s1 = __shfl(se, base + j + 1);
        int s2 = __shfl(se, base + j + 2), s3 = __shfl(se, base + j + 3);
        int s4 = __shfl(se, base + j + 4), s5 = __shfl(se, base + j + 5);
        int s6 = __shfl(se, base + j + 6), s7 = __shfl(se, base + j + 7);
        if (hl < 24) {
            float2 f0 = __half22float2(zh2[(size_t)s0 * 24 + hl]);
            float2 f1 = __half22float2(zh2[(size_t)s1 * 24 + hl]);
            float2 f2 = __half22float2(zh2[(size_t)s2 * 24 + hl]);
            float2 f3 = __half22float2(zh2[(size_t)s3 * 24 + hl]);
            float2 f4 = __half22float2(zh2[(size_t)s4 * 24 + hl]);
            float2 f5 = __half22float2(zh2[(size_t)s5 * 24 + hl]);
            float2 f6 = __half22float2(zh2[(size_t)s6 * 24 + hl]);
            float2 f7 = __half22float2(zh2[(size_t)s7 * 24 + hl]);
            ax += ((f0.x + f1.x) + (f2.x + f3.x)) + ((f4.x + f5.x) + (f6.x + f7.x));
            ay += ((f0.y + f1.y) + (f2.y + f3.y)) + ((f4.y + f5.y) + (f6.y + f7.y));
        }
    }
    for (; j < m; ++j) {
        int s = __shfl(se, base + j);
        if (hl < 24) {
            float2 fv = __half22float2(zh2[(size_t)s * 24 + hl]);
            ax += fv.x; ay += fv.y;
        }
    }
    if (deg > 32) {
        for (int e = beg + 32; e < end; ++e) {
            int s = eidx[e];
            if (hl < 24) {
                float2 fv = __half22float2(zh2[(size_t)s * 24 + hl]);
                ax += fv.x; ay += fv.y;
            }
        }
    }
    if (hl < 24) {
        float di = dinv[n];
        out[(size_t)n * N_CLASSES + 2 * hl] = di * ax + b1[2 * hl];
        if (hl < 23)
            out[(size_t)n * N_CLASSES + 2 * hl + 1] = di * ay + b1[2 * hl + 1];
    }
}

extern "C" void kernel_launch(void* const* d_in, const int* in_sizes, int n_in,
                              void* d_out, int out_size, void* d_ws, size_t ws_size,
                              hipStream_t stream) {
    const float* x  = (const float*)d_in[0];
    const int*   ei = (const int*)d_in[1];
    const float* W0 = (const float*)d_in[2];
    const float* b0 = (const float*)d_in[3];
    const float* W1 = (const float*)d_in[4];
    const float* b1 = (const float*)d_in[5];
    float* out = (float*)d_out;

    char* ws = (char*)d_ws;
    float*  dinv  = (float*)(ws);                         // 400 KB
    int*    rp    = (int*)(ws + 412 * 1024);              // 400 KB + 4
    int*    hsums = (int*)(ws + 824 * 1024);              // 1 KB
    int*    gh    = (int*)(ws + 828 * 1024);              // 196 KB
    int*    gpos  = (int*)(ws + 1028 * 1024);             // 196 KB
    __half* wt0   = (__half*)(ws + 1226 * 1024);          // 16 KB
    __half* wt1   = (__half*)(ws + 1244 * 1024);          // 6 KB
    int*    eidx  = (int*)(ws + 1252 * 1024);             // 6.4 MB -> ~7.65 MB
    __half* yh    = (__half*)(ws + 8ull * 1024 * 1024);   // 12.8 MB -> 20.8 MB
    __half* hr    = (__half*)(ws + 21ull * 1024 * 1024);  // 12.8 MB -> 33.8 MB
    int*    pairs = (int*)hr;   // 6.4 MB alias: dead before k_agg0 writes hr
    __half* zh    = yh;         // alias: yh dead after k_agg0 (9.6 MB used)

    const int* erow = ei;             // edge_index[0] (sources)
    const int* ecol = ei + N_EDGES;   // edge_index[1] (destinations)

    // radix pass: bin histogram -> scan -> scatter -> fused degree+rp+place
    k_hist  <<<SBLK, 256, 0, stream>>>(ecol, gh);
    k_gscan1<<<(NHIST + 255) / 256, 256, 0, stream>>>(gh, gpos, hsums, NHIST);
    k_gscan2<<<1, 512, 0, stream>>>(hsums, (NHIST + 255) / 256);
    k_hfix  <<<(NHIST + 255) / 256, 256, 0, stream>>>(gpos, hsums, NHIST);
    k_radix_scatter<<<SBLK, 256, 0, stream>>>(erow, ecol, gpos, pairs);
    k_binfinish<<<NBIN, 512, 0, stream>>>(gpos, pairs, rp, dinv, eidx);

    k_wprep<<<1, 64, 0, stream>>>(W0, W1, wt0, wt1);

    // layer 0
    k_gemm1<<<(N_NODES + 63) / 64, 256, 0, stream>>>(x, wt0, dinv, yh);
    k_agg0 <<<(N_NODES * 32 + 255) / 256, 256, 0, stream>>>(rp, eidx, dinv, yh, b0, hr);

    // layer 1
    k_gemm2<<<(N_NODES + 63) / 64, 256, 0, stream>>>(hr, wt1, dinv, zh);
    k_agg1 <<<(N_NODES * 32 + 255) / 256, 256, 0, stream>>>(rp, eidx, dinv, zh, b1, out);
}

// Round 9
// 159.001 us; speedup vs baseline: 3.2531x; 1.2966x over previous
//
#include <hip/hip_runtime.h>
#include <hip/hip_fp16.h>

#define N_NODES   100000
#define N_EDGES   1600000
#define N_FEAT    100
#define HIDDEN    64
#define N_CLASSES 47
#define ZPAD      48
#define NBIN      ((N_NODES + 511) / 512)   // 196 radix bins (dest >> 9)
#define SBLK      256                        // scatter blocks
#define CHUNK     (N_EDGES / SBLK)           // 6250 edges per scatter block
#define NHIST     (NBIN * SBLK)              // 50176 histogram entries
#define WT0_ELEMS (HIDDEN * 128)             // 8192
#define WT1_ELEMS (ZPAD * 64)                // 3072

typedef _Float16 f16x8 __attribute__((ext_vector_type(8)));
typedef float f32x4 __attribute__((ext_vector_type(4)));

// ---------------- generic 2-level exclusive scan (for bin histogram) -------

__global__ __launch_bounds__(256) void k_gscan1(const int* __restrict__ in,
                                                int* __restrict__ out,
                                                int* __restrict__ sums, int n) {
    __shared__ int tmp[256];
    int i = blockIdx.x * 256 + threadIdx.x;
    int v = (i < n) ? in[i] : 0;
    tmp[threadIdx.x] = v;
    __syncthreads();
    for (int off = 1; off < 256; off <<= 1) {
        int t = (threadIdx.x >= off) ? tmp[threadIdx.x - off] : 0;
        __syncthreads();
        tmp[threadIdx.x] += t;
        __syncthreads();
    }
    if (i < n) out[i] = tmp[threadIdx.x] - v;
    if (threadIdx.x == 255) sums[blockIdx.x] = tmp[255];
}

__global__ __launch_bounds__(512) void k_gscan2(int* __restrict__ sums, int nb) {
    __shared__ int tmp[512];
    int i = threadIdx.x;
    int v = (i < nb) ? sums[i] : 0;
    tmp[i] = v;
    __syncthreads();
    for (int off = 1; off < 512; off <<= 1) {
        int t = (i >= off) ? tmp[i - off] : 0;
        __syncthreads();
        tmp[i] += t;
        __syncthreads();
    }
    if (i < nb) sums[i] = tmp[i] - v;
}

__global__ void k_hfix(int* __restrict__ out, const int* __restrict__ sums, int n) {
    int i = blockIdx.x * 256 + threadIdx.x;
    if (i < n) out[i] += sums[i >> 8];
}

// ---------------- radix pass: bin = dest >> 9 ----------------

__global__ __launch_bounds__(256) void k_hist(const int* __restrict__ ecol,
                                              int* __restrict__ gh) {
    __shared__ int lh[NBIN];
    int b = blockIdx.x, t = threadIdx.x;
    for (int i = t; i < NBIN; i += 256) lh[i] = 0;
    __syncthreads();
    int e0 = b * CHUNK;
    for (int i = t; i < CHUNK; i += 256)
        atomicAdd(&lh[ecol[e0 + i] >> 9], 1);
    __syncthreads();
    for (int i = t; i < NBIN; i += 256) gh[i * SBLK + b] = lh[i];
}

__global__ __launch_bounds__(256) void k_radix_scatter(
    const int* __restrict__ erow, const int* __restrict__ ecol,
    const int* __restrict__ gpos, int* __restrict__ pairs) {
    __shared__ int lc[NBIN];
    int b = blockIdx.x, t = threadIdx.x;
    for (int i = t; i < NBIN; i += 256) lc[i] = gpos[i * SBLK + b];
    __syncthreads();
    int e0 = b * CHUNK;
    for (int i = t; i < CHUNK; i += 256) {
        int e = e0 + i;
        int r = erow[e], c = ecol[e];
        int pos = atomicAdd(&lc[c >> 9], 1);
        pairs[pos] = r | ((c & 511) << 17);
    }
}

// one block per bin: per-node degree -> LDS scan -> rp/dinv -> place eidx
__global__ __launch_bounds__(512) void k_binfinish(
    const int* __restrict__ gpos, const int* __restrict__ pairs,
    int* __restrict__ rp, float* __restrict__ dinv, int* __restrict__ eidx) {
    __shared__ int cnt[512];
    __shared__ int tmp[512];
    int b = blockIdx.x, t = threadIdx.x;
    int n0 = b << 9;
    int beg = gpos[b * SBLK];
    int end = (b + 1 < NBIN) ? gpos[(b + 1) * SBLK] : N_EDGES;

    cnt[t] = 0;
    __syncthreads();
    for (int i = beg + t; i < end; i += 512)
        atomicAdd(&cnt[(pairs[i] >> 17) & 511], 1);
    __syncthreads();
    int v = cnt[t];
    tmp[t] = v;
    __syncthreads();
    for (int off = 1; off < 512; off <<= 1) {
        int u = (t >= off) ? tmp[t - off] : 0;
        __syncthreads();
        tmp[t] += u;
        __syncthreads();
    }
    int rpv = beg + tmp[t] - v;
    int n = n0 + t;
    if (n < N_NODES) {
        rp[n] = rpv;
        dinv[n] = rsqrtf(1.0f + (float)v);
    }
    if (b == NBIN - 1 && t == 0) rp[N_NODES] = N_EDGES;
    cnt[t] = rpv;
    __syncthreads();
    for (int i = beg + t; i < end; i += 512) {
        int p = pairs[i];
        int pos = atomicAdd(&cnt[(p >> 17) & 511], 1);
        eidx[pos] = p & 0x1FFFF;
    }
}

// -------- weight prep (parallel): Wt0[64][128]=W0^T pad; Wt1[48][64]=W1^T pad
__global__ __launch_bounds__(256) void k_wprep(const float* __restrict__ W0,
                                               const float* __restrict__ W1,
                                               __half* __restrict__ wt0,
                                               __half* __restrict__ wt1) {
    int i = blockIdx.x * 256 + threadIdx.x;
    if (i < WT0_ELEMS) {
        int n = i >> 7, k = i & 127;
        wt0[i] = __float2half((k < N_FEAT) ? W0[k * HIDDEN + n] : 0.0f);
    } else if (i < WT0_ELEMS + WT1_ELEMS) {
        int j = i - WT0_ELEMS;
        int n = j >> 6, k = j & 63;
        wt1[j] = __float2half((n < N_CLASSES) ? W1[k * N_CLASSES + n] : 0.0f);
    }
}

// -------- layer 0 GEMM (MFMA): yh = fp16( dinv[row] * (x @ W0) )
// A frag: m = lane&15, k = 8*(lane>>4)+j contiguous; B frag: n = lane&15, same k
// D frag: m = 4*(lane>>4)+r, n = lane&15   [verified m89/m97 layouts]
__global__ __launch_bounds__(256) void k_gemm1(
    const float* __restrict__ x, const __half* __restrict__ wt0,
    const float* __restrict__ dinv, __half* __restrict__ yh) {
    int w = threadIdx.x >> 6, l = threadIdx.x & 63;
    int g = l >> 4, c16 = l & 15;
    int row = blockIdx.x * 64 + w * 16 + c16;
    int rl = (row < N_NODES) ? row : (N_NODES - 1);
    const float* xr = x + (size_t)rl * N_FEAT;

    f16x8 a[4];
    #pragma unroll
    for (int s = 0; s < 4; ++s) {
        int k0 = 32 * s + 8 * g;
        float4 f0 = (k0 + 3 < N_FEAT) ? *(const float4*)(xr + k0)
                                      : make_float4(0.f, 0.f, 0.f, 0.f);
        float4 f1 = (k0 + 7 < N_FEAT) ? *(const float4*)(xr + k0 + 4)
                                      : make_float4(0.f, 0.f, 0.f, 0.f);
        a[s][0] = (_Float16)f0.x; a[s][1] = (_Float16)f0.y;
        a[s][2] = (_Float16)f0.z; a[s][3] = (_Float16)f0.w;
        a[s][4] = (_Float16)f1.x; a[s][5] = (_Float16)f1.y;
        a[s][6] = (_Float16)f1.z; a[s][7] = (_Float16)f1.w;
    }
    f32x4 acc0 = {0,0,0,0}, acc1 = {0,0,0,0}, acc2 = {0,0,0,0}, acc3 = {0,0,0,0};
    #pragma unroll
    for (int s = 0; s < 4; ++s) {
        int ko = 32 * s + 8 * g;
        f16x8 b0 = *(const f16x8*)(wt0 + (0 * 16 + c16) * 128 + ko);
        f16x8 b1 = *(const f16x8*)(wt0 + (1 * 16 + c16) * 128 + ko);
        f16x8 b2 = *(const f16x8*)(wt0 + (2 * 16 + c16) * 128 + ko);
        f16x8 b3 = *(const f16x8*)(wt0 + (3 * 16 + c16) * 128 + ko);
        acc0 = __builtin_amdgcn_mfma_f32_16x16x32_f16(a[s], b0, acc0, 0, 0, 0);
        acc1 = __builtin_amdgcn_mfma_f32_16x16x32_f16(a[s], b1, acc1, 0, 0, 0);
        acc2 = __builtin_amdgcn_mfma_f32_16x16x32_f16(a[s], b2, acc2, 0, 0, 0);
        acc3 = __builtin_amdgcn_mfma_f32_16x16x32_f16(a[s], b3, acc3, 0, 0, 0);
    }
    int orow = blockIdx.x * 64 + w * 16 + 4 * g;
    #pragma unroll
    for (int r = 0; r < 4; ++r) {
        if (orow + r < N_NODES) {
            float di = dinv[orow + r];
            size_t base = (size_t)(orow + r) * HIDDEN + c16;
            yh[base +  0] = __float2half(di * acc0[r]);
            yh[base + 16] = __float2half(di * acc1[r]);
            yh[base + 32] = __float2half(di * acc2[r]);
            yh[base + 48] = __float2half(di * acc3[r]);
        }
    }
}

// -------- layer 0 aggregate: hr[n] = relu(dinv[n]*(yh[n]+sum yh[src]) + b0)
// 2 nodes per wave: 32 lanes/node, each lane owns a feature PAIR (half2)
__global__ __launch_bounds__(256) void k_agg0(
    const int* __restrict__ rp, const int* __restrict__ eidx,
    const float* __restrict__ dinv, const __half* __restrict__ yh,
    const float* __restrict__ b0, __half* __restrict__ hr) {
    int t = blockIdx.x * 256 + threadIdx.x;
    int n = t >> 5;
    int hl = threadIdx.x & 31;
    if (n >= N_NODES) return;
    int beg = rp[n], end = rp[n + 1];
    int deg = end - beg;
    int se = (beg + hl < end) ? eidx[beg + hl] : 0;
    const __half2* yh2 = (const __half2*)yh;
    float2 f = __half22float2(yh2[(size_t)n * 32 + hl]);   // self loop
    float ax = f.x, ay = f.y;
    int m = deg < 32 ? deg : 32;
    int base = threadIdx.x & 32;
    int j = 0;
    for (; j + 8 <= m; j += 8) {
        int s0 = __shfl(se, base + j + 0), s1 = __shfl(se, base + j + 1);
        int s2 = __shfl(se, base + j + 2), s3 = __shfl(se, base + j + 3);
        int s4 = __shfl(se, base + j + 4), s5 = __shfl(se, base + j + 5);
        int s6 = __shfl(se, base + j + 6), s7 = __shfl(se, base + j + 7);
        float2 f0 = __half22float2(yh2[(size_t)s0 * 32 + hl]);
        float2 f1 = __half22float2(yh2[(size_t)s1 * 32 + hl]);
        float2 f2 = __half22float2(yh2[(size_t)s2 * 32 + hl]);
        float2 f3 = __half22float2(yh2[(size_t)s3 * 32 + hl]);
        float2 f4 = __half22float2(yh2[(size_t)s4 * 32 + hl]);
        float2 f5 = __half22float2(yh2[(size_t)s5 * 32 + hl]);
        float2 f6 = __half22float2(yh2[(size_t)s6 * 32 + hl]);
        float2 f7 = __half22float2(yh2[(size_t)s7 * 32 + hl]);
        ax += ((f0.x + f1.x) + (f2.x + f3.x)) + ((f4.x + f5.x) + (f6.x + f7.x));
        ay += ((f0.y + f1.y) + (f2.y + f3.y)) + ((f4.y + f5.y) + (f6.y + f7.y));
    }
    for (; j < m; ++j) {
        int s = __shfl(se, base + j);
        float2 fv = __half22float2(yh2[(size_t)s * 32 + hl]);
        ax += fv.x; ay += fv.y;
    }
    if (deg > 32) {
        for (int e = beg + 32; e < end; ++e) {
            int s = eidx[e];
            float2 fv = __half22float2(yh2[(size_t)s * 32 + hl]);
            ax += fv.x; ay += fv.y;
        }
    }
    float di = dinv[n];
    float o0 = fmaxf(di * ax + b0[2 * hl], 0.0f);
    float o1 = fmaxf(di * ay + b0[2 * hl + 1], 0.0f);
    ((__half2*)hr)[(size_t)n * 32 + hl] = __floats2half2_rn(o0, o1);
}

// -------- layer 1 GEMM (MFMA): zh = fp16( dinv[row] * (hr @ W1) ), pad 48 ---
__global__ __launch_bounds__(256) void k_gemm2(
    const __half* __restrict__ hr, const __half* __restrict__ wt1,
    const float* __restrict__ dinv, __half* __restrict__ zh) {
    int w = threadIdx.x >> 6, l = threadIdx.x & 63;
    int g = l >> 4, c16 = l & 15;
    int row = blockIdx.x * 64 + w * 16 + c16;
    int rl = (row < N_NODES) ? row : (N_NODES - 1);

    f16x8 a0 = *(const f16x8*)(hr + (size_t)rl * 64 +  0 + 8 * g);
    f16x8 a1 = *(const f16x8*)(hr + (size_t)rl * 64 + 32 + 8 * g);
    f32x4 acc0 = {0,0,0,0}, acc1 = {0,0,0,0}, acc2 = {0,0,0,0};
    #pragma unroll
    for (int s = 0; s < 2; ++s) {
        int ko = 32 * s + 8 * g;
        f16x8 b0 = *(const f16x8*)(wt1 + (0 * 16 + c16) * 64 + ko);
        f16x8 b1 = *(const f16x8*)(wt1 + (1 * 16 + c16) * 64 + ko);
        f16x8 b2 = *(const f16x8*)(wt1 + (2 * 16 + c16) * 64 + ko);
        f16x8 av = s ? a1 : a0;
        acc0 = __builtin_amdgcn_mfma_f32_16x16x32_f16(av, b0, acc0, 0, 0, 0);
        acc1 = __builtin_amdgcn_mfma_f32_16x16x32_f16(av, b1, acc1, 0, 0, 0);
        acc2 = __builtin_amdgcn_mfma_f32_16x16x32_f16(av, b2, acc2, 0, 0, 0);
    }
    int orow = blockIdx.x * 64 + w * 16 + 4 * g;
    #pragma unroll
    for (int r = 0; r < 4; ++r) {
        if (orow + r < N_NODES) {
            float di = dinv[orow + r];
            size_t base = (size_t)(orow + r) * ZPAD + c16;
            zh[base +  0] = __float2half(di * acc0[r]);
            zh[base + 16] = __float2half(di * acc1[r]);
            zh[base + 32] = __float2half(di * acc2[r]);
        }
    }
}

// -------- layer 1 aggregate: out[n] = dinv[n]*(zh[n]+sum zh[src]) + b1 ------
__global__ __launch_bounds__(256) void k_agg1(
    const int* __restrict__ rp, const int* __restrict__ eidx,
    const float* __restrict__ dinv, const __half* __restrict__ zh,
    const float* __restrict__ b1, float* __restrict__ out) {
    int t = blockIdx.x * 256 + threadIdx.x;
    int n = t >> 5;
    int hl = threadIdx.x & 31;
    if (n >= N_NODES) return;
    int beg = rp[n], end = rp[n + 1];
    int deg = end - beg;
    int se = (beg + hl < end) ? eidx[beg + hl] : 0;
    const __half2* zh2 = (const __half2*)zh;
    float ax = 0.0f, ay = 0.0f;
    if (hl < 24) {
        float2 f = __half22float2(zh2[(size_t)n * 24 + hl]);
        ax = f.x; ay = f.y;
    }
    int m = deg < 32 ? deg : 32;
    int base = threadIdx.x & 32;
    int j = 0;
    for (; j + 8 <= m; j += 8) {
        int s0 = __shfl(se, base + j + 0), s1 = __shfl(se, base + j + 1);
        int s2 = __shfl(se, base + j + 2), s3 = __shfl(se, base + j + 3);
        int s4 = __shfl(se, base + j + 4), s5 = __shfl(se, base + j + 5);
        int s6 = __shfl(se, base + j + 6), s7 = __shfl(se, base + j + 7);
        if (hl < 24) {
            float2 f0 = __half22float2(zh2[(size_t)s0 * 24 + hl]);
            float2 f1 = __half22float2(zh2[(size_t)s1 * 24 + hl]);
            float2 f2 = __half22float2(zh2[(size_t)s2 * 24 + hl]);
            float2 f3 = __half22float2(zh2[(size_t)s3 * 24 + hl]);
            float2 f4 = __half22float2(zh2[(size_t)s4 * 24 + hl]);
            float2 f5 = __half22float2(zh2[(size_t)s5 * 24 + hl]);
            float2 f6 = __half22float2(zh2[(size_t)s6 * 24 + hl]);
            float2 f7 = __half22float2(zh2[(size_t)s7 * 24 + hl]);
            ax += ((f0.x + f1.x) + (f2.x + f3.x)) + ((f4.x + f5.x) + (f6.x + f7.x));
            ay += ((f0.y + f1.y) + (f2.y + f3.y)) + ((f4.y + f5.y) + (f6.y + f7.y));
        }
    }
    for (; j < m; ++j) {
        int s = __shfl(se, base + j);
        if (hl < 24) {
            float2 fv = __half22float2(zh2[(size_t)s * 24 + hl]);
            ax += fv.x; ay += fv.y;
        }
    }
    if (deg > 32) {
        for (int e = beg + 32; e < end; ++e) {
            int s = eidx[e];
            if (hl < 24) {
                float2 fv = __half22float2(zh2[(size_t)s * 24 + hl]);
                ax += fv.x; ay += fv.y;
            }
        }
    }
    if (hl < 24) {
        float di = dinv[n];
        out[(size_t)n * N_CLASSES + 2 * hl] = di * ax + b1[2 * hl];
        if (hl < 23)
            out[(size_t)n * N_CLASSES + 2 * hl + 1] = di * ay + b1[2 * hl + 1];
    }
}

extern "C" void kernel_launch(void* const* d_in, const int* in_sizes, int n_in,
                              void* d_out, int out_size, void* d_ws, size_t ws_size,
                              hipStream_t stream) {
    const float* x  = (const float*)d_in[0];
    const int*   ei = (const int*)d_in[1];
    const float* W0 = (const float*)d_in[2];
    const float* b0 = (const float*)d_in[3];
    const float* W1 = (const float*)d_in[4];
    const float* b1 = (const float*)d_in[5];
    float* out = (float*)d_out;

    char* ws = (char*)d_ws;
    float*  dinv  = (float*)(ws);                         // 400 KB
    int*    rp    = (int*)(ws + 412 * 1024);              // 400 KB + 4
    int*    hsums = (int*)(ws + 824 * 1024);              // 1 KB
    int*    gh    = (int*)(ws + 828 * 1024);              // 196 KB
    int*    gpos  = (int*)(ws + 1028 * 1024);             // 196 KB
    __half* wt0   = (__half*)(ws + 1226 * 1024);          // 16 KB
    __half* wt1   = (__half*)(ws + 1244 * 1024);          // 6 KB
    int*    eidx  = (int*)(ws + 1252 * 1024);             // 6.4 MB -> ~7.65 MB
    __half* yh    = (__half*)(ws + 8ull * 1024 * 1024);   // 12.8 MB -> 20.8 MB
    __half* hr    = (__half*)(ws + 21ull * 1024 * 1024);  // 12.8 MB -> 33.8 MB
    int*    pairs = (int*)hr;   // 6.4 MB alias: dead before k_agg0 writes hr
    __half* zh    = yh;         // alias: yh dead after k_agg0 (9.6 MB used)

    const int* erow = ei;             // edge_index[0] (sources)
    const int* ecol = ei + N_EDGES;   // edge_index[1] (destinations)

    // radix pass: bin histogram -> scan -> scatter -> fused degree+rp+place
    k_hist  <<<SBLK, 256, 0, stream>>>(ecol, gh);
    k_gscan1<<<(NHIST + 255) / 256, 256, 0, stream>>>(gh, gpos, hsums, NHIST);
    k_gscan2<<<1, 512, 0, stream>>>(hsums, (NHIST + 255) / 256);
    k_hfix  <<<(NHIST + 255) / 256, 256, 0, stream>>>(gpos, hsums, NHIST);
    k_radix_scatter<<<SBLK, 256, 0, stream>>>(erow, ecol, gpos, pairs);
    k_binfinish<<<NBIN, 512, 0, stream>>>(gpos, pairs, rp, dinv, eidx);

    k_wprep<<<(WT0_ELEMS + WT1_ELEMS + 255) / 256, 256, 0, stream>>>(W0, W1, wt0, wt1);

    // layer 0
    k_gemm1<<<(N_NODES + 63) / 64, 256, 0, stream>>>(x, wt0, dinv, yh);
    k_agg0 <<<(N_NODES * 32 + 255) / 256, 256, 0, stream>>>(rp, eidx, dinv, yh, b0, hr);

    // layer 1
    k_gemm2<<<(N_NODES + 63) / 64, 256, 0, stream>>>(hr, wt1, dinv, zh);
    k_agg1 <<<(N_NODES * 32 + 255) / 256, 256, 0, stream>>>(rp, eidx, dinv, zh, b1, out);
}

// Round 10
// 146.743 us; speedup vs baseline: 3.5248x; 1.0835x over previous
//
#include <hip/hip_runtime.h>
#include <hip/hip_fp16.h>

#define N_NODES   100000
#define N_EDGES   1600000
#define N_FEAT    100
#define HIDDEN    64
#define N_CLASSES 47
#define ZPAD      48
#define NBIN      ((N_NODES + 511) / 512)   // 196 radix bins (dest >> 9)
#define SBLK      256                        // scatter blocks
#define CHUNK     (N_EDGES / SBLK)           // 6250 edges per scatter block
#define NHIST     (NBIN * SBLK)              // 50176 histogram entries
#define WT0_ELEMS (HIDDEN * 128)             // 8192
#define WT1_ELEMS (ZPAD * 64)                // 3072

typedef _Float16 f16x8 __attribute__((ext_vector_type(8)));
typedef float f32x4 __attribute__((ext_vector_type(4)));

// ---------------- generic 2-level exclusive scan (for bin histogram) -------

__global__ __launch_bounds__(256) void k_gscan1(const int* __restrict__ in,
                                                int* __restrict__ out,
                                                int* __restrict__ sums, int n) {
    __shared__ int tmp[256];
    int i = blockIdx.x * 256 + threadIdx.x;
    int v = (i < n) ? in[i] : 0;
    tmp[threadIdx.x] = v;
    __syncthreads();
    for (int off = 1; off < 256; off <<= 1) {
        int t = (threadIdx.x >= off) ? tmp[threadIdx.x - off] : 0;
        __syncthreads();
        tmp[threadIdx.x] += t;
        __syncthreads();
    }
    if (i < n) out[i] = tmp[threadIdx.x] - v;
    if (threadIdx.x == 255) sums[blockIdx.x] = tmp[255];
}

__global__ __launch_bounds__(512) void k_gscan2(int* __restrict__ sums, int nb) {
    __shared__ int tmp[512];
    int i = threadIdx.x;
    int v = (i < nb) ? sums[i] : 0;
    tmp[i] = v;
    __syncthreads();
    for (int off = 1; off < 512; off <<= 1) {
        int t = (i >= off) ? tmp[i - off] : 0;
        __syncthreads();
        tmp[i] += t;
        __syncthreads();
    }
    if (i < nb) sums[i] = tmp[i] - v;
}

__global__ void k_hfix(int* __restrict__ out, const int* __restrict__ sums, int n) {
    int i = blockIdx.x * 256 + threadIdx.x;
    if (i < n) out[i] += sums[i >> 8];
}

// ---------------- radix pass: bin = dest >> 9 ----------------

__global__ __launch_bounds__(256) void k_hist(const int* __restrict__ ecol,
                                              int* __restrict__ gh) {
    __shared__ int lh[NBIN];
    int b = blockIdx.x, t = threadIdx.x;
    for (int i = t; i < NBIN; i += 256) lh[i] = 0;
    __syncthreads();
    int e0 = b * CHUNK;
    for (int i = t; i < CHUNK; i += 256)
        atomicAdd(&lh[ecol[e0 + i] >> 9], 1);
    __syncthreads();
    for (int i = t; i < NBIN; i += 256) gh[i * SBLK + b] = lh[i];
}

__global__ __launch_bounds__(256) void k_radix_scatter(
    const int* __restrict__ erow, const int* __restrict__ ecol,
    const int* __restrict__ gpos, int* __restrict__ pairs) {
    __shared__ int lc[NBIN];
    int b = blockIdx.x, t = threadIdx.x;
    for (int i = t; i < NBIN; i += 256) lc[i] = gpos[i * SBLK + b];
    __syncthreads();
    int e0 = b * CHUNK;
    for (int i = t; i < CHUNK; i += 256) {
        int e = e0 + i;
        int r = erow[e], c = ecol[e];
        int pos = atomicAdd(&lc[c >> 9], 1);
        pairs[pos] = r | ((c & 511) << 17);
    }
}

// one block per bin: per-node degree -> LDS scan -> rp/dinv -> place eidx
__global__ __launch_bounds__(512) void k_binfinish(
    const int* __restrict__ gpos, const int* __restrict__ pairs,
    int* __restrict__ rp, float* __restrict__ dinv, int* __restrict__ eidx) {
    __shared__ int cnt[512];
    __shared__ int tmp[512];
    int b = blockIdx.x, t = threadIdx.x;
    int n0 = b << 9;
    int beg = gpos[b * SBLK];
    int end = (b + 1 < NBIN) ? gpos[(b + 1) * SBLK] : N_EDGES;

    cnt[t] = 0;
    __syncthreads();
    for (int i = beg + t; i < end; i += 512)
        atomicAdd(&cnt[(pairs[i] >> 17) & 511], 1);
    __syncthreads();
    int v = cnt[t];
    tmp[t] = v;
    __syncthreads();
    for (int off = 1; off < 512; off <<= 1) {
        int u = (t >= off) ? tmp[t - off] : 0;
        __syncthreads();
        tmp[t] += u;
        __syncthreads();
    }
    int rpv = beg + tmp[t] - v;
    int n = n0 + t;
    if (n < N_NODES) {
        rp[n] = rpv;
        dinv[n] = rsqrtf(1.0f + (float)v);
    }
    if (b == NBIN - 1 && t == 0) rp[N_NODES] = N_EDGES;
    cnt[t] = rpv;
    __syncthreads();
    for (int i = beg + t; i < end; i += 512) {
        int p = pairs[i];
        int pos = atomicAdd(&cnt[(p >> 17) & 511], 1);
        eidx[pos] = p & 0x1FFFF;
    }
}

// -------- weight prep (parallel): Wt0[64][128]=W0^T pad; Wt1[48][64]=W1^T pad
__global__ __launch_bounds__(256) void k_wprep(const float* __restrict__ W0,
                                               const float* __restrict__ W1,
                                               __half* __restrict__ wt0,
                                               __half* __restrict__ wt1) {
    int i = blockIdx.x * 256 + threadIdx.x;
    if (i < WT0_ELEMS) {
        int n = i >> 7, k = i & 127;
        wt0[i] = __float2half((k < N_FEAT) ? W0[k * HIDDEN + n] : 0.0f);
    } else if (i < WT0_ELEMS + WT1_ELEMS) {
        int j = i - WT0_ELEMS;
        int n = j >> 6, k = j & 63;
        wt1[j] = __float2half((n < N_CLASSES) ? W1[k * N_CLASSES + n] : 0.0f);
    }
}

// -------- layer 0 GEMM (MFMA): yh = fp16( dinv[row] * (x @ W0) )
__global__ __launch_bounds__(256) void k_gemm1(
    const float* __restrict__ x, const __half* __restrict__ wt0,
    const float* __restrict__ dinv, __half* __restrict__ yh) {
    int w = threadIdx.x >> 6, l = threadIdx.x & 63;
    int g = l >> 4, c16 = l & 15;
    int row = blockIdx.x * 64 + w * 16 + c16;
    int rl = (row < N_NODES) ? row : (N_NODES - 1);
    const float* xr = x + (size_t)rl * N_FEAT;

    f16x8 a[4];
    #pragma unroll
    for (int s = 0; s < 4; ++s) {
        int k0 = 32 * s + 8 * g;
        float4 f0 = (k0 + 3 < N_FEAT) ? *(const float4*)(xr + k0)
                                      : make_float4(0.f, 0.f, 0.f, 0.f);
        float4 f1 = (k0 + 7 < N_FEAT) ? *(const float4*)(xr + k0 + 4)
                                      : make_float4(0.f, 0.f, 0.f, 0.f);
        a[s][0] = (_Float16)f0.x; a[s][1] = (_Float16)f0.y;
        a[s][2] = (_Float16)f0.z; a[s][3] = (_Float16)f0.w;
        a[s][4] = (_Float16)f1.x; a[s][5] = (_Float16)f1.y;
        a[s][6] = (_Float16)f1.z; a[s][7] = (_Float16)f1.w;
    }
    f32x4 acc0 = {0,0,0,0}, acc1 = {0,0,0,0}, acc2 = {0,0,0,0}, acc3 = {0,0,0,0};
    #pragma unroll
    for (int s = 0; s < 4; ++s) {
        int ko = 32 * s + 8 * g;
        f16x8 b0 = *(const f16x8*)(wt0 + (0 * 16 + c16) * 128 + ko);
        f16x8 b1 = *(const f16x8*)(wt0 + (1 * 16 + c16) * 128 + ko);
        f16x8 b2 = *(const f16x8*)(wt0 + (2 * 16 + c16) * 128 + ko);
        f16x8 b3 = *(const f16x8*)(wt0 + (3 * 16 + c16) * 128 + ko);
        acc0 = __builtin_amdgcn_mfma_f32_16x16x32_f16(a[s], b0, acc0, 0, 0, 0);
        acc1 = __builtin_amdgcn_mfma_f32_16x16x32_f16(a[s], b1, acc1, 0, 0, 0);
        acc2 = __builtin_amdgcn_mfma_f32_16x16x32_f16(a[s], b2, acc2, 0, 0, 0);
        acc3 = __builtin_amdgcn_mfma_f32_16x16x32_f16(a[s], b3, acc3, 0, 0, 0);
    }
    int orow = blockIdx.x * 64 + w * 16 + 4 * g;
    #pragma unroll
    for (int r = 0; r < 4; ++r) {
        if (orow + r < N_NODES) {
            float di = dinv[orow + r];
            size_t base = (size_t)(orow + r) * HIDDEN + c16;
            yh[base +  0] = __float2half(di * acc0[r]);
            yh[base + 16] = __float2half(di * acc1[r]);
            yh[base + 32] = __float2half(di * acc2[r]);
            yh[base + 48] = __float2half(di * acc3[r]);
        }
    }
}

// -------- layer 0 aggregate: hr[n] = relu(dinv[n]*(yh[n]+sum yh[src]) + b0)
// 2 nodes/wave, 32 lanes/node, lane owns a half2. All gathers issued in
// masked 8-batches — no serial tail (tail was the R9 latency bottleneck).
__global__ __launch_bounds__(256) void k_agg0(
    const int* __restrict__ rp, const int* __restrict__ eidx,
    const float* __restrict__ dinv, const __half* __restrict__ yh,
    const float* __restrict__ b0, __half* __restrict__ hr) {
    int t = blockIdx.x * 256 + threadIdx.x;
    int n = t >> 5;
    int hl = threadIdx.x & 31;
    if (n >= N_NODES) return;
    int beg = rp[n], end = rp[n + 1];
    int deg = end - beg;
    int se = (beg + hl < end) ? eidx[beg + hl] : 0;
    const __half2* yh2 = (const __half2*)yh;
    float2 f = __half22float2(yh2[(size_t)n * 32 + hl]);   // self loop
    float ax = f.x, ay = f.y;
    int m = deg < 32 ? deg : 32;
    int base = threadIdx.x & 32;

    #pragma unroll
    for (int jb = 0; jb < 4; ++jb) {
        int J = jb * 8;
        if (m > J) {   // batch live for this node (divergence ok: exec mask)
            int s0 = __shfl(se, base + J + 0), s1 = __shfl(se, base + J + 1);
            int s2 = __shfl(se, base + J + 2), s3 = __shfl(se, base + J + 3);
            int s4 = __shfl(se, base + J + 4), s5 = __shfl(se, base + J + 5);
            int s6 = __shfl(se, base + J + 6), s7 = __shfl(se, base + J + 7);
            float2 f0 = __half22float2(yh2[(size_t)s0 * 32 + hl]);
            float2 f1 = __half22float2(yh2[(size_t)s1 * 32 + hl]);
            float2 f2 = __half22float2(yh2[(size_t)s2 * 32 + hl]);
            float2 f3 = __half22float2(yh2[(size_t)s3 * 32 + hl]);
            float2 f4 = __half22float2(yh2[(size_t)s4 * 32 + hl]);
            float2 f5 = __half22float2(yh2[(size_t)s5 * 32 + hl]);
            float2 f6 = __half22float2(yh2[(size_t)s6 * 32 + hl]);
            float2 f7 = __half22float2(yh2[(size_t)s7 * 32 + hl]);
            // masked accumulate: invalid slots (se==0 loads of hot row 0) add 0
            ax += ((m > J + 0 ? f0.x : 0.f) + (m > J + 1 ? f1.x : 0.f)) +
                  ((m > J + 2 ? f2.x : 0.f) + (m > J + 3 ? f3.x : 0.f)) +
                  ((m > J + 4 ? f4.x : 0.f) + (m > J + 5 ? f5.x : 0.f)) +
                  ((m > J + 6 ? f6.x : 0.f) + (m > J + 7 ? f7.x : 0.f));
            ay += ((m > J + 0 ? f0.y : 0.f) + (m > J + 1 ? f1.y : 0.f)) +
                  ((m > J + 2 ? f2.y : 0.f) + (m > J + 3 ? f3.y : 0.f)) +
                  ((m > J + 4 ? f4.y : 0.f) + (m > J + 5 ? f5.y : 0.f)) +
                  ((m > J + 6 ? f6.y : 0.f) + (m > J + 7 ? f7.y : 0.f));
        }
    }
    if (deg > 32) {   // P(deg>32) ~ 1e-4 for Poisson(16): negligible serial
        for (int e = beg + 32; e < end; ++e) {
            int s = eidx[e];
            float2 fv = __half22float2(yh2[(size_t)s * 32 + hl]);
            ax += fv.x; ay += fv.y;
        }
    }
    float di = dinv[n];
    float o0 = fmaxf(di * ax + b0[2 * hl], 0.0f);
    float o1 = fmaxf(di * ay + b0[2 * hl + 1], 0.0f);
    ((__half2*)hr)[(size_t)n * 32 + hl] = __floats2half2_rn(o0, o1);
}

// -------- layer 1 GEMM (MFMA): zh = fp16( dinv[row] * (hr @ W1) ), pad 48 ---
__global__ __launch_bounds__(256) void k_gemm2(
    const __half* __restrict__ hr, const __half* __restrict__ wt1,
    const float* __restrict__ dinv, __half* __restrict__ zh) {
    int w = threadIdx.x >> 6, l = threadIdx.x & 63;
    int g = l >> 4, c16 = l & 15;
    int row = blockIdx.x * 64 + w * 16 + c16;
    int rl = (row < N_NODES) ? row : (N_NODES - 1);

    f16x8 a0 = *(const f16x8*)(hr + (size_t)rl * 64 +  0 + 8 * g);
    f16x8 a1 = *(const f16x8*)(hr + (size_t)rl * 64 + 32 + 8 * g);
    f32x4 acc0 = {0,0,0,0}, acc1 = {0,0,0,0}, acc2 = {0,0,0,0};
    #pragma unroll
    for (int s = 0; s < 2; ++s) {
        int ko = 32 * s + 8 * g;
        f16x8 b0 = *(const f16x8*)(wt1 + (0 * 16 + c16) * 64 + ko);
        f16x8 b1 = *(const f16x8*)(wt1 + (1 * 16 + c16) * 64 + ko);
        f16x8 b2 = *(const f16x8*)(wt1 + (2 * 16 + c16) * 64 + ko);
        f16x8 av = s ? a1 : a0;
        acc0 = __builtin_amdgcn_mfma_f32_16x16x32_f16(av, b0, acc0, 0, 0, 0);
        acc1 = __builtin_amdgcn_mfma_f32_16x16x32_f16(av, b1, acc1, 0, 0, 0);
        acc2 = __builtin_amdgcn_mfma_f32_16x16x32_f16(av, b2, acc2, 0, 0, 0);
    }
    int orow = blockIdx.x * 64 + w * 16 + 4 * g;
    #pragma unroll
    for (int r = 0; r < 4; ++r) {
        if (orow + r < N_NODES) {
            float di = dinv[orow + r];
            size_t base = (size_t)(orow + r) * ZPAD + c16;
            zh[base +  0] = __float2half(di * acc0[r]);
            zh[base + 16] = __float2half(di * acc1[r]);
            zh[base + 32] = __float2half(di * acc2[r]);
        }
    }
}

// -------- layer 1 aggregate: out[n] = dinv[n]*(zh[n]+sum zh[src]) + b1 ------
__global__ __launch_bounds__(256) void k_agg1(
    const int* __restrict__ rp, const int* __restrict__ eidx,
    const float* __restrict__ dinv, const __half* __restrict__ zh,
    const float* __restrict__ b1, float* __restrict__ out) {
    int t = blockIdx.x * 256 + threadIdx.x;
    int n = t >> 5;
    int hl = threadIdx.x & 31;
    if (n >= N_NODES) return;
    int beg = rp[n], end = rp[n + 1];
    int deg = end - beg;
    int se = (beg + hl < end) ? eidx[beg + hl] : 0;
    const __half2* zh2 = (const __half2*)zh;
    float ax = 0.0f, ay = 0.0f;
    if (hl < 24) {
        float2 f = __half22float2(zh2[(size_t)n * 24 + hl]);
        ax = f.x; ay = f.y;
    }
    int m = deg < 32 ? deg : 32;
    int base = threadIdx.x & 32;

    #pragma unroll
    for (int jb = 0; jb < 4; ++jb) {
        int J = jb * 8;
        if (m > J) {
            int s0 = __shfl(se, base + J + 0), s1 = __shfl(se, base + J + 1);
            int s2 = __shfl(se, base + J + 2), s3 = __shfl(se, base + J + 3);
            int s4 = __shfl(se, base + J + 4), s5 = __shfl(se, base + J + 5);
            int s6 = __shfl(se, base + J + 6), s7 = __shfl(se, base + J + 7);
            if (hl < 24) {
                float2 f0 = __half22float2(zh2[(size_t)s0 * 24 + hl]);
                float2 f1 = __half22float2(zh2[(size_t)s1 * 24 + hl]);
                float2 f2 = __half22float2(zh2[(size_t)s2 * 24 + hl]);
                float2 f3 = __half22float2(zh2[(size_t)s3 * 24 + hl]);
                float2 f4 = __half22float2(zh2[(size_t)s4 * 24 + hl]);
                float2 f5 = __half22float2(zh2[(size_t)s5 * 24 + hl]);
                float2 f6 = __half22float2(zh2[(size_t)s6 * 24 + hl]);
                float2 f7 = __half22float2(zh2[(size_t)s7 * 24 + hl]);
                ax += ((m > J + 0 ? f0.x : 0.f) + (m > J + 1 ? f1.x : 0.f)) +
                      ((m > J + 2 ? f2.x : 0.f) + (m > J + 3 ? f3.x : 0.f)) +
                      ((m > J + 4 ? f4.x : 0.f) + (m > J + 5 ? f5.x : 0.f)) +
                      ((m > J + 6 ? f6.x : 0.f) + (m > J + 7 ? f7.x : 0.f));
                ay += ((m > J + 0 ? f0.y : 0.f) + (m > J + 1 ? f1.y : 0.f)) +
                      ((m > J + 2 ? f2.y : 0.f) + (m > J + 3 ? f3.y : 0.f)) +
                      ((m > J + 4 ? f4.y : 0.f) + (m > J + 5 ? f5.y : 0.f)) +
                      ((m > J + 6 ? f6.y : 0.f) + (m > J + 7 ? f7.y : 0.f));
            }
        }
    }
    if (deg > 32) {
        for (int e = beg + 32; e < end; ++e) {
            int s = eidx[e];
            if (hl < 24) {
                float2 fv = __half22float2(zh2[(size_t)s * 24 + hl]);
                ax += fv.x; ay += fv.y;
            }
        }
    }
    if (hl < 24) {
        float di = dinv[n];
        out[(size_t)n * N_CLASSES + 2 * hl] = di * ax + b1[2 * hl];
        if (hl < 23)
            out[(size_t)n * N_CLASSES + 2 * hl + 1] = di * ay + b1[2 * hl + 1];
    }
}

extern "C" void kernel_launch(void* const* d_in, const int* in_sizes, int n_in,
                              void* d_out, int out_size, void* d_ws, size_t ws_size,
                              hipStream_t stream) {
    const float* x  = (const float*)d_in[0];
    const int*   ei = (const int*)d_in[1];
    const float* W0 = (const float*)d_in[2];
    const float* b0 = (const float*)d_in[3];
    const float* W1 = (const float*)d_in[4];
    const float* b1 = (const float*)d_in[5];
    float* out = (float*)d_out;

    char* ws = (char*)d_ws;
    float*  dinv  = (float*)(ws);                         // 400 KB
    int*    rp    = (int*)(ws + 412 * 1024);              // 400 KB + 4
    int*    hsums = (int*)(ws + 824 * 1024);              // 1 KB
    int*    gh    = (int*)(ws + 828 * 1024);              // 196 KB
    int*    gpos  = (int*)(ws + 1028 * 1024);             // 196 KB
    __half* wt0   = (__half*)(ws + 1226 * 1024);          // 16 KB
    __half* wt1   = (__half*)(ws + 1244 * 1024);          // 6 KB
    int*    eidx  = (int*)(ws + 1252 * 1024);             // 6.4 MB -> ~7.65 MB
    __half* yh    = (__half*)(ws + 8ull * 1024 * 1024);   // 12.8 MB -> 20.8 MB
    __half* hr    = (__half*)(ws + 21ull * 1024 * 1024);  // 12.8 MB -> 33.8 MB
    int*    pairs = (int*)hr;   // 6.4 MB alias: dead before k_agg0 writes hr
    __half* zh    = yh;         // alias: yh dead after k_agg0 (9.6 MB used)

    const int* erow = ei;             // edge_index[0] (sources)
    const int* ecol = ei + N_EDGES;   // edge_index[1] (destinations)

    // radix pass: bin histogram -> scan -> scatter -> fused degree+rp+place
    k_hist  <<<SBLK, 256, 0, stream>>>(ecol, gh);
    k_gscan1<<<(NHIST + 255) / 256, 256, 0, stream>>>(gh, gpos, hsums, NHIST);
    k_gscan2<<<1, 512, 0, stream>>>(hsums, (NHIST + 255) / 256);
    k_hfix  <<<(NHIST + 255) / 256, 256, 0, stream>>>(gpos, hsums, NHIST);
    k_radix_scatter<<<SBLK, 256, 0, stream>>>(erow, ecol, gpos, pairs);
    k_binfinish<<<NBIN, 512, 0, stream>>>(gpos, pairs, rp, dinv, eidx);

    k_wprep<<<(WT0_ELEMS + WT1_ELEMS + 255) / 256, 256, 0, stream>>>(W0, W1, wt0, wt1);

    // layer 0
    k_gemm1<<<(N_NODES + 63) / 64, 256, 0, stream>>>(x, wt0, dinv, yh);
    k_agg0 <<<(N_NODES * 32 + 255) / 256, 256, 0, stream>>>(rp, eidx, dinv, yh, b0, hr);

    // layer 1
    k_gemm2<<<(N_NODES + 63) / 64, 256, 0, stream>>>(hr, wt1, dinv, zh);
    k_agg1 <<<(N_NODES * 32 + 255) / 256, 256, 0, stream>>>(rp, eidx, dinv, zh, b1, out);
}

// Round 11
// 146.001 us; speedup vs baseline: 3.5428x; 1.0051x over previous
//
#include <hip/hip_runtime.h>
#include <hip/hip_fp16.h>

#define N_NODES   100000
#define N_EDGES   1600000
#define N_FEAT    100
#define HIDDEN    64
#define N_CLASSES 47
#define ZPAD      48
#define NBIN      ((N_NODES + 255) / 256)   // 391 radix bins (dest >> 8)
#define SBLK      256                        // scatter blocks
#define CHUNK     (N_EDGES / SBLK)           // 6250 edges per scatter block
#define NHIST     (NBIN * SBLK)              // 100096 histogram entries
#define WT0_ELEMS (HIDDEN * 128)             // 8192
#define WT1_ELEMS (ZPAD * 64)                // 3072

typedef _Float16 f16x8 __attribute__((ext_vector_type(8)));
typedef float f32x4 __attribute__((ext_vector_type(4)));

// ---------------- generic 2-level exclusive scan (for bin histogram) -------

__global__ __launch_bounds__(256) void k_gscan1(const int* __restrict__ in,
                                                int* __restrict__ out,
                                                int* __restrict__ sums, int n) {
    __shared__ int tmp[256];
    int i = blockIdx.x * 256 + threadIdx.x;
    int v = (i < n) ? in[i] : 0;
    tmp[threadIdx.x] = v;
    __syncthreads();
    for (int off = 1; off < 256; off <<= 1) {
        int t = (threadIdx.x >= off) ? tmp[threadIdx.x - off] : 0;
        __syncthreads();
        tmp[threadIdx.x] += t;
        __syncthreads();
    }
    if (i < n) out[i] = tmp[threadIdx.x] - v;   // chunk-local exclusive
    if (threadIdx.x == 255) sums[blockIdx.x] = tmp[255];
}

__global__ __launch_bounds__(512) void k_gscan2(int* __restrict__ sums, int nb) {
    __shared__ int tmp[512];
    int i = threadIdx.x;
    int v = (i < nb) ? sums[i] : 0;
    tmp[i] = v;
    __syncthreads();
    for (int off = 1; off < 512; off <<= 1) {
        int t = (i >= off) ? tmp[i - off] : 0;
        __syncthreads();
        tmp[i] += t;
        __syncthreads();
    }
    if (i < nb) sums[i] = tmp[i] - v;   // exclusive
}

// ---------------- radix pass: bin = dest >> 8 (256 nodes/bin) ----------------
// gh laid out [bin][block]; since SBLK==256, flat index (bin*256+b) >> 8 == bin,
// so consumers add hsums[bin] inline (k_hfix pass eliminated).

__global__ __launch_bounds__(256) void k_hist(const int* __restrict__ ecol,
                                              int* __restrict__ gh) {
    __shared__ int lh[NBIN];
    int b = blockIdx.x, t = threadIdx.x;
    for (int i = t; i < NBIN; i += 256) lh[i] = 0;
    __syncthreads();
    int e0 = b * CHUNK;
    for (int i = t; i < CHUNK; i += 256)
        atomicAdd(&lh[ecol[e0 + i] >> 8], 1);
    __syncthreads();
    for (int i = t; i < NBIN; i += 256) gh[i * SBLK + b] = lh[i];
}

// payload: row (17 bits) | (dest & 255) << 17
__global__ __launch_bounds__(256) void k_radix_scatter(
    const int* __restrict__ erow, const int* __restrict__ ecol,
    const int* __restrict__ gpos, const int* __restrict__ hsums,
    int* __restrict__ pairs) {
    __shared__ int lc[NBIN];
    int b = blockIdx.x, t = threadIdx.x;
    for (int i = t; i < NBIN; i += 256) lc[i] = gpos[i * SBLK + b] + hsums[i];
    __syncthreads();
    int e0 = b * CHUNK;
    for (int i = t; i < CHUNK; i += 256) {
        int e = e0 + i;
        int r = erow[e], c = ecol[e];
        int pos = atomicAdd(&lc[c >> 8], 1);
        pairs[pos] = r | ((c & 255) << 17);
    }
}

// one block per bin: per-node degree -> LDS scan -> rp/dinv -> place eidx
__global__ __launch_bounds__(256) void k_binfinish(
    const int* __restrict__ gpos, const int* __restrict__ hsums,
    const int* __restrict__ pairs,
    int* __restrict__ rp, float* __restrict__ dinv, int* __restrict__ eidx) {
    __shared__ int cnt[256];
    __shared__ int tmp[256];
    int b = blockIdx.x, t = threadIdx.x;
    int n0 = b << 8;
    int beg = gpos[b * SBLK] + hsums[b];
    int end = (b + 1 < NBIN) ? gpos[(b + 1) * SBLK] + hsums[b + 1] : N_EDGES;

    cnt[t] = 0;
    __syncthreads();
    for (int i = beg + t; i < end; i += 256)
        atomicAdd(&cnt[(pairs[i] >> 17) & 255], 1);
    __syncthreads();
    int v = cnt[t];
    tmp[t] = v;
    __syncthreads();
    for (int off = 1; off < 256; off <<= 1) {
        int u = (t >= off) ? tmp[t - off] : 0;
        __syncthreads();
        tmp[t] += u;
        __syncthreads();
    }
    int rpv = beg + tmp[t] - v;
    int n = n0 + t;
    if (n < N_NODES) {
        rp[n] = rpv;
        dinv[n] = rsqrtf(1.0f + (float)v);
    }
    if (b == NBIN - 1 && t == 0) rp[N_NODES] = N_EDGES;
    cnt[t] = rpv;
    __syncthreads();
    for (int i = beg + t; i < end; i += 256) {
        int p = pairs[i];
        int pos = atomicAdd(&cnt[(p >> 17) & 255], 1);
        eidx[pos] = p & 0x1FFFF;
    }
}

// -------- weight prep (parallel): Wt0[64][128]=W0^T pad; Wt1[48][64]=W1^T pad
__global__ __launch_bounds__(256) void k_wprep(const float* __restrict__ W0,
                                               const float* __restrict__ W1,
                                               __half* __restrict__ wt0,
                                               __half* __restrict__ wt1) {
    int i = blockIdx.x * 256 + threadIdx.x;
    if (i < WT0_ELEMS) {
        int n = i >> 7, k = i & 127;
        wt0[i] = __float2half((k < N_FEAT) ? W0[k * HIDDEN + n] : 0.0f);
    } else if (i < WT0_ELEMS + WT1_ELEMS) {
        int j = i - WT0_ELEMS;
        int n = j >> 6, k = j & 63;
        wt1[j] = __float2half((n < N_CLASSES) ? W1[k * N_CLASSES + n] : 0.0f);
    }
}

// -------- layer 0 GEMM (MFMA): yh = fp16( dinv[row] * (x @ W0) )
__global__ __launch_bounds__(256) void k_gemm1(
    const float* __restrict__ x, const __half* __restrict__ wt0,
    const float* __restrict__ dinv, __half* __restrict__ yh) {
    int w = threadIdx.x >> 6, l = threadIdx.x & 63;
    int g = l >> 4, c16 = l & 15;
    int row = blockIdx.x * 64 + w * 16 + c16;
    int rl = (row < N_NODES) ? row : (N_NODES - 1);
    const float* xr = x + (size_t)rl * N_FEAT;

    f16x8 a[4];
    #pragma unroll
    for (int s = 0; s < 4; ++s) {
        int k0 = 32 * s + 8 * g;
        float4 f0 = (k0 + 3 < N_FEAT) ? *(const float4*)(xr + k0)
                                      : make_float4(0.f, 0.f, 0.f, 0.f);
        float4 f1 = (k0 + 7 < N_FEAT) ? *(const float4*)(xr + k0 + 4)
                                      : make_float4(0.f, 0.f, 0.f, 0.f);
        a[s][0] = (_Float16)f0.x; a[s][1] = (_Float16)f0.y;
        a[s][2] = (_Float16)f0.z; a[s][3] = (_Float16)f0.w;
        a[s][4] = (_Float16)f1.x; a[s][5] = (_Float16)f1.y;
        a[s][6] = (_Float16)f1.z; a[s][7] = (_Float16)f1.w;
    }
    f32x4 acc0 = {0,0,0,0}, acc1 = {0,0,0,0}, acc2 = {0,0,0,0}, acc3 = {0,0,0,0};
    #pragma unroll
    for (int s = 0; s < 4; ++s) {
        int ko = 32 * s + 8 * g;
        f16x8 b0 = *(const f16x8*)(wt0 + (0 * 16 + c16) * 128 + ko);
        f16x8 b1 = *(const f16x8*)(wt0 + (1 * 16 + c16) * 128 + ko);
        f16x8 b2 = *(const f16x8*)(wt0 + (2 * 16 + c16) * 128 + ko);
        f16x8 b3 = *(const f16x8*)(wt0 + (3 * 16 + c16) * 128 + ko);
        acc0 = __builtin_amdgcn_mfma_f32_16x16x32_f16(a[s], b0, acc0, 0, 0, 0);
        acc1 = __builtin_amdgcn_mfma_f32_16x16x32_f16(a[s], b1, acc1, 0, 0, 0);
        acc2 = __builtin_amdgcn_mfma_f32_16x16x32_f16(a[s], b2, acc2, 0, 0, 0);
        acc3 = __builtin_amdgcn_mfma_f32_16x16x32_f16(a[s], b3, acc3, 0, 0, 0);
    }
    int orow = blockIdx.x * 64 + w * 16 + 4 * g;
    #pragma unroll
    for (int r = 0; r < 4; ++r) {
        if (orow + r < N_NODES) {
            float di = dinv[orow + r];
            size_t base = (size_t)(orow + r) * HIDDEN + c16;
            yh[base +  0] = __float2half(di * acc0[r]);
            yh[base + 16] = __float2half(di * acc1[r]);
            yh[base + 32] = __float2half(di * acc2[r]);
            yh[base + 48] = __float2half(di * acc3[r]);
        }
    }
}

// -------- layer 0 aggregate: hr[n] = relu(dinv[n]*(yh[n]+sum yh[src]) + b0)
// 2 nodes/wave, 32 lanes/node, lane owns a half2; masked 8-batches, no tail.
__global__ __launch_bounds__(256) void k_agg0(
    const int* __restrict__ rp, const int* __restrict__ eidx,
    const float* __restrict__ dinv, const __half* __restrict__ yh,
    const float* __restrict__ b0, __half* __restrict__ hr) {
    int t = blockIdx.x * 256 + threadIdx.x;
    int n = t >> 5;
    int hl = threadIdx.x & 31;
    if (n >= N_NODES) return;
    int beg = rp[n], end = rp[n + 1];
    int deg = end - beg;
    int se = (beg + hl < end) ? eidx[beg + hl] : 0;
    const __half2* yh2 = (const __half2*)yh;
    float2 f = __half22float2(yh2[(size_t)n * 32 + hl]);   // self loop
    float ax = f.x, ay = f.y;
    int m = deg < 32 ? deg : 32;
    int base = threadIdx.x & 32;

    #pragma unroll
    for (int jb = 0; jb < 4; ++jb) {
        int J = jb * 8;
        if (m > J) {
            int s0 = __shfl(se, base + J + 0), s1 = __shfl(se, base + J + 1);
            int s2 = __shfl(se, base + J + 2), s3 = __shfl(se, base + J + 3);
            int s4 = __shfl(se, base + J + 4), s5 = __shfl(se, base + J + 5);
            int s6 = __shfl(se, base + J + 6), s7 = __shfl(se, base + J + 7);
            float2 f0 = __half22float2(yh2[(size_t)s0 * 32 + hl]);
            float2 f1 = __half22float2(yh2[(size_t)s1 * 32 + hl]);
            float2 f2 = __half22float2(yh2[(size_t)s2 * 32 + hl]);
            float2 f3 = __half22float2(yh2[(size_t)s3 * 32 + hl]);
            float2 f4 = __half22float2(yh2[(size_t)s4 * 32 + hl]);
            float2 f5 = __half22float2(yh2[(size_t)s5 * 32 + hl]);
            float2 f6 = __half22float2(yh2[(size_t)s6 * 32 + hl]);
            float2 f7 = __half22float2(yh2[(size_t)s7 * 32 + hl]);
            ax += ((m > J + 0 ? f0.x : 0.f) + (m > J + 1 ? f1.x : 0.f)) +
                  ((m > J + 2 ? f2.x : 0.f) + (m > J + 3 ? f3.x : 0.f)) +
                  ((m > J + 4 ? f4.x : 0.f) + (m > J + 5 ? f5.x : 0.f)) +
                  ((m > J + 6 ? f6.x : 0.f) + (m > J + 7 ? f7.x : 0.f));
            ay += ((m > J + 0 ? f0.y : 0.f) + (m > J + 1 ? f1.y : 0.f)) +
                  ((m > J + 2 ? f2.y : 0.f) + (m > J + 3 ? f3.y : 0.f)) +
                  ((m > J + 4 ? f4.y : 0.f) + (m > J + 5 ? f5.y : 0.f)) +
                  ((m > J + 6 ? f6.y : 0.f) + (m > J + 7 ? f7.y : 0.f));
        }
    }
    if (deg > 32) {
        for (int e = beg + 32; e < end; ++e) {
            int s = eidx[e];
            float2 fv = __half22float2(yh2[(size_t)s * 32 + hl]);
            ax += fv.x; ay += fv.y;
        }
    }
    float di = dinv[n];
    float o0 = fmaxf(di * ax + b0[2 * hl], 0.0f);
    float o1 = fmaxf(di * ay + b0[2 * hl + 1], 0.0f);
    ((__half2*)hr)[(size_t)n * 32 + hl] = __floats2half2_rn(o0, o1);
}

// -------- layer 1 GEMM (MFMA): zh = fp16( dinv[row] * (hr @ W1) ), pad 48 ---
__global__ __launch_bounds__(256) void k_gemm2(
    const __half* __restrict__ hr, const __half* __restrict__ wt1,
    const float* __restrict__ dinv, __half* __restrict__ zh) {
    int w = threadIdx.x >> 6, l = threadIdx.x & 63;
    int g = l >> 4, c16 = l & 15;
    int row = blockIdx.x * 64 + w * 16 + c16;
    int rl = (row < N_NODES) ? row : (N_NODES - 1);

    f16x8 a0 = *(const f16x8*)(hr + (size_t)rl * 64 +  0 + 8 * g);
    f16x8 a1 = *(const f16x8*)(hr + (size_t)rl * 64 + 32 + 8 * g);
    f32x4 acc0 = {0,0,0,0}, acc1 = {0,0,0,0}, acc2 = {0,0,0,0};
    #pragma unroll
    for (int s = 0; s < 2; ++s) {
        int ko = 32 * s + 8 * g;
        f16x8 b0 = *(const f16x8*)(wt1 + (0 * 16 + c16) * 64 + ko);
        f16x8 b1 = *(const f16x8*)(wt1 + (1 * 16 + c16) * 64 + ko);
        f16x8 b2 = *(const f16x8*)(wt1 + (2 * 16 + c16) * 64 + ko);
        f16x8 av = s ? a1 : a0;
        acc0 = __builtin_amdgcn_mfma_f32_16x16x32_f16(av, b0, acc0, 0, 0, 0);
        acc1 = __builtin_amdgcn_mfma_f32_16x16x32_f16(av, b1, acc1, 0, 0, 0);
        acc2 = __builtin_amdgcn_mfma_f32_16x16x32_f16(av, b2, acc2, 0, 0, 0);
    }
    int orow = blockIdx.x * 64 + w * 16 + 4 * g;
    #pragma unroll
    for (int r = 0; r < 4; ++r) {
        if (orow + r < N_NODES) {
            float di = dinv[orow + r];
            size_t base = (size_t)(orow + r) * ZPAD + c16;
            zh[base +  0] = __float2half(di * acc0[r]);
            zh[base + 16] = __float2half(di * acc1[r]);
            zh[base + 32] = __float2half(di * acc2[r]);
        }
    }
}

// -------- layer 1 aggregate: out[n] = dinv[n]*(zh[n]+sum zh[src]) + b1 ------
__global__ __launch_bounds__(256) void k_agg1(
    const int* __restrict__ rp, const int* __restrict__ eidx,
    const float* __restrict__ dinv, const __half* __restrict__ zh,
    const float* __restrict__ b1, float* __restrict__ out) {
    int t = blockIdx.x * 256 + threadIdx.x;
    int n = t >> 5;
    int hl = threadIdx.x & 31;
    if (n >= N_NODES) return;
    int beg = rp[n], end = rp[n + 1];
    int deg = end - beg;
    int se = (beg + hl < end) ? eidx[beg + hl] : 0;
    const __half2* zh2 = (const __half2*)zh;
    float ax = 0.0f, ay = 0.0f;
    if (hl < 24) {
        float2 f = __half22float2(zh2[(size_t)n * 24 + hl]);
        ax = f.x; ay = f.y;
    }
    int m = deg < 32 ? deg : 32;
    int base = threadIdx.x & 32;

    #pragma unroll
    for (int jb = 0; jb < 4; ++jb) {
        int J = jb * 8;
        if (m > J) {
            int s0 = __shfl(se, base + J + 0), s1 = __shfl(se, base + J + 1);
            int s2 = __shfl(se, base + J + 2), s3 = __shfl(se, base + J + 3);
            int s4 = __shfl(se, base + J + 4), s5 = __shfl(se, base + J + 5);
            int s6 = __shfl(se, base + J + 6), s7 = __shfl(se, base + J + 7);
            if (hl < 24) {
                float2 f0 = __half22float2(zh2[(size_t)s0 * 24 + hl]);
                float2 f1 = __half22float2(zh2[(size_t)s1 * 24 + hl]);
                float2 f2 = __half22float2(zh2[(size_t)s2 * 24 + hl]);
                float2 f3 = __half22float2(zh2[(size_t)s3 * 24 + hl]);
                float2 f4 = __half22float2(zh2[(size_t)s4 * 24 + hl]);
                float2 f5 = __half22float2(zh2[(size_t)s5 * 24 + hl]);
                float2 f6 = __half22float2(zh2[(size_t)s6 * 24 + hl]);
                float2 f7 = __half22float2(zh2[(size_t)s7 * 24 + hl]);
                ax += ((m > J + 0 ? f0.x : 0.f) + (m > J + 1 ? f1.x : 0.f)) +
                      ((m > J + 2 ? f2.x : 0.f) + (m > J + 3 ? f3.x : 0.f)) +
                      ((m > J + 4 ? f4.x : 0.f) + (m > J + 5 ? f5.x : 0.f)) +
                      ((m > J + 6 ? f6.x : 0.f) + (m > J + 7 ? f7.x : 0.f));
                ay += ((m > J + 0 ? f0.y : 0.f) + (m > J + 1 ? f1.y : 0.f)) +
                      ((m > J + 2 ? f2.y : 0.f) + (m > J + 3 ? f3.y : 0.f)) +
                      ((m > J + 4 ? f4.y : 0.f) + (m > J + 5 ? f5.y : 0.f)) +
                      ((m > J + 6 ? f6.y : 0.f) + (m > J + 7 ? f7.y : 0.f));
            }
        }
    }
    if (deg > 32) {
        for (int e = beg + 32; e < end; ++e) {
            int s = eidx[e];
            if (hl < 24) {
                float2 fv = __half22float2(zh2[(size_t)s * 24 + hl]);
                ax += fv.x; ay += fv.y;
            }
        }
    }
    if (hl < 24) {
        float di = dinv[n];
        out[(size_t)n * N_CLASSES + 2 * hl] = di * ax + b1[2 * hl];
        if (hl < 23)
            out[(size_t)n * N_CLASSES + 2 * hl + 1] = di * ay + b1[2 * hl + 1];
    }
}

extern "C" void kernel_launch(void* const* d_in, const int* in_sizes, int n_in,
                              void* d_out, int out_size, void* d_ws, size_t ws_size,
                              hipStream_t stream) {
    const float* x  = (const float*)d_in[0];
    const int*   ei = (const int*)d_in[1];
    const float* W0 = (const float*)d_in[2];
    const float* b0 = (const float*)d_in[3];
    const float* W1 = (const float*)d_in[4];
    const float* b1 = (const float*)d_in[5];
    float* out = (float*)d_out;

    char* ws = (char*)d_ws;
    float*  dinv  = (float*)(ws);                         // 400 KB
    int*    rp    = (int*)(ws + 412 * 1024);              // 400 KB + 4
    int*    hsums = (int*)(ws + 824 * 1024);              // 1.6 KB (391 ints)
    int*    gh    = (int*)(ws + 828 * 1024);              // 400 KB -> 1228
    int*    gpos  = (int*)(ws + 1232 * 1024);             // 400 KB -> 1632
    __half* wt0   = (__half*)(ws + 1640 * 1024);          // 16 KB
    __half* wt1   = (__half*)(ws + 1660 * 1024);          // 6 KB
    int*    eidx  = (int*)(ws + 1668 * 1024);             // 6.4 MB -> ~8.1 MB
    __half* yh    = (__half*)(ws + 9ull * 1024 * 1024);   // 12.8 MB -> 21.8 MB
    __half* hr    = (__half*)(ws + 22ull * 1024 * 1024);  // 12.8 MB -> 34.8 MB
    int*    pairs = (int*)hr;   // 6.4 MB alias: dead before k_agg0 writes hr
    __half* zh    = yh;         // alias: yh dead after k_agg0 (9.6 MB used)

    const int* erow = ei;             // edge_index[0] (sources)
    const int* ecol = ei + N_EDGES;   // edge_index[1] (destinations)

    // radix pass: bin histogram -> scan -> scatter -> fused degree+rp+place
    k_hist  <<<SBLK, 256, 0, stream>>>(ecol, gh);
    k_gscan1<<<NBIN, 256, 0, stream>>>(gh, gpos, hsums, NHIST);
    k_gscan2<<<1, 512, 0, stream>>>(hsums, NBIN);
    k_radix_scatter<<<SBLK, 256, 0, stream>>>(erow, ecol, gpos, hsums, pairs);
    k_binfinish<<<NBIN, 256, 0, stream>>>(gpos, hsums, pairs, rp, dinv, eidx);

    k_wprep<<<(WT0_ELEMS + WT1_ELEMS + 255) / 256, 256, 0, stream>>>(W0, W1, wt0, wt1);

    // layer 0
    k_gemm1<<<(N_NODES + 63) / 64, 256, 0, stream>>>(x, wt0, dinv, yh);
    k_agg0 <<<(N_NODES * 32 + 255) / 256, 256, 0, stream>>>(rp, eidx, dinv, yh, b0, hr);

    // layer 1
    k_gemm2<<<(N_NODES + 63) / 64, 256, 0, stream>>>(hr, wt1, dinv, zh);
    k_agg1 <<<(N_NODES * 32 + 255) / 256, 256, 0, stream>>>(rp, eidx, dinv, zh, b1, out);
}

// Round 12
// 137.100 us; speedup vs baseline: 3.7728x; 1.0649x over previous
//
#include <hip/hip_runtime.h>
#include <hip/hip_fp16.h>

#define N_NODES   100000
#define N_EDGES   1600000
#define N_FEAT    100
#define HIDDEN    64
#define N_CLASSES 47
#define ZPAD      48
#define NBIN      ((N_NODES + 255) / 256)   // 391 radix bins (dest >> 8)
#define SBLK      256                        // scatter blocks
#define CHUNK     (N_EDGES / SBLK)           // 6250 edges per scatter block
#define NHIST     (NBIN * SBLK)              // 100096 histogram entries
#define WT0_ELEMS (HIDDEN * 128)             // 8192
#define WT1_ELEMS (ZPAD * 64)                // 3072

typedef _Float16 f16x8 __attribute__((ext_vector_type(8)));
typedef float f32x4 __attribute__((ext_vector_type(4)));

// ---------------- generic 2-level exclusive scan (for bin histogram) -------

__global__ __launch_bounds__(256) void k_gscan1(const int* __restrict__ in,
                                                int* __restrict__ out,
                                                int* __restrict__ sums, int n) {
    __shared__ int tmp[256];
    int i = blockIdx.x * 256 + threadIdx.x;
    int v = (i < n) ? in[i] : 0;
    tmp[threadIdx.x] = v;
    __syncthreads();
    for (int off = 1; off < 256; off <<= 1) {
        int t = (threadIdx.x >= off) ? tmp[threadIdx.x - off] : 0;
        __syncthreads();
        tmp[threadIdx.x] += t;
        __syncthreads();
    }
    if (i < n) out[i] = tmp[threadIdx.x] - v;   // chunk-local exclusive
    if (threadIdx.x == 255) sums[blockIdx.x] = tmp[255];
}

__global__ __launch_bounds__(512) void k_gscan2(int* __restrict__ sums, int nb) {
    __shared__ int tmp[512];
    int i = threadIdx.x;
    int v = (i < nb) ? sums[i] : 0;
    tmp[i] = v;
    __syncthreads();
    for (int off = 1; off < 512; off <<= 1) {
        int t = (i >= off) ? tmp[i - off] : 0;
        __syncthreads();
        tmp[i] += t;
        __syncthreads();
    }
    if (i < nb) sums[i] = tmp[i] - v;   // exclusive
}

// ---------------- radix pass: bin = dest >> 8 (256 nodes/bin) ----------------

__global__ __launch_bounds__(256) void k_hist(const int* __restrict__ ecol,
                                              int* __restrict__ gh) {
    __shared__ int lh[NBIN];
    int b = blockIdx.x, t = threadIdx.x;
    for (int i = t; i < NBIN; i += 256) lh[i] = 0;
    __syncthreads();
    int e0 = b * CHUNK;
    for (int i = t; i < CHUNK; i += 256)
        atomicAdd(&lh[ecol[e0 + i] >> 8], 1);
    __syncthreads();
    for (int i = t; i < NBIN; i += 256) gh[i * SBLK + b] = lh[i];
}

// payload: row (17 bits) | (dest & 255) << 17
__global__ __launch_bounds__(256) void k_radix_scatter(
    const int* __restrict__ erow, const int* __restrict__ ecol,
    const int* __restrict__ gpos, const int* __restrict__ hsums,
    int* __restrict__ pairs) {
    __shared__ int lc[NBIN];
    int b = blockIdx.x, t = threadIdx.x;
    for (int i = t; i < NBIN; i += 256) lc[i] = gpos[i * SBLK + b] + hsums[i];
    __syncthreads();
    int e0 = b * CHUNK;
    for (int i = t; i < CHUNK; i += 256) {
        int e = e0 + i;
        int r = erow[e], c = ecol[e];
        int pos = atomicAdd(&lc[c >> 8], 1);
        pairs[pos] = r | ((c & 255) << 17);
    }
}

// one block per bin: per-node degree -> LDS scan -> rp/dinv -> place eidx
__global__ __launch_bounds__(256) void k_binfinish(
    const int* __restrict__ gpos, const int* __restrict__ hsums,
    const int* __restrict__ pairs,
    int* __restrict__ rp, float* __restrict__ dinv, int* __restrict__ eidx) {
    __shared__ int cnt[256];
    __shared__ int tmp[256];
    int b = blockIdx.x, t = threadIdx.x;
    int n0 = b << 8;
    int beg = gpos[b * SBLK] + hsums[b];
    int end = (b + 1 < NBIN) ? gpos[(b + 1) * SBLK] + hsums[b + 1] : N_EDGES;

    cnt[t] = 0;
    __syncthreads();
    for (int i = beg + t; i < end; i += 256)
        atomicAdd(&cnt[(pairs[i] >> 17) & 255], 1);
    __syncthreads();
    int v = cnt[t];
    tmp[t] = v;
    __syncthreads();
    for (int off = 1; off < 256; off <<= 1) {
        int u = (t >= off) ? tmp[t - off] : 0;
        __syncthreads();
        tmp[t] += u;
        __syncthreads();
    }
    int rpv = beg + tmp[t] - v;
    int n = n0 + t;
    if (n < N_NODES) {
        rp[n] = rpv;
        dinv[n] = rsqrtf(1.0f + (float)v);
    }
    if (b == NBIN - 1 && t == 0) rp[N_NODES] = N_EDGES;
    cnt[t] = rpv;
    __syncthreads();
    for (int i = beg + t; i < end; i += 256) {
        int p = pairs[i];
        int pos = atomicAdd(&cnt[(p >> 17) & 255], 1);
        eidx[pos] = p & 0x1FFFF;
    }
}

// -------- weight prep (parallel): Wt0[64][128]=W0^T pad; Wt1[48][64]=W1^T pad
__global__ __launch_bounds__(256) void k_wprep(const float* __restrict__ W0,
                                               const float* __restrict__ W1,
                                               __half* __restrict__ wt0,
                                               __half* __restrict__ wt1) {
    int i = blockIdx.x * 256 + threadIdx.x;
    if (i < WT0_ELEMS) {
        int n = i >> 7, k = i & 127;
        wt0[i] = __float2half((k < N_FEAT) ? W0[k * HIDDEN + n] : 0.0f);
    } else if (i < WT0_ELEMS + WT1_ELEMS) {
        int j = i - WT0_ELEMS;
        int n = j >> 6, k = j & 63;
        wt1[j] = __float2half((n < N_CLASSES) ? W1[k * N_CLASSES + n] : 0.0f);
    }
}

// -------- layer 0 GEMM (MFMA): yh = fp16( dinv[row] * (x @ W0) )
__global__ __launch_bounds__(256) void k_gemm1(
    const float* __restrict__ x, const __half* __restrict__ wt0,
    const float* __restrict__ dinv, __half* __restrict__ yh) {
    int w = threadIdx.x >> 6, l = threadIdx.x & 63;
    int g = l >> 4, c16 = l & 15;
    int row = blockIdx.x * 64 + w * 16 + c16;
    int rl = (row < N_NODES) ? row : (N_NODES - 1);
    const float* xr = x + (size_t)rl * N_FEAT;

    f16x8 a[4];
    #pragma unroll
    for (int s = 0; s < 4; ++s) {
        int k0 = 32 * s + 8 * g;
        float4 f0 = (k0 + 3 < N_FEAT) ? *(const float4*)(xr + k0)
                                      : make_float4(0.f, 0.f, 0.f, 0.f);
        float4 f1 = (k0 + 7 < N_FEAT) ? *(const float4*)(xr + k0 + 4)
                                      : make_float4(0.f, 0.f, 0.f, 0.f);
        a[s][0] = (_Float16)f0.x; a[s][1] = (_Float16)f0.y;
        a[s][2] = (_Float16)f0.z; a[s][3] = (_Float16)f0.w;
        a[s][4] = (_Float16)f1.x; a[s][5] = (_Float16)f1.y;
        a[s][6] = (_Float16)f1.z; a[s][7] = (_Float16)f1.w;
    }
    f32x4 acc0 = {0,0,0,0}, acc1 = {0,0,0,0}, acc2 = {0,0,0,0}, acc3 = {0,0,0,0};
    #pragma unroll
    for (int s = 0; s < 4; ++s) {
        int ko = 32 * s + 8 * g;
        f16x8 b0 = *(const f16x8*)(wt0 + (0 * 16 + c16) * 128 + ko);
        f16x8 b1 = *(const f16x8*)(wt0 + (1 * 16 + c16) * 128 + ko);
        f16x8 b2 = *(const f16x8*)(wt0 + (2 * 16 + c16) * 128 + ko);
        f16x8 b3 = *(const f16x8*)(wt0 + (3 * 16 + c16) * 128 + ko);
        acc0 = __builtin_amdgcn_mfma_f32_16x16x32_f16(a[s], b0, acc0, 0, 0, 0);
        acc1 = __builtin_amdgcn_mfma_f32_16x16x32_f16(a[s], b1, acc1, 0, 0, 0);
        acc2 = __builtin_amdgcn_mfma_f32_16x16x32_f16(a[s], b2, acc2, 0, 0, 0);
        acc3 = __builtin_amdgcn_mfma_f32_16x16x32_f16(a[s], b3, acc3, 0, 0, 0);
    }
    int orow = blockIdx.x * 64 + w * 16 + 4 * g;
    #pragma unroll
    for (int r = 0; r < 4; ++r) {
        if (orow + r < N_NODES) {
            float di = dinv[orow + r];
            size_t base = (size_t)(orow + r) * HIDDEN + c16;
            yh[base +  0] = __float2half(di * acc0[r]);
            yh[base + 16] = __float2half(di * acc1[r]);
            yh[base + 32] = __float2half(di * acc2[r]);
            yh[base + 48] = __float2half(di * acc3[r]);
        }
    }
}

// -------- fused layer-0 aggregate + layer-1 GEMM --------------------------
// Gather phase: 2 nodes/wave (8 nodes/block), 16-deep masked gather batches;
// post-relu fp16 rows staged in LDS. Epilogue: wave 0 runs gemm2's MFMA on
// the block's 8 rows (A rows 8-15 zeroed) and writes zh = fp16(dinv*(hr@W1)).
// NOTE: zh must NOT alias yh (gathers of yh race with zh writes otherwise).
__global__ __launch_bounds__(256) void k_agg0(
    const int* __restrict__ rp, const int* __restrict__ eidx,
    const float* __restrict__ dinv, const __half* __restrict__ yh,
    const float* __restrict__ b0, const __half* __restrict__ wt1,
    __half* __restrict__ zh) {
    __shared__ __half hs[16][64];   // rows 0-7 = this block's hr; 8-15 zero
    int t = blockIdx.x * 256 + threadIdx.x;
    int n = t >> 5;                 // grid is exactly 12500 blocks: n < N_NODES
    int hl = threadIdx.x & 31;
    int nl = threadIdx.x >> 5;      // node slot 0..7 in block

    ((__half2*)hs)[256 + threadIdx.x] = __floats2half2_rn(0.f, 0.f); // rows 8-15

    int beg = rp[n], end = rp[n + 1];
    int deg = end - beg;
    int se = (beg + hl < end) ? eidx[beg + hl] : 0;
    const __half2* yh2 = (const __half2*)yh;
    float2 fs = __half22float2(yh2[(size_t)n * 32 + hl]);   // self loop
    float ax = fs.x, ay = fs.y;
    int m = deg < 32 ? deg : 32;
    int base = threadIdx.x & 32;

    {   // batch 0: slots 0..15, unconditional (se=0 slots add 0)
        int s0 = __shfl(se, base + 0),  s1 = __shfl(se, base + 1);
        int s2 = __shfl(se, base + 2),  s3 = __shfl(se, base + 3);
        int s4 = __shfl(se, base + 4),  s5 = __shfl(se, base + 5);
        int s6 = __shfl(se, base + 6),  s7 = __shfl(se, base + 7);
        int s8 = __shfl(se, base + 8),  s9 = __shfl(se, base + 9);
        int sa = __shfl(se, base + 10), sb = __shfl(se, base + 11);
        int sc = __shfl(se, base + 12), sd = __shfl(se, base + 13);
        int sec = __shfl(se, base + 14), sf = __shfl(se, base + 15);
        float2 f0 = __half22float2(yh2[(size_t)s0 * 32 + hl]);
        float2 f1 = __half22float2(yh2[(size_t)s1 * 32 + hl]);
        float2 f2 = __half22float2(yh2[(size_t)s2 * 32 + hl]);
        float2 f3 = __half22float2(yh2[(size_t)s3 * 32 + hl]);
        float2 f4 = __half22float2(yh2[(size_t)s4 * 32 + hl]);
        float2 f5 = __half22float2(yh2[(size_t)s5 * 32 + hl]);
        float2 f6 = __half22float2(yh2[(size_t)s6 * 32 + hl]);
        float2 f7 = __half22float2(yh2[(size_t)s7 * 32 + hl]);
        float2 f8 = __half22float2(yh2[(size_t)s8 * 32 + hl]);
        float2 f9 = __half22float2(yh2[(size_t)s9 * 32 + hl]);
        float2 fa = __half22float2(yh2[(size_t)sa * 32 + hl]);
        float2 fb = __half22float2(yh2[(size_t)sb * 32 + hl]);
        float2 fc = __half22float2(yh2[(size_t)sc * 32 + hl]);
        float2 fd = __half22float2(yh2[(size_t)sd * 32 + hl]);
        float2 fe = __half22float2(yh2[(size_t)sec * 32 + hl]);
        float2 ff = __half22float2(yh2[(size_t)sf * 32 + hl]);
        ax += ((m > 0  ? f0.x : 0.f) + (m > 1  ? f1.x : 0.f)) +
              ((m > 2  ? f2.x : 0.f) + (m > 3  ? f3.x : 0.f)) +
              ((m > 4  ? f4.x : 0.f) + (m > 5  ? f5.x : 0.f)) +
              ((m > 6  ? f6.x : 0.f) + (m > 7  ? f7.x : 0.f)) +
              ((m > 8  ? f8.x : 0.f) + (m > 9  ? f9.x : 0.f)) +
              ((m > 10 ? fa.x : 0.f) + (m > 11 ? fb.x : 0.f)) +
              ((m > 12 ? fc.x : 0.f) + (m > 13 ? fd.x : 0.f)) +
              ((m > 14 ? fe.x : 0.f) + (m > 15 ? ff.x : 0.f));
        ay += ((m > 0  ? f0.y : 0.f) + (m > 1  ? f1.y : 0.f)) +
              ((m > 2  ? f2.y : 0.f) + (m > 3  ? f3.y : 0.f)) +
              ((m > 4  ? f4.y : 0.f) + (m > 5  ? f5.y : 0.f)) +
              ((m > 6  ? f6.y : 0.f) + (m > 7  ? f7.y : 0.f)) +
              ((m > 8  ? f8.y : 0.f) + (m > 9  ? f9.y : 0.f)) +
              ((m > 10 ? fa.y : 0.f) + (m > 11 ? fb.y : 0.f)) +
              ((m > 12 ? fc.y : 0.f) + (m > 13 ? fd.y : 0.f)) +
              ((m > 14 ? fe.y : 0.f) + (m > 15 ? ff.y : 0.f));
    }
    if (m > 16) {   // batch 1: slots 16..31
        int s0 = __shfl(se, base + 16), s1 = __shfl(se, base + 17);
        int s2 = __shfl(se, base + 18), s3 = __shfl(se, base + 19);
        int s4 = __shfl(se, base + 20), s5 = __shfl(se, base + 21);
        int s6 = __shfl(se, base + 22), s7 = __shfl(se, base + 23);
        int s8 = __shfl(se, base + 24), s9 = __shfl(se, base + 25);
        int sa = __shfl(se, base + 26), sb = __shfl(se, base + 27);
        int sc = __shfl(se, base + 28), sd = __shfl(se, base + 29);
        int sec = __shfl(se, base + 30), sf = __shfl(se, base + 31);
        float2 f0 = __half22float2(yh2[(size_t)s0 * 32 + hl]);
        float2 f1 = __half22float2(yh2[(size_t)s1 * 32 + hl]);
        float2 f2 = __half22float2(yh2[(size_t)s2 * 32 + hl]);
        float2 f3 = __half22float2(yh2[(size_t)s3 * 32 + hl]);
        float2 f4 = __half22float2(yh2[(size_t)s4 * 32 + hl]);
        float2 f5 = __half22float2(yh2[(size_t)s5 * 32 + hl]);
        float2 f6 = __half22float2(yh2[(size_t)s6 * 32 + hl]);
        float2 f7 = __half22float2(yh2[(size_t)s7 * 32 + hl]);
        float2 f8 = __half22float2(yh2[(size_t)s8 * 32 + hl]);
        float2 f9 = __half22float2(yh2[(size_t)s9 * 32 + hl]);
        float2 fa = __half22float2(yh2[(size_t)sa * 32 + hl]);
        float2 fb = __half22float2(yh2[(size_t)sb * 32 + hl]);
        float2 fc = __half22float2(yh2[(size_t)sc * 32 + hl]);
        float2 fd = __half22float2(yh2[(size_t)sd * 32 + hl]);
        float2 fe = __half22float2(yh2[(size_t)sec * 32 + hl]);
        float2 ff = __half22float2(yh2[(size_t)sf * 32 + hl]);
        ax += ((m > 16 ? f0.x : 0.f) + (m > 17 ? f1.x : 0.f)) +
              ((m > 18 ? f2.x : 0.f) + (m > 19 ? f3.x : 0.f)) +
              ((m > 20 ? f4.x : 0.f) + (m > 21 ? f5.x : 0.f)) +
              ((m > 22 ? f6.x : 0.f) + (m > 23 ? f7.x : 0.f)) +
              ((m > 24 ? f8.x : 0.f) + (m > 25 ? f9.x : 0.f)) +
              ((m > 26 ? fa.x : 0.f) + (m > 27 ? fb.x : 0.f)) +
              ((m > 28 ? fc.x : 0.f) + (m > 29 ? fd.x : 0.f)) +
              ((m > 30 ? fe.x : 0.f) + (m > 31 ? ff.x : 0.f));
        ay += ((m > 16 ? f0.y : 0.f) + (m > 17 ? f1.y : 0.f)) +
              ((m > 18 ? f2.y : 0.f) + (m > 19 ? f3.y : 0.f)) +
              ((m > 20 ? f4.y : 0.f) + (m > 21 ? f5.y : 0.f)) +
              ((m > 22 ? f6.y : 0.f) + (m > 23 ? f7.y : 0.f)) +
              ((m > 24 ? f8.y : 0.f) + (m > 25 ? f9.y : 0.f)) +
              ((m > 26 ? fa.y : 0.f) + (m > 27 ? fb.y : 0.f)) +
              ((m > 28 ? fc.y : 0.f) + (m > 29 ? fd.y : 0.f)) +
              ((m > 30 ? fe.y : 0.f) + (m > 31 ? ff.y : 0.f));
    }
    if (deg > 32) {
        for (int e = beg + 32; e < end; ++e) {
            int s = eidx[e];
            float2 fv = __half22float2(yh2[(size_t)s * 32 + hl]);
            ax += fv.x; ay += fv.y;
        }
    }
    float di = dinv[n];
    float2 b2 = ((const float2*)b0)[hl];
    float o0 = fmaxf(di * ax + b2.x, 0.0f);
    float o1 = fmaxf(di * ay + b2.y, 0.0f);
    ((__half2*)hs)[nl * 32 + hl] = __floats2half2_rn(o0, o1);
    __syncthreads();

    // ---- epilogue: wave 0 computes zh rows for the block's 8 nodes -------
    if (threadIdx.x < 64) {
        int l = threadIdx.x;
        int g = l >> 4, c16 = l & 15;
        f16x8 a0 = *(const f16x8*)(&hs[c16][8 * g]);
        f16x8 a1 = *(const f16x8*)(&hs[c16][32 + 8 * g]);
        f32x4 acc0 = {0,0,0,0}, acc1 = {0,0,0,0}, acc2 = {0,0,0,0};
        #pragma unroll
        for (int s = 0; s < 2; ++s) {
            int ko = 32 * s + 8 * g;
            f16x8 b0f = *(const f16x8*)(wt1 + (0 * 16 + c16) * 64 + ko);
            f16x8 b1f = *(const f16x8*)(wt1 + (1 * 16 + c16) * 64 + ko);
            f16x8 b2f = *(const f16x8*)(wt1 + (2 * 16 + c16) * 64 + ko);
            f16x8 av = s ? a1 : a0;
            acc0 = __builtin_amdgcn_mfma_f32_16x16x32_f16(av, b0f, acc0, 0, 0, 0);
            acc1 = __builtin_amdgcn_mfma_f32_16x16x32_f16(av, b1f, acc1, 0, 0, 0);
            acc2 = __builtin_amdgcn_mfma_f32_16x16x32_f16(av, b2f, acc2, 0, 0, 0);
        }
        if (g < 2) {   // D rows 0..7 are the valid ones
            int nrow = blockIdx.x * 8 + 4 * g;
            #pragma unroll
            for (int r = 0; r < 4; ++r) {
                float dr = dinv[nrow + r];
                size_t bz = (size_t)(nrow + r) * ZPAD + c16;
                zh[bz +  0] = __float2half(dr * acc0[r]);
                zh[bz + 16] = __float2half(dr * acc1[r]);
                zh[bz + 32] = __float2half(dr * acc2[r]);
            }
        }
    }
}

// -------- layer 1 aggregate: out[n] = dinv[n]*(zh[n]+sum zh[src]) + b1 ------
__global__ __launch_bounds__(256) void k_agg1(
    const int* __restrict__ rp, const int* __restrict__ eidx,
    const float* __restrict__ dinv, const __half* __restrict__ zh,
    const float* __restrict__ b1, float* __restrict__ out) {
    int t = blockIdx.x * 256 + threadIdx.x;
    int n = t >> 5;
    int hl = threadIdx.x & 31;
    if (n >= N_NODES) return;
    int beg = rp[n], end = rp[n + 1];
    int deg = end - beg;
    int se = (beg + hl < end) ? eidx[beg + hl] : 0;
    const __half2* zh2 = (const __half2*)zh;
    float ax = 0.0f, ay = 0.0f;
    if (hl < 24) {
        float2 f = __half22float2(zh2[(size_t)n * 24 + hl]);
        ax = f.x; ay = f.y;
    }
    int m = deg < 32 ? deg : 32;
    int base = threadIdx.x & 32;

    {   // batch 0: slots 0..15, unconditional
        int s0 = __shfl(se, base + 0),  s1 = __shfl(se, base + 1);
        int s2 = __shfl(se, base + 2),  s3 = __shfl(se, base + 3);
        int s4 = __shfl(se, base + 4),  s5 = __shfl(se, base + 5);
        int s6 = __shfl(se, base + 6),  s7 = __shfl(se, base + 7);
        int s8 = __shfl(se, base + 8),  s9 = __shfl(se, base + 9);
        int sa = __shfl(se, base + 10), sb = __shfl(se, base + 11);
        int sc = __shfl(se, base + 12), sd = __shfl(se, base + 13);
        int sec = __shfl(se, base + 14), sf = __shfl(se, base + 15);
        if (hl < 24) {
            float2 f0 = __half22float2(zh2[(size_t)s0 * 24 + hl]);
            float2 f1 = __half22float2(zh2[(size_t)s1 * 24 + hl]);
            float2 f2 = __half22float2(zh2[(size_t)s2 * 24 + hl]);
            float2 f3 = __half22float2(zh2[(size_t)s3 * 24 + hl]);
            float2 f4 = __half22float2(zh2[(size_t)s4 * 24 + hl]);
            float2 f5 = __half22float2(zh2[(size_t)s5 * 24 + hl]);
            float2 f6 = __half22float2(zh2[(size_t)s6 * 24 + hl]);
            float2 f7 = __half22float2(zh2[(size_t)s7 * 24 + hl]);
            float2 f8 = __half22float2(zh2[(size_t)s8 * 24 + hl]);
            float2 f9 = __half22float2(zh2[(size_t)s9 * 24 + hl]);
            float2 fa = __half22float2(zh2[(size_t)sa * 24 + hl]);
            float2 fb = __half22float2(zh2[(size_t)sb * 24 + hl]);
            float2 fc = __half22float2(zh2[(size_t)sc * 24 + hl]);
            float2 fd = __half22float2(zh2[(size_t)sd * 24 + hl]);
            float2 fe = __half22float2(zh2[(size_t)sec * 24 + hl]);
            float2 ff = __half22float2(zh2[(size_t)sf * 24 + hl]);
            ax += ((m > 0  ? f0.x : 0.f) + (m > 1  ? f1.x : 0.f)) +
                  ((m > 2  ? f2.x : 0.f) + (m > 3  ? f3.x : 0.f)) +
                  ((m > 4  ? f4.x : 0.f) + (m > 5  ? f5.x : 0.f)) +
                  ((m > 6  ? f6.x : 0.f) + (m > 7  ? f7.x : 0.f)) +
                  ((m > 8  ? f8.x : 0.f) + (m > 9  ? f9.x : 0.f)) +
                  ((m > 10 ? fa.x : 0.f) + (m > 11 ? fb.x : 0.f)) +
                  ((m > 12 ? fc.x : 0.f) + (m > 13 ? fd.x : 0.f)) +
                  ((m > 14 ? fe.x : 0.f) + (m > 15 ? ff.x : 0.f));
            ay += ((m > 0  ? f0.y : 0.f) + (m > 1  ? f1.y : 0.f)) +
                  ((m > 2  ? f2.y : 0.f) + (m > 3  ? f3.y : 0.f)) +
                  ((m > 4  ? f4.y : 0.f) + (m > 5  ? f5.y : 0.f)) +
                  ((m > 6  ? f6.y : 0.f) + (m > 7  ? f7.y : 0.f)) +
                  ((m > 8  ? f8.y : 0.f) + (m > 9  ? f9.y : 0.f)) +
                  ((m > 10 ? fa.y : 0.f) + (m > 11 ? fb.y : 0.f)) +
                  ((m > 12 ? fc.y : 0.f) + (m > 13 ? fd.y : 0.f)) +
                  ((m > 14 ? fe.y : 0.f) + (m > 15 ? ff.y : 0.f));
        }
    }
    if (m > 16) {   // batch 1: slots 16..31
        int s0 = __shfl(se, base + 16), s1 = __shfl(se, base + 17);
        int s2 = __shfl(se, base + 18), s3 = __shfl(se, base + 19);
        int s4 = __shfl(se, base + 20), s5 = __shfl(se, base + 21);
        int s6 = __shfl(se, base + 22), s7 = __shfl(se, base + 23);
        int s8 = __shfl(se, base + 24), s9 = __shfl(se, base + 25);
        int sa = __shfl(se, base + 26), sb = __shfl(se, base + 27);
        int sc = __shfl(se, base + 28), sd = __shfl(se, base + 29);
        int sec = __shfl(se, base + 30), sf = __shfl(se, base + 31);
        if (hl < 24) {
            float2 f0 = __half22float2(zh2[(size_t)s0 * 24 + hl]);
            float2 f1 = __half22float2(zh2[(size_t)s1 * 24 + hl]);
            float2 f2 = __half22float2(zh2[(size_t)s2 * 24 + hl]);
            float2 f3 = __half22float2(zh2[(size_t)s3 * 24 + hl]);
            float2 f4 = __half22float2(zh2[(size_t)s4 * 24 + hl]);
            float2 f5 = __half22float2(zh2[(size_t)s5 * 24 + hl]);
            float2 f6 = __half22float2(zh2[(size_t)s6 * 24 + hl]);
            float2 f7 = __half22float2(zh2[(size_t)s7 * 24 + hl]);
            float2 f8 = __half22float2(zh2[(size_t)s8 * 24 + hl]);
            float2 f9 = __half22float2(zh2[(size_t)s9 * 24 + hl]);
            float2 fa = __half22float2(zh2[(size_t)sa * 24 + hl]);
            float2 fb = __half22float2(zh2[(size_t)sb * 24 + hl]);
            float2 fc = __half22float2(zh2[(size_t)sc * 24 + hl]);
            float2 fd = __half22float2(zh2[(size_t)sd * 24 + hl]);
            float2 fe = __half22float2(zh2[(size_t)sec * 24 + hl]);
            float2 ff = __half22float2(zh2[(size_t)sf * 24 + hl]);
            ax += ((m > 16 ? f0.x : 0.f) + (m > 17 ? f1.x : 0.f)) +
                  ((m > 18 ? f2.x : 0.f) + (m > 19 ? f3.x : 0.f)) +
                  ((m > 20 ? f4.x : 0.f) + (m > 21 ? f5.x : 0.f)) +
                  ((m > 22 ? f6.x : 0.f) + (m > 23 ? f7.x : 0.f)) +
                  ((m > 24 ? f8.x : 0.f) + (m > 25 ? f9.x : 0.f)) +
                  ((m > 26 ? fa.x : 0.f) + (m > 27 ? fb.x : 0.f)) +
                  ((m > 28 ? fc.x : 0.f) + (m > 29 ? fd.x : 0.f)) +
                  ((m > 30 ? fe.x : 0.f) + (m > 31 ? ff.x : 0.f));
            ay += ((m > 16 ? f0.y : 0.f) + (m > 17 ? f1.y : 0.f)) +
                  ((m > 18 ? f2.y : 0.f) + (m > 19 ? f3.y : 0.f)) +
                  ((m > 20 ? f4.y : 0.f) + (m > 21 ? f5.y : 0.f)) +
                  ((m > 22 ? f6.y : 0.f) + (m > 23 ? f7.y : 0.f)) +
                  ((m > 24 ? f8.y : 0.f) + (m > 25 ? f9.y : 0.f)) +
                  ((m > 26 ? fa.y : 0.f) + (m > 27 ? fb.y : 0.f)) +
                  ((m > 28 ? fc.y : 0.f) + (m > 29 ? fd.y : 0.f)) +
                  ((m > 30 ? fe.y : 0.f) + (m > 31 ? ff.y : 0.f));
        }
    }
    if (deg > 32) {
        for (int e = beg + 32; e < end; ++e) {
            int s = eidx[e];
            if (hl < 24) {
                float2 fv = __half22float2(zh2[(size_t)s * 24 + hl]);
                ax += fv.x; ay += fv.y;
            }
        }
    }
    if (hl < 24) {
        float di = dinv[n];
        out[(size_t)n * N_CLASSES + 2 * hl] = di * ax + b1[2 * hl];
        if (hl < 23)
            out[(size_t)n * N_CLASSES + 2 * hl + 1] = di * ay + b1[2 * hl + 1];
    }
}

extern "C" void kernel_launch(void* const* d_in, const int* in_sizes, int n_in,
                              void* d_out, int out_size, void* d_ws, size_t ws_size,
                              hipStream_t stream) {
    const float* x  = (const float*)d_in[0];
    const int*   ei = (const int*)d_in[1];
    const float* W0 = (const float*)d_in[2];
    const float* b0 = (const float*)d_in[3];
    const float* W1 = (const float*)d_in[4];
    const float* b1 = (const float*)d_in[5];
    float* out = (float*)d_out;

    char* ws = (char*)d_ws;
    float*  dinv  = (float*)(ws);                         // 400 KB
    int*    rp    = (int*)(ws + 412 * 1024);              // 400 KB + 4
    int*    hsums = (int*)(ws + 824 * 1024);              // 1.6 KB (391 ints)
    int*    gh    = (int*)(ws + 828 * 1024);              // 400 KB
    int*    gpos  = (int*)(ws + 1232 * 1024);             // 400 KB
    __half* wt0   = (__half*)(ws + 1640 * 1024);          // 16 KB
    __half* wt1   = (__half*)(ws + 1660 * 1024);          // 6 KB
    int*    eidx  = (int*)(ws + 1668 * 1024);             // 6.4 MB -> ~8.1 MB
    __half* yh    = (__half*)(ws + 9ull * 1024 * 1024);   // 12.8 MB -> 21.8 MB
    __half* zh    = (__half*)(ws + 22ull * 1024 * 1024);  // 9.6 MB (own buffer!)
    int*    pairs = (int*)zh;   // 6.4 MB alias: dead before k_agg0 writes zh

    const int* erow = ei;             // edge_index[0] (sources)
    const int* ecol = ei + N_EDGES;   // edge_index[1] (destinations)

    // radix pass: bin histogram -> scan -> scatter -> fused degree+rp+place
    k_hist  <<<SBLK, 256, 0, stream>>>(ecol, gh);
    k_gscan1<<<NBIN, 256, 0, stream>>>(gh, gpos, hsums, NHIST);
    k_gscan2<<<1, 512, 0, stream>>>(hsums, NBIN);
    k_radix_scatter<<<SBLK, 256, 0, stream>>>(erow, ecol, gpos, hsums, pairs);
    k_binfinish<<<NBIN, 256, 0, stream>>>(gpos, hsums, pairs, rp, dinv, eidx);

    k_wprep<<<(WT0_ELEMS + WT1_ELEMS + 255) / 256, 256, 0, stream>>>(W0, W1, wt0, wt1);

    // layer 0 GEMM, then fused (layer-0 aggregate + layer-1 GEMM)
    k_gemm1<<<(N_NODES + 63) / 64, 256, 0, stream>>>(x, wt0, dinv, yh);
    k_agg0 <<<(N_NODES * 32) / 256, 256, 0, stream>>>(rp, eidx, dinv, yh, b0, wt1, zh);

    // layer 1 aggregate
    k_agg1 <<<(N_NODES * 32) / 256, 256, 0, stream>>>(rp, eidx, dinv, zh, b1, out);
}

// Round 13
// 133.479 us; speedup vs baseline: 3.8751x; 1.0271x over previous
//
#include <hip/hip_runtime.h>
#include <hip/hip_fp16.h>

#define N_NODES   100000
#define N_EDGES   1600000
#define N_FEAT    100
#define HIDDEN    64
#define N_CLASSES 47
#define ZPAD      48
#define NBIN      ((N_NODES + 255) / 256)   // 391 radix bins (dest >> 8)
#define SBLK      512                        // scatter blocks
#define CHUNK     (N_EDGES / SBLK)           // 3125 edges per scatter block
#define NHIST     (NBIN * SBLK)              // 200192 histogram entries
#define WT0_ELEMS (HIDDEN * 128)             // 8192
#define WT1_ELEMS (ZPAD * 64)                // 3072
#define WPREP_N   (WT0_ELEMS + WT1_ELEMS)    // 11264 (= 44 blocks of 256)

typedef _Float16 f16x8 __attribute__((ext_vector_type(8)));
typedef float f32x4 __attribute__((ext_vector_type(4)));

// ---------------- scan: 512-thread blocks, one block per bin ----------------

__global__ __launch_bounds__(512) void k_gscan1(const int* __restrict__ in,
                                                int* __restrict__ out,
                                                int* __restrict__ sums, int n) {
    __shared__ int tmp[512];
    int i = blockIdx.x * 512 + threadIdx.x;
    int v = (i < n) ? in[i] : 0;
    tmp[threadIdx.x] = v;
    __syncthreads();
    for (int off = 1; off < 512; off <<= 1) {
        int t = (threadIdx.x >= off) ? tmp[threadIdx.x - off] : 0;
        __syncthreads();
        tmp[threadIdx.x] += t;
        __syncthreads();
    }
    if (i < n) out[i] = tmp[threadIdx.x] - v;   // bin-local exclusive
    if (threadIdx.x == 511) sums[blockIdx.x] = tmp[511];
}

__global__ __launch_bounds__(512) void k_gscan2(int* __restrict__ sums, int nb) {
    __shared__ int tmp[512];
    int i = threadIdx.x;
    int v = (i < nb) ? sums[i] : 0;
    tmp[i] = v;
    __syncthreads();
    for (int off = 1; off < 512; off <<= 1) {
        int t = (i >= off) ? tmp[i - off] : 0;
        __syncthreads();
        tmp[i] += t;
        __syncthreads();
    }
    if (i < nb) sums[i] = tmp[i] - v;   // exclusive
}

// ---------------- radix pass: bin = dest >> 8 (256 nodes/bin) ----------------
// gh laid out [bin][block] with SBLK=512: flat (bin*512+b) >> 9 == bin, and
// k_gscan1's 512-thread blocks align 1:1 with bins -> hsums[bin] added inline.

// fused: blocks 0..43 also do the weight transpose (wprep)
__global__ __launch_bounds__(256) void k_hist(const int* __restrict__ ecol,
                                              int* __restrict__ gh,
                                              const float* __restrict__ W0,
                                              const float* __restrict__ W1,
                                              __half* __restrict__ wt0,
                                              __half* __restrict__ wt1) {
    int wi = blockIdx.x * 256 + threadIdx.x;
    if (wi < WT0_ELEMS) {
        int n = wi >> 7, k = wi & 127;
        wt0[wi] = __float2half((k < N_FEAT) ? W0[k * HIDDEN + n] : 0.0f);
    } else if (wi < WPREP_N) {
        int j = wi - WT0_ELEMS;
        int n = j >> 6, k = j & 63;
        wt1[j] = __float2half((n < N_CLASSES) ? W1[k * N_CLASSES + n] : 0.0f);
    }

    __shared__ int lh[NBIN];
    int b = blockIdx.x, t = threadIdx.x;
    for (int i = t; i < NBIN; i += 256) lh[i] = 0;
    __syncthreads();
    int e0 = b * CHUNK;
    for (int i = t; i < CHUNK; i += 256)
        atomicAdd(&lh[ecol[e0 + i] >> 8], 1);
    __syncthreads();
    for (int i = t; i < NBIN; i += 256) gh[i * SBLK + b] = lh[i];
}

// payload: row (17 bits) | (dest & 255) << 17
__global__ __launch_bounds__(256) void k_radix_scatter(
    const int* __restrict__ erow, const int* __restrict__ ecol,
    const int* __restrict__ gpos, const int* __restrict__ hsums,
    int* __restrict__ pairs) {
    __shared__ int lc[NBIN];
    int b = blockIdx.x, t = threadIdx.x;
    for (int i = t; i < NBIN; i += 256) lc[i] = gpos[i * SBLK + b] + hsums[i];
    __syncthreads();
    int e0 = b * CHUNK;
    for (int i = t; i < CHUNK; i += 256) {
        int e = e0 + i;
        int r = erow[e], c = ecol[e];
        int pos = atomicAdd(&lc[c >> 8], 1);
        pairs[pos] = r | ((c & 255) << 17);
    }
}

// one block per bin, 1024 threads: degree count -> LDS scan -> rp/dinv -> place
__global__ __launch_bounds__(1024) void k_binfinish(
    const int* __restrict__ gpos, const int* __restrict__ hsums,
    const int* __restrict__ pairs,
    int* __restrict__ rp, float* __restrict__ dinv, int* __restrict__ eidx) {
    __shared__ int cnt[256];
    __shared__ int tmp[256];
    int b = blockIdx.x, t = threadIdx.x;
    int n0 = b << 8;
    int beg = gpos[b * SBLK] + hsums[b];
    int end = (b + 1 < NBIN) ? gpos[(b + 1) * SBLK] + hsums[b + 1] : N_EDGES;

    if (t < 256) cnt[t] = 0;
    __syncthreads();
    for (int i = beg + t; i < end; i += 1024)
        atomicAdd(&cnt[(pairs[i] >> 17) & 255], 1);
    __syncthreads();
    int v = 0;
    if (t < 256) { v = cnt[t]; tmp[t] = v; }
    __syncthreads();
    for (int off = 1; off < 256; off <<= 1) {
        int u = (t < 256 && t >= off) ? tmp[t - off] : 0;
        __syncthreads();
        if (t < 256) tmp[t] += u;
        __syncthreads();
    }
    if (t < 256) {
        int rpv = beg + tmp[t] - v;
        int n = n0 + t;
        if (n < N_NODES) {
            rp[n] = rpv;
            dinv[n] = rsqrtf(1.0f + (float)v);
        }
        cnt[t] = rpv;   // placement cursor
    }
    if (b == NBIN - 1 && t == 0) rp[N_NODES] = N_EDGES;
    __syncthreads();
    for (int i = beg + t; i < end; i += 1024) {
        int p = pairs[i];
        int pos = atomicAdd(&cnt[(p >> 17) & 255], 1);
        eidx[pos] = p & 0x1FFFF;
    }
}

// -------- layer 0 GEMM (MFMA): yh = fp16( dinv[row] * (x @ W0) )
__global__ __launch_bounds__(256) void k_gemm1(
    const float* __restrict__ x, const __half* __restrict__ wt0,
    const float* __restrict__ dinv, __half* __restrict__ yh) {
    int w = threadIdx.x >> 6, l = threadIdx.x & 63;
    int g = l >> 4, c16 = l & 15;
    int row = blockIdx.x * 64 + w * 16 + c16;
    int rl = (row < N_NODES) ? row : (N_NODES - 1);
    const float* xr = x + (size_t)rl * N_FEAT;

    f16x8 a[4];
    #pragma unroll
    for (int s = 0; s < 4; ++s) {
        int k0 = 32 * s + 8 * g;
        float4 f0 = (k0 + 3 < N_FEAT) ? *(const float4*)(xr + k0)
                                      : make_float4(0.f, 0.f, 0.f, 0.f);
        float4 f1 = (k0 + 7 < N_FEAT) ? *(const float4*)(xr + k0 + 4)
                                      : make_float4(0.f, 0.f, 0.f, 0.f);
        a[s][0] = (_Float16)f0.x; a[s][1] = (_Float16)f0.y;
        a[s][2] = (_Float16)f0.z; a[s][3] = (_Float16)f0.w;
        a[s][4] = (_Float16)f1.x; a[s][5] = (_Float16)f1.y;
        a[s][6] = (_Float16)f1.z; a[s][7] = (_Float16)f1.w;
    }
    f32x4 acc0 = {0,0,0,0}, acc1 = {0,0,0,0}, acc2 = {0,0,0,0}, acc3 = {0,0,0,0};
    #pragma unroll
    for (int s = 0; s < 4; ++s) {
        int ko = 32 * s + 8 * g;
        f16x8 b0 = *(const f16x8*)(wt0 + (0 * 16 + c16) * 128 + ko);
        f16x8 b1 = *(const f16x8*)(wt0 + (1 * 16 + c16) * 128 + ko);
        f16x8 b2 = *(const f16x8*)(wt0 + (2 * 16 + c16) * 128 + ko);
        f16x8 b3 = *(const f16x8*)(wt0 + (3 * 16 + c16) * 128 + ko);
        acc0 = __builtin_amdgcn_mfma_f32_16x16x32_f16(a[s], b0, acc0, 0, 0, 0);
        acc1 = __builtin_amdgcn_mfma_f32_16x16x32_f16(a[s], b1, acc1, 0, 0, 0);
        acc2 = __builtin_amdgcn_mfma_f32_16x16x32_f16(a[s], b2, acc2, 0, 0, 0);
        acc3 = __builtin_amdgcn_mfma_f32_16x16x32_f16(a[s], b3, acc3, 0, 0, 0);
    }
    int orow = blockIdx.x * 64 + w * 16 + 4 * g;
    #pragma unroll
    for (int r = 0; r < 4; ++r) {
        if (orow + r < N_NODES) {
            float di = dinv[orow + r];
            size_t base = (size_t)(orow + r) * HIDDEN + c16;
            yh[base +  0] = __float2half(di * acc0[r]);
            yh[base + 16] = __float2half(di * acc1[r]);
            yh[base + 32] = __float2half(di * acc2[r]);
            yh[base + 48] = __float2half(di * acc3[r]);
        }
    }
}

// -------- fused layer-0 aggregate + layer-1 GEMM --------------------------
__global__ __launch_bounds__(256) void k_agg0(
    const int* __restrict__ rp, const int* __restrict__ eidx,
    const float* __restrict__ dinv, const __half* __restrict__ yh,
    const float* __restrict__ b0, const __half* __restrict__ wt1,
    __half* __restrict__ zh) {
    __shared__ __half hs[16][64];   // rows 0-7 = this block's hr; 8-15 zero
    int t = blockIdx.x * 256 + threadIdx.x;
    int n = t >> 5;                 // grid exactly 12500 blocks: n < N_NODES
    int hl = threadIdx.x & 31;
    int nl = threadIdx.x >> 5;

    ((__half2*)hs)[256 + threadIdx.x] = __floats2half2_rn(0.f, 0.f); // rows 8-15

    int beg = rp[n], end = rp[n + 1];
    int deg = end - beg;
    int se = (beg + hl < end) ? eidx[beg + hl] : 0;
    const __half2* yh2 = (const __half2*)yh;
    float2 fs = __half22float2(yh2[(size_t)n * 32 + hl]);   // self loop
    float ax = fs.x, ay = fs.y;
    int m = deg < 32 ? deg : 32;
    int base = threadIdx.x & 32;

    {   // batch 0: slots 0..15, unconditional (se=0 slots add 0)
        int s0 = __shfl(se, base + 0),  s1 = __shfl(se, base + 1);
        int s2 = __shfl(se, base + 2),  s3 = __shfl(se, base + 3);
        int s4 = __shfl(se, base + 4),  s5 = __shfl(se, base + 5);
        int s6 = __shfl(se, base + 6),  s7 = __shfl(se, base + 7);
        int s8 = __shfl(se, base + 8),  s9 = __shfl(se, base + 9);
        int sa = __shfl(se, base + 10), sb = __shfl(se, base + 11);
        int sc = __shfl(se, base + 12), sd = __shfl(se, base + 13);
        int sec = __shfl(se, base + 14), sf = __shfl(se, base + 15);
        float2 f0 = __half22float2(yh2[(size_t)s0 * 32 + hl]);
        float2 f1 = __half22float2(yh2[(size_t)s1 * 32 + hl]);
        float2 f2 = __half22float2(yh2[(size_t)s2 * 32 + hl]);
        float2 f3 = __half22float2(yh2[(size_t)s3 * 32 + hl]);
        float2 f4 = __half22float2(yh2[(size_t)s4 * 32 + hl]);
        float2 f5 = __half22float2(yh2[(size_t)s5 * 32 + hl]);
        float2 f6 = __half22float2(yh2[(size_t)s6 * 32 + hl]);
        float2 f7 = __half22float2(yh2[(size_t)s7 * 32 + hl]);
        float2 f8 = __half22float2(yh2[(size_t)s8 * 32 + hl]);
        float2 f9 = __half22float2(yh2[(size_t)s9 * 32 + hl]);
        float2 fa = __half22float2(yh2[(size_t)sa * 32 + hl]);
        float2 fb = __half22float2(yh2[(size_t)sb * 32 + hl]);
        float2 fc = __half22float2(yh2[(size_t)sc * 32 + hl]);
        float2 fd = __half22float2(yh2[(size_t)sd * 32 + hl]);
        float2 fe = __half22float2(yh2[(size_t)sec * 32 + hl]);
        float2 ff = __half22float2(yh2[(size_t)sf * 32 + hl]);
        ax += ((m > 0  ? f0.x : 0.f) + (m > 1  ? f1.x : 0.f)) +
              ((m > 2  ? f2.x : 0.f) + (m > 3  ? f3.x : 0.f)) +
              ((m > 4  ? f4.x : 0.f) + (m > 5  ? f5.x : 0.f)) +
              ((m > 6  ? f6.x : 0.f) + (m > 7  ? f7.x : 0.f)) +
              ((m > 8  ? f8.x : 0.f) + (m > 9  ? f9.x : 0.f)) +
              ((m > 10 ? fa.x : 0.f) + (m > 11 ? fb.x : 0.f)) +
              ((m > 12 ? fc.x : 0.f) + (m > 13 ? fd.x : 0.f)) +
              ((m > 14 ? fe.x : 0.f) + (m > 15 ? ff.x : 0.f));
        ay += ((m > 0  ? f0.y : 0.f) + (m > 1  ? f1.y : 0.f)) +
              ((m > 2  ? f2.y : 0.f) + (m > 3  ? f3.y : 0.f)) +
              ((m > 4  ? f4.y : 0.f) + (m > 5  ? f5.y : 0.f)) +
              ((m > 6  ? f6.y : 0.f) + (m > 7  ? f7.y : 0.f)) +
              ((m > 8  ? f8.y : 0.f) + (m > 9  ? f9.y : 0.f)) +
              ((m > 10 ? fa.y : 0.f) + (m > 11 ? fb.y : 0.f)) +
              ((m > 12 ? fc.y : 0.f) + (m > 13 ? fd.y : 0.f)) +
              ((m > 14 ? fe.y : 0.f) + (m > 15 ? ff.y : 0.f));
    }
    if (m > 16) {   // batch 1: slots 16..31
        int s0 = __shfl(se, base + 16), s1 = __shfl(se, base + 17);
        int s2 = __shfl(se, base + 18), s3 = __shfl(se, base + 19);
        int s4 = __shfl(se, base + 20), s5 = __shfl(se, base + 21);
        int s6 = __shfl(se, base + 22), s7 = __shfl(se, base + 23);
        int s8 = __shfl(se, base + 24), s9 = __shfl(se, base + 25);
        int sa = __shfl(se, base + 26), sb = __shfl(se, base + 27);
        int sc = __shfl(se, base + 28), sd = __shfl(se, base + 29);
        int sec = __shfl(se, base + 30), sf = __shfl(se, base + 31);
        float2 f0 = __half22float2(yh2[(size_t)s0 * 32 + hl]);
        float2 f1 = __half22float2(yh2[(size_t)s1 * 32 + hl]);
        float2 f2 = __half22float2(yh2[(size_t)s2 * 32 + hl]);
        float2 f3 = __half22float2(yh2[(size_t)s3 * 32 + hl]);
        float2 f4 = __half22float2(yh2[(size_t)s4 * 32 + hl]);
        float2 f5 = __half22float2(yh2[(size_t)s5 * 32 + hl]);
        float2 f6 = __half22float2(yh2[(size_t)s6 * 32 + hl]);
        float2 f7 = __half22float2(yh2[(size_t)s7 * 32 + hl]);
        float2 f8 = __half22float2(yh2[(size_t)s8 * 32 + hl]);
        float2 f9 = __half22float2(yh2[(size_t)s9 * 32 + hl]);
        float2 fa = __half22float2(yh2[(size_t)sa * 32 + hl]);
        float2 fb = __half22float2(yh2[(size_t)sb * 32 + hl]);
        float2 fc = __half22float2(yh2[(size_t)sc * 32 + hl]);
        float2 fd = __half22float2(yh2[(size_t)sd * 32 + hl]);
        float2 fe = __half22float2(yh2[(size_t)sec * 32 + hl]);
        float2 ff = __half22float2(yh2[(size_t)sf * 32 + hl]);
        ax += ((m > 16 ? f0.x : 0.f) + (m > 17 ? f1.x : 0.f)) +
              ((m > 18 ? f2.x : 0.f) + (m > 19 ? f3.x : 0.f)) +
              ((m > 20 ? f4.x : 0.f) + (m > 21 ? f5.x : 0.f)) +
              ((m > 22 ? f6.x : 0.f) + (m > 23 ? f7.x : 0.f)) +
              ((m > 24 ? f8.x : 0.f) + (m > 25 ? f9.x : 0.f)) +
              ((m > 26 ? fa.x : 0.f) + (m > 27 ? fb.x : 0.f)) +
              ((m > 28 ? fc.x : 0.f) + (m > 29 ? fd.x : 0.f)) +
              ((m > 30 ? fe.x : 0.f) + (m > 31 ? ff.x : 0.f));
        ay += ((m > 16 ? f0.y : 0.f) + (m > 17 ? f1.y : 0.f)) +
              ((m > 18 ? f2.y : 0.f) + (m > 19 ? f3.y : 0.f)) +
              ((m > 20 ? f4.y : 0.f) + (m > 21 ? f5.y : 0.f)) +
              ((m > 22 ? f6.y : 0.f) + (m > 23 ? f7.y : 0.f)) +
              ((m > 24 ? f8.y : 0.f) + (m > 25 ? f9.y : 0.f)) +
              ((m > 26 ? fa.y : 0.f) + (m > 27 ? fb.y : 0.f)) +
              ((m > 28 ? fc.y : 0.f) + (m > 29 ? fd.y : 0.f)) +
              ((m > 30 ? fe.y : 0.f) + (m > 31 ? ff.y : 0.f));
    }
    if (deg > 32) {
        for (int e = beg + 32; e < end; ++e) {
            int s = eidx[e];
            float2 fv = __half22float2(yh2[(size_t)s * 32 + hl]);
            ax += fv.x; ay += fv.y;
        }
    }
    float di = dinv[n];
    float2 b2 = ((const float2*)b0)[hl];
    float o0 = fmaxf(di * ax + b2.x, 0.0f);
    float o1 = fmaxf(di * ay + b2.y, 0.0f);
    ((__half2*)hs)[nl * 32 + hl] = __floats2half2_rn(o0, o1);
    __syncthreads();

    // ---- epilogue: wave 0 computes zh rows for the block's 8 nodes -------
    if (threadIdx.x < 64) {
        int l = threadIdx.x;
        int g = l >> 4, c16 = l & 15;
        f16x8 a0 = *(const f16x8*)(&hs[c16][8 * g]);
        f16x8 a1 = *(const f16x8*)(&hs[c16][32 + 8 * g]);
        f32x4 acc0 = {0,0,0,0}, acc1 = {0,0,0,0}, acc2 = {0,0,0,0};
        #pragma unroll
        for (int s = 0; s < 2; ++s) {
            int ko = 32 * s + 8 * g;
            f16x8 b0f = *(const f16x8*)(wt1 + (0 * 16 + c16) * 64 + ko);
            f16x8 b1f = *(const f16x8*)(wt1 + (1 * 16 + c16) * 64 + ko);
            f16x8 b2f = *(const f16x8*)(wt1 + (2 * 16 + c16) * 64 + ko);
            f16x8 av = s ? a1 : a0;
            acc0 = __builtin_amdgcn_mfma_f32_16x16x32_f16(av, b0f, acc0, 0, 0, 0);
            acc1 = __builtin_amdgcn_mfma_f32_16x16x32_f16(av, b1f, acc1, 0, 0, 0);
            acc2 = __builtin_amdgcn_mfma_f32_16x16x32_f16(av, b2f, acc2, 0, 0, 0);
        }
        if (g < 2) {   // D rows 0..7 are the valid ones
            int nrow = blockIdx.x * 8 + 4 * g;
            #pragma unroll
            for (int r = 0; r < 4; ++r) {
                float dr = dinv[nrow + r];
                size_t bz = (size_t)(nrow + r) * ZPAD + c16;
                zh[bz +  0] = __float2half(dr * acc0[r]);
                zh[bz + 16] = __float2half(dr * acc1[r]);
                zh[bz + 32] = __float2half(dr * acc2[r]);
            }
        }
    }
}

// -------- layer 1 aggregate: out[n] = dinv[n]*(zh[n]+sum zh[src]) + b1 ------
__global__ __launch_bounds__(256) void k_agg1(
    const int* __restrict__ rp, const int* __restrict__ eidx,
    const float* __restrict__ dinv, const __half* __restrict__ zh,
    const float* __restrict__ b1, float* __restrict__ out) {
    int t = blockIdx.x * 256 + threadIdx.x;
    int n = t >> 5;
    int hl = threadIdx.x & 31;
    if (n >= N_NODES) return;
    int beg = rp[n], end = rp[n + 1];
    int deg = end - beg;
    int se = (beg + hl < end) ? eidx[beg + hl] : 0;
    const __half2* zh2 = (const __half2*)zh;
    float ax = 0.0f, ay = 0.0f;
    if (hl < 24) {
        float2 f = __half22float2(zh2[(size_t)n * 24 + hl]);
        ax = f.x; ay = f.y;
    }
    int m = deg < 32 ? deg : 32;
    int base = threadIdx.x & 32;

    {   // batch 0: slots 0..15, unconditional
        int s0 = __shfl(se, base + 0),  s1 = __shfl(se, base + 1);
        int s2 = __shfl(se, base + 2),  s3 = __shfl(se, base + 3);
        int s4 = __shfl(se, base + 4),  s5 = __shfl(se, base + 5);
        int s6 = __shfl(se, base + 6),  s7 = __shfl(se, base + 7);
        int s8 = __shfl(se, base + 8),  s9 = __shfl(se, base + 9);
        int sa = __shfl(se, base + 10), sb = __shfl(se, base + 11);
        int sc = __shfl(se, base + 12), sd = __shfl(se, base + 13);
        int sec = __shfl(se, base + 14), sf = __shfl(se, base + 15);
        if (hl < 24) {
            float2 f0 = __half22float2(zh2[(size_t)s0 * 24 + hl]);
            float2 f1 = __half22float2(zh2[(size_t)s1 * 24 + hl]);
            float2 f2 = __half22float2(zh2[(size_t)s2 * 24 + hl]);
            float2 f3 = __half22float2(zh2[(size_t)s3 * 24 + hl]);
            float2 f4 = __half22float2(zh2[(size_t)s4 * 24 + hl]);
            float2 f5 = __half22float2(zh2[(size_t)s5 * 24 + hl]);
            float2 f6 = __half22float2(zh2[(size_t)s6 * 24 + hl]);
            float2 f7 = __half22float2(zh2[(size_t)s7 * 24 + hl]);
            float2 f8 = __half22float2(zh2[(size_t)s8 * 24 + hl]);
            float2 f9 = __half22float2(zh2[(size_t)s9 * 24 + hl]);
            float2 fa = __half22float2(zh2[(size_t)sa * 24 + hl]);
            float2 fb = __half22float2(zh2[(size_t)sb * 24 + hl]);
            float2 fc = __half22float2(zh2[(size_t)sc * 24 + hl]);
            float2 fd = __half22float2(zh2[(size_t)sd * 24 + hl]);
            float2 fe = __half22float2(zh2[(size_t)sec * 24 + hl]);
            float2 ff = __half22float2(zh2[(size_t)sf * 24 + hl]);
            ax += ((m > 0  ? f0.x : 0.f) + (m > 1  ? f1.x : 0.f)) +
                  ((m > 2  ? f2.x : 0.f) + (m > 3  ? f3.x : 0.f)) +
                  ((m > 4  ? f4.x : 0.f) + (m > 5  ? f5.x : 0.f)) +
                  ((m > 6  ? f6.x : 0.f) + (m > 7  ? f7.x : 0.f)) +
                  ((m > 8  ? f8.x : 0.f) + (m > 9  ? f9.x : 0.f)) +
                  ((m > 10 ? fa.x : 0.f) + (m > 11 ? fb.x : 0.f)) +
                  ((m > 12 ? fc.x : 0.f) + (m > 13 ? fd.x : 0.f)) +
                  ((m > 14 ? fe.x : 0.f) + (m > 15 ? ff.x : 0.f));
            ay += ((m > 0  ? f0.y : 0.f) + (m > 1  ? f1.y : 0.f)) +
                  ((m > 2  ? f2.y : 0.f) + (m > 3  ? f3.y : 0.f)) +
                  ((m > 4  ? f4.y : 0.f) + (m > 5  ? f5.y : 0.f)) +
                  ((m > 6  ? f6.y : 0.f) + (m > 7  ? f7.y : 0.f)) +
                  ((m > 8  ? f8.y : 0.f) + (m > 9  ? f9.y : 0.f)) +
                  ((m > 10 ? fa.y : 0.f) + (m > 11 ? fb.y : 0.f)) +
                  ((m > 12 ? fc.y : 0.f) + (m > 13 ? fd.y : 0.f)) +
                  ((m > 14 ? fe.y : 0.f) + (m > 15 ? ff.y : 0.f));
        }
    }
    if (m > 16) {   // batch 1: slots 16..31
        int s0 = __shfl(se, base + 16), s1 = __shfl(se, base + 17);
        int s2 = __shfl(se, base + 18), s3 = __shfl(se, base + 19);
        int s4 = __shfl(se, base + 20), s5 = __shfl(se, base + 21);
        int s6 = __shfl(se, base + 22), s7 = __shfl(se, base + 23);
        int s8 = __shfl(se, base + 24), s9 = __shfl(se, base + 25);
        int sa = __shfl(se, base + 26), sb = __shfl(se, base + 27);
        int sc = __shfl(se, base + 28), sd = __shfl(se, base + 29);
        int sec = __shfl(se, base + 30), sf = __shfl(se, base + 31);
        if (hl < 24) {
            float2 f0 = __half22float2(zh2[(size_t)s0 * 24 + hl]);
            float2 f1 = __half22float2(zh2[(size_t)s1 * 24 + hl]);
            float2 f2 = __half22float2(zh2[(size_t)s2 * 24 + hl]);
            float2 f3 = __half22float2(zh2[(size_t)s3 * 24 + hl]);
            float2 f4 = __half22float2(zh2[(size_t)s4 * 24 + hl]);
            float2 f5 = __half22float2(zh2[(size_t)s5 * 24 + hl]);
            float2 f6 = __half22float2(zh2[(size_t)s6 * 24 + hl]);
            float2 f7 = __half22float2(zh2[(size_t)s7 * 24 + hl]);
            float2 f8 = __half22float2(zh2[(size_t)s8 * 24 + hl]);
            float2 f9 = __half22float2(zh2[(size_t)s9 * 24 + hl]);
            float2 fa = __half22float2(zh2[(size_t)sa * 24 + hl]);
            float2 fb = __half22float2(zh2[(size_t)sb * 24 + hl]);
            float2 fc = __half22float2(zh2[(size_t)sc * 24 + hl]);
            float2 fd = __half22float2(zh2[(size_t)sd * 24 + hl]);
            float2 fe = __half22float2(zh2[(size_t)sec * 24 + hl]);
            float2 ff = __half22float2(zh2[(size_t)sf * 24 + hl]);
            ax += ((m > 16 ? f0.x : 0.f) + (m > 17 ? f1.x : 0.f)) +
                  ((m > 18 ? f2.x : 0.f) + (m > 19 ? f3.x : 0.f)) +
                  ((m > 20 ? f4.x : 0.f) + (m > 21 ? f5.x : 0.f)) +
                  ((m > 22 ? f6.x : 0.f) + (m > 23 ? f7.x : 0.f)) +
                  ((m > 24 ? f8.x : 0.f) + (m > 25 ? f9.x : 0.f)) +
                  ((m > 26 ? fa.x : 0.f) + (m > 27 ? fb.x : 0.f)) +
                  ((m > 28 ? fc.x : 0.f) + (m > 29 ? fd.x : 0.f)) +
                  ((m > 30 ? fe.x : 0.f) + (m > 31 ? ff.x : 0.f));
            ay += ((m > 16 ? f0.y : 0.f) + (m > 17 ? f1.y : 0.f)) +
                  ((m > 18 ? f2.y : 0.f) + (m > 19 ? f3.y : 0.f)) +
                  ((m > 20 ? f4.y : 0.f) + (m > 21 ? f5.y : 0.f)) +
                  ((m > 22 ? f6.y : 0.f) + (m > 23 ? f7.y : 0.f)) +
                  ((m > 24 ? f8.y : 0.f) + (m > 25 ? f9.y : 0.f)) +
                  ((m > 26 ? fa.y : 0.f) + (m > 27 ? fb.y : 0.f)) +
                  ((m > 28 ? fc.y : 0.f) + (m > 29 ? fd.y : 0.f)) +
                  ((m > 30 ? fe.y : 0.f) + (m > 31 ? ff.y : 0.f));
        }
    }
    if (deg > 32) {
        for (int e = beg + 32; e < end; ++e) {
            int s = eidx[e];
            if (hl < 24) {
                float2 fv = __half22float2(zh2[(size_t)s * 24 + hl]);
                ax += fv.x; ay += fv.y;
            }
        }
    }
    if (hl < 24) {
        float di = dinv[n];
        out[(size_t)n * N_CLASSES + 2 * hl] = di * ax + b1[2 * hl];
        if (hl < 23)
            out[(size_t)n * N_CLASSES + 2 * hl + 1] = di * ay + b1[2 * hl + 1];
    }
}

extern "C" void kernel_launch(void* const* d_in, const int* in_sizes, int n_in,
                              void* d_out, int out_size, void* d_ws, size_t ws_size,
                              hipStream_t stream) {
    const float* x  = (const float*)d_in[0];
    const int*   ei = (const int*)d_in[1];
    const float* W0 = (const float*)d_in[2];
    const float* b0 = (const float*)d_in[3];
    const float* W1 = (const float*)d_in[4];
    const float* b1 = (const float*)d_in[5];
    float* out = (float*)d_out;

    char* ws = (char*)d_ws;
    float*  dinv  = (float*)(ws);                         // 400 KB
    int*    rp    = (int*)(ws + 412 * 1024);              // 400 KB + 4
    int*    hsums = (int*)(ws + 824 * 1024);              // 1.6 KB (391 ints)
    int*    gh    = (int*)(ws + 828 * 1024);              // 782 KB -> 1610
    int*    gpos  = (int*)(ws + 1612 * 1024);             // 782 KB -> 2394
    __half* wt0   = (__half*)(ws + 2400 * 1024);          // 16 KB
    __half* wt1   = (__half*)(ws + 2420 * 1024);          // 6 KB
    int*    eidx  = (int*)(ws + 2428 * 1024);             // 6.4 MB -> ~8.8 MB
    __half* yh    = (__half*)(ws + 10ull * 1024 * 1024);  // 12.8 MB -> 22.8 MB
    __half* zh    = (__half*)(ws + 23ull * 1024 * 1024);  // 9.6 MB (own buffer)
    int*    pairs = (int*)zh;   // 6.4 MB alias: dead before k_agg0 writes zh

    const int* erow = ei;             // edge_index[0] (sources)
    const int* ecol = ei + N_EDGES;   // edge_index[1] (destinations)

    // radix pass (wprep fused into hist)
    k_hist  <<<SBLK, 256, 0, stream>>>(ecol, gh, W0, W1, wt0, wt1);
    k_gscan1<<<NBIN, 512, 0, stream>>>(gh, gpos, hsums, NHIST);
    k_gscan2<<<1, 512, 0, stream>>>(hsums, NBIN);
    k_radix_scatter<<<SBLK, 256, 0, stream>>>(erow, ecol, gpos, hsums, pairs);
    k_binfinish<<<NBIN, 1024, 0, stream>>>(gpos, hsums, pairs, rp, dinv, eidx);

    // layer 0 GEMM, then fused (layer-0 aggregate + layer-1 GEMM)
    k_gemm1<<<(N_NODES + 63) / 64, 256, 0, stream>>>(x, wt0, dinv, yh);
    k_agg0 <<<(N_NODES * 32) / 256, 256, 0, stream>>>(rp, eidx, dinv, yh, b0, wt1, zh);

    // layer 1 aggregate
    k_agg1 <<<(N_NODES * 32) / 256, 256, 0, stream>>>(rp, eidx, dinv, zh, b1, out);
}